// Round 6
// baseline (2264.052 us; speedup 1.0000x reference)
//
#include <hip/hip_runtime.h>

typedef __bf16 bfrag __attribute__((ext_vector_type(8)));
typedef float ffrag __attribute__((ext_vector_type(16)));

// ---------------------------------------------------------------------------
// Shapes / constants
// ---------------------------------------------------------------------------
constexpr int Bn  = 128;
constexpr int H0  = 98, Wi0 = 40;
constexpr int KH1 = 20, KW1 = 8, H1 = 79, Wo1 = 33, P1 = H1 * Wo1;   // 2607
constexpr int KH2 = 15, KW2 = 8, H2 = 65, Wo2 = 26, P2 = H2 * Wo2;   // 1690
constexpr int KH3 = 10, KW3 = 8, H3 = 56, Wo3 = 19, P3 = H3 * Wo3;   // 1064
constexpr int M1  = Bn * P1;
constexpr int M2  = Bn * P2;
constexpr int M3  = Bn * P3;
constexpr int KFC = 64 * P3;   // 68096
constexpr int FCCH = 16;
constexpr int FCKL = KFC / FCCH;   // 4256
constexpr float EPSF = 1e-5f;

// ---------------------------------------------------------------------------
// Workspace layout (float slots)
// ---------------------------------------------------------------------------
constexpr size_t oA  = 0;
constexpr size_t oB  = oA  + (size_t)Bn * 64 * P1;          // 21,356,544
constexpr size_t oW2 = oB  + (size_t)Bn * 62 * P1;          // +20,689,152
constexpr size_t oW3 = oW2 + 245760;                        // bf16 wq2 (491,520 el)
constexpr size_t oW1 = oW3 + 163840;                        // bf16 wq3 (327,680 el)
constexpr size_t oP  = oW1 + 5120;                          // bf16 wq1 (10,240 el)
constexpr size_t oSt = oP  + (size_t)FCCH * 8192;           // stats 9x128

__device__ __forceinline__ float wred(float v) {
    #pragma unroll
    for (int o = 32; o > 0; o >>= 1) v += __shfl_down(v, o);
    return v;
}
__device__ __forceinline__ float bfly(float v) {
    #pragma unroll
    for (int o = 1; o < 64; o <<= 1) v += __shfl_xor(v, o);
    return v;
}

// ---------------------------------------------------------------------------
// combined prep: zero stats + pack wq1/wq2/wq3 (one dispatch)
// ---------------------------------------------------------------------------
constexpr int NZ  = 9 * 128;                 // 1152
constexpr int NW1 = 10240;
constexpr int NW2 = KH2 * KW2 * 4096;        // 491520
constexpr int NW3 = KH3 * KW3 * 4096;        // 327680
constexpr int NPREP = NZ + NW1 + NW2 + NW3;
__global__ __launch_bounds__(256) void k_prep_all(
    const float* __restrict__ W11, const float* __restrict__ W21,
    const float* __restrict__ W31, __bf16* __restrict__ wq1,
    __bf16* __restrict__ wq2, __bf16* __restrict__ wq3,
    float* __restrict__ st)
{
    int idx = blockIdx.x * 256 + threadIdx.x;
    if (idx < NZ) { st[idx] = 0.f; return; }
    idx -= NZ;
    if (idx < NW1) {
        int j = idx & 7, oc = (idx >> 3) & 63, khh = idx >> 9;
        wq1[idx] = (__bf16)W11[(size_t)oc * 160 + khh * 8 + j];
        return;
    }
    idx -= NW1;
    if (idx < NW2) {
        int j = idx & 7, oc = (idx >> 3) & 63, sub = (idx >> 9) & 1;
        int c = (idx >> 10) & 3, pos = idx >> 12;
        int kh = pos >> 3, kw = pos & 7;
        int ic = c * 16 + sub * 8 + j;
        wq2[idx] = (__bf16)W21[(((size_t)oc * 64 + ic) * KH2 + kh) * 8 + kw];
        return;
    }
    idx -= NW2;
    if (idx < NW3) {
        int j = idx & 7, oc = (idx >> 3) & 63, sub = (idx >> 9) & 1;
        int c = (idx >> 10) & 3, pos = idx >> 12;
        int kh = pos >> 3, kw = pos & 7;
        int ic = c * 16 + sub * 8 + j;
        wq3[idx] = (__bf16)W31[(((size_t)oc * 64 + ic) * KH3 + kh) * 8 + kw];
    }
}

// ---------------------------------------------------------------------------
// conv1 MFMA: x (128,1,98,40) -> (128,64,P1) + bias, fused ch-stats
// ---------------------------------------------------------------------------
constexpr int C1COPY = 1736;   // 217 chunks per copy (217%8=1)
__global__ __launch_bounds__(256, 2) void k_conv1m(
    const float* __restrict__ x, const __bf16* __restrict__ wq,
    const float* __restrict__ bias, float* __restrict__ out,
    float* __restrict__ sto)
{
    const int b = blockIdx.y;
    const int m0 = blockIdx.x * 512;
    const int t = threadIdx.x, lane = t & 63, wv = t >> 6;
    const int l31 = lane & 31, lh = lane >> 5;
    __shared__ __align__(16) __bf16 X8[8 * C1COPY];

    const int oh_lo = m0 / Wo1;
    int abase[4];
    #pragma unroll
    for (int mt = 0; mt < 4; ++mt) {
        int m = m0 + wv * 128 + mt * 32 + l31;
        int mc = m > P1 - 1 ? P1 - 1 : m;
        int oh = mc / Wo1, ow = mc - oh * Wo1;
        int s = ow & 7;
        abase[mt] = s * C1COPY + (oh - oh_lo) * 48 + (ow - s);
    }
    for (int idx = t; idx < 8 * 36 * 6; idx += 256) {
        int s = idx / 216; int rr = idx - s * 216;
        int r = rr / 6, q = rr - r * 6;
        int ih = oh_lo + r; if (ih > H0 - 1) ih = H0 - 1;
        const float* src = x + ((size_t)b * H0 + ih) * Wi0;
        __bf16 tmp[8] __attribute__((aligned(16)));
        #pragma unroll
        for (int j = 0; j < 8; ++j) {
            int col = q * 8 + s + j; if (col > Wi0 - 1) col = Wi0 - 1;
            tmp[j] = (__bf16)src[col];
        }
        *(uint4*)&X8[s * C1COPY + r * 48 + q * 8] = *(uint4*)tmp;
    }
    __syncthreads();

    ffrag acc[4][2] = {};
    #pragma unroll 1
    for (int st2 = 0; st2 < 10; ++st2) {
        const int khl = st2 * 2 + lh;
        const __bf16* wp = wq + ((size_t)khl * 64 + l31) * 8;
        bfrag b0 = *(const bfrag*)(wp);
        bfrag b1 = *(const bfrag*)(wp + 256);
        #pragma unroll
        for (int mt = 0; mt < 4; ++mt) {
            bfrag a = *(const bfrag*)&X8[abase[mt] + khl * 48];
            acc[mt][0] = __builtin_amdgcn_mfma_f32_32x32x16_bf16(a, b0, acc[mt][0], 0, 0, 0);
            acc[mt][1] = __builtin_amdgcn_mfma_f32_32x32x16_bf16(a, b1, acc[mt][1], 0, 0, 0);
        }
    }

    float sS[2] = {0.f, 0.f}, sSS[2] = {0.f, 0.f};
    #pragma unroll
    for (int nt = 0; nt < 2; ++nt) {
        int oc = nt * 32 + l31;
        float bv = bias[oc];
        float* op = out + ((size_t)b * 64 + oc) * P1;
        #pragma unroll
        for (int mt = 0; mt < 4; ++mt) {
            int mbase = m0 + wv * 128 + mt * 32 + lh * 4;
            #pragma unroll
            for (int g = 0; g < 4; ++g) {
                int mr = mbase + g * 8;
                float v0 = acc[mt][nt][g * 4 + 0] + bv;
                float v1 = acc[mt][nt][g * 4 + 1] + bv;
                float v2 = acc[mt][nt][g * 4 + 2] + bv;
                float v3 = acc[mt][nt][g * 4 + 3] + bv;
                if (mr + 1 < P1) {
                    *(float2*)(op + mr) = make_float2(v0, v1);
                    sS[nt] += v0 + v1; sSS[nt] += v0 * v0 + v1 * v1;
                    if (mr + 3 < P1) {
                        *(float2*)(op + mr + 2) = make_float2(v2, v3);
                        sS[nt] += v2 + v3; sSS[nt] += v2 * v2 + v3 * v3;
                    } else if (mr + 2 < P1) {
                        op[mr + 2] = v2; sS[nt] += v2; sSS[nt] += v2 * v2;
                    }
                } else if (mr < P1) {
                    op[mr] = v0; sS[nt] += v0; sSS[nt] += v0 * v0;
                }
            }
        }
    }
    #pragma unroll
    for (int nt = 0; nt < 2; ++nt) {
        sS[nt]  += __shfl_down(sS[nt], 32);
        sSS[nt] += __shfl_down(sSS[nt], 32);
    }
    __syncthreads();
    float* redS  = (float*)X8;
    float* redSS = redS + 256;
    if (lane < 32) {
        #pragma unroll
        for (int nt = 0; nt < 2; ++nt) {
            redS[wv * 64 + nt * 32 + l31]  = sS[nt];
            redSS[wv * 64 + nt * 32 + l31] = sSS[nt];
        }
    }
    __syncthreads();
    if (t < 64) {
        atomicAdd(&sto[t],      redS[t] + redS[64 + t] + redS[128 + t] + redS[192 + t]);
        atomicAdd(&sto[64 + t], redSS[t] + redSS[64 + t] + redSS[128 + t] + redSS[192 + t]);
    }
}

// ---------------------------------------------------------------------------
// lc: per-ch affine + relu on load, 3-tap conv -> 62ch, fused global stats
// ---------------------------------------------------------------------------
template <int POS>
__global__ __launch_bounds__(256) void k_lc(const float* __restrict__ in,
                                            const float* __restrict__ stp,
                                            const float* __restrict__ g,
                                            const float* __restrict__ be,
                                            float inv,
                                            const float* __restrict__ lcw,
                                            const float* __restrict__ lcb,
                                            float* __restrict__ out,
                                            float* __restrict__ sto) {
    __shared__ float sAff[128];
    __shared__ float sred[4], ssred[4];
    if (threadIdx.x < 64) {
        int tt = threadIdx.x;
        float mm = stp[tt] * inv;
        float vv = stp[64 + tt] * inv - mm * mm;
        float sc = g[tt] * rsqrtf(vv + EPSF);
        sAff[tt] = sc;
        sAff[64 + tt] = be[tt] - mm * sc;
    }
    __syncthreads();
    int morig = blockIdx.x * 256 + threadIdx.x;
    bool valid = morig < Bn * POS;
    int m = valid ? morig : Bn * POS - 1;
    int b = m / POS; int p = m - b * POS;
    const float* ip = in + (size_t)b * 64 * POS + p;
    float* op = out + (size_t)b * 62 * POS + p;
    float ts = 0.f, tss = 0.f;
    float y0 = fmaxf(sAff[0] * ip[0]           + sAff[64], 0.f);
    float y1 = fmaxf(sAff[1] * ip[(size_t)POS] + sAff[65], 0.f);
    for (int c = 0; c < 62; ++c) {
        float y2 = fmaxf(sAff[c + 2] * ip[(size_t)(c + 2) * POS] + sAff[64 + c + 2], 0.f);
        float o = lcb[c] + y0 * lcw[c * 3] + y1 * lcw[c * 3 + 1] + y2 * lcw[c * 3 + 2];
        op[(size_t)c * POS] = o;
        if (valid) { ts += o; tss += o * o; }
        y0 = y1; y1 = y2;
    }
    ts = wred(ts); tss = wred(tss);
    int wv = threadIdx.x >> 6, ln = threadIdx.x & 63;
    if (ln == 0) { sred[wv] = ts; ssred[wv] = tss; }
    __syncthreads();
    if (threadIdx.x == 0) {
        atomicAdd(&sto[0],  sred[0] + sred[1] + sred[2] + sred[3]);
        atomicAdd(&sto[64], ssred[0] + ssred[1] + ssred[2] + ssred[3]);
    }
}

// ---------------------------------------------------------------------------
// mix: scalar affine+relu, channel-mix 62->64, fused per-channel stats
// ---------------------------------------------------------------------------
template <int POS>
__global__ __launch_bounds__(256) void k_mix(const float* __restrict__ in,
                                             const float* __restrict__ stp,
                                             const float* __restrict__ g,
                                             const float* __restrict__ be,
                                             float inv,
                                             const float* __restrict__ Wm,
                                             const float* __restrict__ bm,
                                             float* __restrict__ out,
                                             float* __restrict__ sto) {
    __shared__ float redS[4][64], redSS[4][64];
    float mm = stp[0] * inv;
    float vv = stp[64] * inv - mm * mm;
    float s0 = g[0] * rsqrtf(vv + EPSF);
    float t0 = be[0] - mm * s0;

    int morig = blockIdx.x * 256 + threadIdx.x;
    bool valid = morig < Bn * POS;
    int m = valid ? morig : Bn * POS - 1;
    int b = m / POS; int p = m - b * POS;
    const float* ip = in + (size_t)b * 62 * POS + p;
    float z[62];
    #pragma unroll
    for (int d = 0; d < 62; ++d)
        z[d] = fmaxf(s0 * ip[(size_t)d * POS] + t0, 0.f);
    float* op = out + (size_t)b * 64 * POS + p;
    int lane = threadIdx.x & 63, wv = threadIdx.x >> 6;
    float myS = 0.f, mySS = 0.f;
    for (int c = 0; c < 64; ++c) {
        float acc = bm[c];
        #pragma unroll
        for (int d = 0; d < 62; ++d) acc += z[d] * Wm[c * 62 + d];
        op[(size_t)c * POS] = acc;
        float vvv = valid ? acc : 0.f;
        float sT  = bfly(vvv);
        float ssT = bfly(vvv * vvv);
        if (lane == c) { myS = sT; mySS = ssT; }
    }
    redS[wv][lane] = myS; redSS[wv][lane] = mySS;
    __syncthreads();
    if (threadIdx.x < 64) {
        int tt = threadIdx.x;
        atomicAdd(&sto[tt],      redS[0][tt] + redS[1][tt] + redS[2][tt] + redS[3][tt]);
        atomicAdd(&sto[64 + tt], redSS[0][tt] + redSS[1][tt] + redSS[2][tt] + redSS[3][tt]);
    }
}

// ---------------------------------------------------------------------------
// prep: fp32 [b][64][P] + affine(from stats) -> bf16 channel-last halves
// ---------------------------------------------------------------------------
template <int IH, int IW>
__global__ __launch_bounds__(256) void k_prep_in(const float* __restrict__ in,
                                                 const float* __restrict__ stp,
                                                 const float* __restrict__ g,
                                                 const float* __restrict__ be,
                                                 float inv,
                                                 __bf16* __restrict__ out) {
    constexpr int P = IH * IW;
    __shared__ float tile[64][65];
    const int b = blockIdx.y, p0 = blockIdx.x * 64;
    const int pl = threadIdx.x & 63, ch4 = threadIdx.x >> 6;
    #pragma unroll
    for (int i = 0; i < 16; ++i) {
        int c = i * 4 + ch4;
        int p = p0 + pl; if (p > P - 1) p = P - 1;
        tile[pl][c] = in[((size_t)b * 64 + c) * P + p];
    }
    __syncthreads();
    const int cl = threadIdx.x & 63;
    float mm = stp[cl] * inv;
    float vv = stp[64 + cl] * inv - mm * mm;
    float sc = g[cl] * rsqrtf(vv + EPSF);
    float sh = be[cl] - mm * sc;
    #pragma unroll
    for (int i = 0; i < 16; ++i) {
        int plocal = i * 4 + ch4;
        int p = p0 + plocal; if (p > P - 1) p = P - 1;
        int ih = p / IW, iw = p - ih * IW;
        float v = sc * tile[plocal][cl] + sh;
        out[(((size_t)b * IH + ih) * 2 + (cl >> 5)) * (IW * 32) + iw * 32 + (cl & 31)] = (__bf16)v;
    }
}

// ---------------------------------------------------------------------------
// implicit-GEMM conv, bf16 MFMA 32x32x16; M=512/block, proven swizzle,
// fused ch-stats
// ---------------------------------------------------------------------------
template <int KH, int KW, int IH, int IW, int OH, int OW, int NR>
__global__ __launch_bounds__(256, 2) void k_convmfma(
    const __bf16* __restrict__ in,
    const __bf16* __restrict__ wq,
    const float* __restrict__ bias,
    float* __restrict__ out,
    float* __restrict__ sto)
{
    constexpr int P = OH * OW;
    const int b  = blockIdx.y;
    const int m0 = blockIdx.x * 512;
    const int t  = threadIdx.x;
    const int lane = t & 63;
    const int wv = t >> 6;
    const int l31 = lane & 31, lh = lane >> 5;

    __shared__ __align__(16) __bf16 As[NR * IW * 32 + 64];

    const int oh_lo = m0 / OW;
    int posm[4];
    #pragma unroll
    for (int mt = 0; mt < 4; ++mt) {
        int m = m0 + wv * 128 + mt * 32 + l31;
        int mc = m > P - 1 ? P - 1 : m;
        int oh = mc / OW, ow = mc - oh * OW;
        posm[mt] = (oh - oh_lo) * IW + ow;
    }

    ffrag acc[4][2] = {};

    for (int ich = 0; ich < 2; ++ich) {
        __syncthreads();
        constexpr int ROWCH = IW * 4;
        constexpr int CH = NR * ROWCH;
        for (int idx = t; idx < CH; idx += 256) {
            int r = idx / ROWCH, o = idx - r * ROWCH;
            int ih = oh_lo + r; if (ih > IH - 1) ih = IH - 1;
            const __bf16* src = in + ((size_t)(b * IH + ih) * 2 + ich) * (IW * 32) + o * 8;
            int sw = idx ^ ((idx >> 2) & 7);       // proven bijective swizzle
            *(uint4*)&As[sw * 8] = *(const uint4*)src;
        }
        __syncthreads();

        const __bf16* wich = wq + ich * 2048;
        for (int kh = 0; kh < KH; ++kh) {
            const int rowoff = kh * IW;
            const __bf16* wkh = wich + (size_t)(kh * KW) * 4096 + lh * 512 + l31 * 8;
            #pragma unroll 1
            for (int kw = 0; kw < KW; ++kw) {
                const __bf16* wp = wkh + kw * 4096;
                #pragma unroll
                for (int cc = 0; cc < 2; ++cc) {
                    bfrag b0 = *(const bfrag*)(wp + cc * 1024);
                    bfrag b1 = *(const bfrag*)(wp + cc * 1024 + 256);
                    #pragma unroll
                    for (int mt = 0; mt < 4; ++mt) {
                        int X = posm[mt] + rowoff + kw;
                        int gc = (X << 2) + cc * 2 + lh;
                        bfrag a = *(const bfrag*)&As[(gc ^ (X & 7)) * 8];
                        acc[mt][0] = __builtin_amdgcn_mfma_f32_32x32x16_bf16(a, b0, acc[mt][0], 0, 0, 0);
                        acc[mt][1] = __builtin_amdgcn_mfma_f32_32x32x16_bf16(a, b1, acc[mt][1], 0, 0, 0);
                    }
                }
            }
        }
    }

    float sS[2] = {0.f, 0.f}, sSS[2] = {0.f, 0.f};
    #pragma unroll
    for (int nt = 0; nt < 2; ++nt) {
        int oc = nt * 32 + l31;
        float bv = bias[oc];
        float* op = out + ((size_t)b * 64 + oc) * P;
        #pragma unroll
        for (int mt = 0; mt < 4; ++mt) {
            int mbase = m0 + wv * 128 + mt * 32 + lh * 4;
            #pragma unroll
            for (int g = 0; g < 4; ++g) {
                int mr = mbase + g * 8;
                if (mr < P) {
                    float v0 = acc[mt][nt][g * 4 + 0] + bv;
                    float v1 = acc[mt][nt][g * 4 + 1] + bv;
                    *(float2*)(op + mr) = make_float2(v0, v1);
                    sS[nt] += v0 + v1; sSS[nt] += v0 * v0 + v1 * v1;
                    if (mr + 2 < P) {
                        float v2 = acc[mt][nt][g * 4 + 2] + bv;
                        float v3 = acc[mt][nt][g * 4 + 3] + bv;
                        *(float2*)(op + mr + 2) = make_float2(v2, v3);
                        sS[nt] += v2 + v3; sSS[nt] += v2 * v2 + v3 * v3;
                    }
                }
            }
        }
    }
    #pragma unroll
    for (int nt = 0; nt < 2; ++nt) {
        sS[nt]  += __shfl_down(sS[nt], 32);
        sSS[nt] += __shfl_down(sSS[nt], 32);
    }
    __syncthreads();
    float* redS  = (float*)As;
    float* redSS = redS + 256;
    if (lane < 32) {
        #pragma unroll
        for (int nt = 0; nt < 2; ++nt) {
            redS[wv * 64 + nt * 32 + l31]  = sS[nt];
            redSS[wv * 64 + nt * 32 + l31] = sSS[nt];
        }
    }
    __syncthreads();
    if (t < 64) {
        atomicAdd(&sto[t],      redS[t] + redS[64 + t] + redS[128 + t] + redS[192 + t]);
        atomicAdd(&sto[64 + t], redSS[t] + redSS[64 + t] + redSS[128 + t] + redSS[192 + t]);
    }
}

// ---------------------------------------------------------------------------
// FC head
// ---------------------------------------------------------------------------
__global__ __launch_bounds__(256) void k_transpose(const float* __restrict__ in,
                                                   const float* __restrict__ stp,
                                                   const float* __restrict__ g,
                                                   const float* __restrict__ be,
                                                   float inv,
                                                   float* __restrict__ hT) {
    __shared__ float tile[32][33];
    int j0 = blockIdx.x * 32, b0 = blockIdx.y * 32;
    int lo = threadIdx.x & 31, hi = threadIdx.x >> 5;
    int c  = (j0 + lo) / P3;
    float mm = stp[c] * inv;
    float vv = stp[64 + c] * inv - mm * mm;
    float sc = g[c] * rsqrtf(vv + EPSF);
    float sh = be[c] - mm * sc;
    #pragma unroll
    for (int tt = 0; tt < 4; ++tt) {
        int bl = tt * 8 + hi;
        tile[bl][lo] = sc * in[(size_t)(b0 + bl) * KFC + (j0 + lo)] + sh;
    }
    __syncthreads();
    #pragma unroll
    for (int tt = 0; tt < 4; ++tt) {
        int jl = tt * 8 + hi;
        hT[(size_t)(j0 + jl) * Bn + b0 + lo] = tile[lo][jl];
    }
}

__global__ __launch_bounds__(256) void k_fc1(const float* __restrict__ hT,
                                             const float* __restrict__ Wf1,
                                             float* __restrict__ Pb) {
    int lane = threadIdx.x & 63;
    int f0 = __builtin_amdgcn_readfirstlane((threadIdx.x >> 6) * 16);
    int b  = blockIdx.y * 64 + lane;
    int kc = blockIdx.x;
    int k0 = kc * FCKL;
    float acc[16] = {};
    for (int k = k0; k < k0 + FCKL; ++k) {
        float hv = hT[(size_t)k * Bn + b];
        #pragma unroll
        for (int f = 0; f < 16; ++f)
            acc[f] += hv * Wf1[(size_t)(f0 + f) * KFC + k];
    }
    float* pp = Pb + (size_t)kc * 8192 + (size_t)b * 64 + f0;
    #pragma unroll
    for (int f = 0; f < 16; ++f) pp[f] = acc[f];
}

// fc1 split-K reduce + batch-BN + relu + fc2, single block
__global__ __launch_bounds__(256) void k_fcfin(const float* __restrict__ Pb,
                                               const float* __restrict__ bf1,
                                               const float* __restrict__ gf,
                                               const float* __restrict__ bef,
                                               const float* __restrict__ Wf2,
                                               const float* __restrict__ bf2,
                                               float* __restrict__ out) {
    __shared__ float sF[8192];
    __shared__ float sfa[128];
    const int t = threadIdx.x;
    for (int m = t; m < 8192; m += 256) {
        float s = 0.f;
        #pragma unroll
        for (int kc = 0; kc < FCCH; ++kc) s += Pb[(size_t)kc * 8192 + m];
        sF[m] = s;
    }
    __syncthreads();
    if (t < 64) {
        float s = 0.f, ss = 0.f;
        for (int b = 0; b < Bn; ++b) {
            float v = sF[b * 64 + t] + bf1[t];
            s += v; ss += v * v;
        }
        float m  = s / 128.f;
        float va = ss / 128.f - m * m;
        float sc = gf[t] * rsqrtf(va + EPSF);
        sfa[t] = sc;
        sfa[64 + t] = sc * bf1[t] + bef[t] - m * sc;   // folded bf1
    }
    __syncthreads();
    for (int m = t; m < Bn * 35; m += 256) {
        int b = m / 35, o = m - b * 35;
        float acc = bf2[o];
        for (int ff = 0; ff < 64; ++ff) {
            int f = (ff + t) & 63;   // stagger to avoid LDS bank serialization
            float z = fmaxf(sfa[f] * sF[b * 64 + f] + sfa[64 + f], 0.f);
            acc += z * Wf2[o * 64 + f];
        }
        out[m] = acc;
    }
}

// ---------------------------------------------------------------------------
// launch
// ---------------------------------------------------------------------------
extern "C" void kernel_launch(void* const* d_in, const int* in_sizes, int n_in,
                              void* d_out, int out_size, void* d_ws, size_t ws_size,
                              hipStream_t stream) {
    const float* x    = (const float*)d_in[0];
    const float* W11  = (const float*)d_in[1];
    const float* b11  = (const float*)d_in[2];
    const float* g11  = (const float*)d_in[3];
    const float* be11 = (const float*)d_in[4];
    const float* lc1w = (const float*)d_in[5];
    const float* lc1b = (const float*)d_in[6];
    const float* g12  = (const float*)d_in[7];
    const float* be12 = (const float*)d_in[8];
    const float* W13  = (const float*)d_in[9];
    const float* b13  = (const float*)d_in[10];
    const float* g13  = (const float*)d_in[11];
    const float* be13 = (const float*)d_in[12];
    const float* W21  = (const float*)d_in[13];
    const float* b21  = (const float*)d_in[14];
    const float* g21  = (const float*)d_in[15];
    const float* be21 = (const float*)d_in[16];
    const float* lc2w = (const float*)d_in[17];
    const float* lc2b = (const float*)d_in[18];
    const float* g22  = (const float*)d_in[19];
    const float* be22 = (const float*)d_in[20];
    const float* W23  = (const float*)d_in[21];
    const float* b23  = (const float*)d_in[22];
    const float* g23  = (const float*)d_in[23];
    const float* be23 = (const float*)d_in[24];
    const float* W31  = (const float*)d_in[25];
    const float* b31  = (const float*)d_in[26];
    const float* g31  = (const float*)d_in[27];
    const float* be31 = (const float*)d_in[28];
    const float* lc3w = (const float*)d_in[29];
    const float* lc3b = (const float*)d_in[30];
    const float* g32  = (const float*)d_in[31];
    const float* be32 = (const float*)d_in[32];
    const float* W33  = (const float*)d_in[33];
    const float* b33  = (const float*)d_in[34];
    const float* g33  = (const float*)d_in[35];
    const float* be33 = (const float*)d_in[36];
    const float* Wf1  = (const float*)d_in[37];
    const float* bf1  = (const float*)d_in[38];
    const float* gf   = (const float*)d_in[39];
    const float* bef  = (const float*)d_in[40];
    const float* Wf2  = (const float*)d_in[41];
    const float* bf2  = (const float*)d_in[42];

    float* ws  = (float*)d_ws;
    float* A   = ws + oA;
    float* Bb  = ws + oB;
    __bf16* Bcl = (__bf16*)(ws + oB);
    __bf16* wq2 = (__bf16*)(ws + oW2);
    __bf16* wq3 = (__bf16*)(ws + oW3);
    __bf16* wq1 = (__bf16*)(ws + oW1);
    float* Pb  = ws + oP;
    float* st  = ws + oSt;

    const int blk1 = (M1 + 255) / 256;
    const int blk2 = M2 / 256;
    const int blk3 = M3 / 256;

    k_prep_all<<<(NPREP + 255) / 256, 256, 0, stream>>>(W11, W21, W31, wq1, wq2, wq3, st);

    // ---- stage 1 ----
    k_conv1m<<<dim3((P1 + 511) / 512, Bn), 256, 0, stream>>>(x, wq1, b11, A, st + 0 * 128);
    k_lc<P1><<<blk1, 256, 0, stream>>>(A, st + 0 * 128, g11, be11, 1.0f / (float)M1,
                                       lc1w, lc1b, Bb, st + 1 * 128);
    k_mix<P1><<<blk1, 256, 0, stream>>>(Bb, st + 1 * 128, g12, be12, 1.0f / (62.0f * (float)M1),
                                        W13, b13, A, st + 2 * 128);

    // ---- stage 2 ----
    k_prep_in<H1, Wo1><<<dim3((P1 + 63) / 64, Bn), 256, 0, stream>>>(
        A, st + 2 * 128, g13, be13, 1.0f / (float)M1, Bcl);
    k_convmfma<KH2, KW2, H1, Wo1, H2, Wo2, 35>
        <<<dim3((P2 + 511) / 512, Bn), 256, 0, stream>>>(Bcl, wq2, b21, A, st + 3 * 128);
    k_lc<P2><<<blk2, 256, 0, stream>>>(A, st + 3 * 128, g21, be21, 1.0f / (float)M2,
                                       lc2w, lc2b, Bb, st + 4 * 128);
    k_mix<P2><<<blk2, 256, 0, stream>>>(Bb, st + 4 * 128, g22, be22, 1.0f / (62.0f * (float)M2),
                                        W23, b23, A, st + 5 * 128);

    // ---- stage 3 ----
    k_prep_in<H2, Wo2><<<dim3((P2 + 63) / 64, Bn), 256, 0, stream>>>(
        A, st + 5 * 128, g23, be23, 1.0f / (float)M2, Bcl);
    k_convmfma<KH3, KW3, H2, Wo2, H3, Wo3, 37>
        <<<dim3((P3 + 511) / 512, Bn), 256, 0, stream>>>(Bcl, wq3, b31, A, st + 6 * 128);
    k_lc<P3><<<blk3, 256, 0, stream>>>(A, st + 6 * 128, g31, be31, 1.0f / (float)M3,
                                       lc3w, lc3b, Bb, st + 7 * 128);
    k_mix<P3><<<blk3, 256, 0, stream>>>(Bb, st + 7 * 128, g32, be32, 1.0f / (62.0f * (float)M3),
                                        W33, b33, A, st + 8 * 128);

    // ---- FC head ----
    k_transpose<<<dim3(KFC / 32, Bn / 32), 256, 0, stream>>>(
        A, st + 8 * 128, g33, be33, 1.0f / (float)M3, Bb);
    k_fc1<<<dim3(FCCH, 2), 256, 0, stream>>>(Bb, Wf1, Pb);
    k_fcfin<<<1, 256, 0, stream>>>(Pb, bf1, gf, bef, Wf2, bf2, (float*)d_out);
}

// Round 7
// 1222.038 us; speedup vs baseline: 1.8527x; 1.8527x over previous
//
#include <hip/hip_runtime.h>

typedef __bf16 bfrag __attribute__((ext_vector_type(8)));
typedef float ffrag __attribute__((ext_vector_type(16)));

// ---------------------------------------------------------------------------
// Shapes / constants
// ---------------------------------------------------------------------------
constexpr int Bn  = 128;
constexpr int H0  = 98, Wi0 = 40;
constexpr int KH1 = 20, KW1 = 8, H1 = 79, Wo1 = 33, P1 = H1 * Wo1;   // 2607
constexpr int KH2 = 15, KW2 = 8, H2 = 65, Wo2 = 26, P2 = H2 * Wo2;   // 1690
constexpr int KH3 = 10, KW3 = 8, H3 = 56, Wo3 = 19, P3 = H3 * Wo3;   // 1064
constexpr int M1  = Bn * P1;
constexpr int M2  = Bn * P2;
constexpr int M3  = Bn * P3;
constexpr int KFC = 64 * P3;   // 68096
constexpr int FCCH = 128;          // split-K chunks (parallelism!)
constexpr int FCKL = KFC / FCCH;   // 532
constexpr float EPSF = 1e-5f;

// ---------------------------------------------------------------------------
// Workspace layout (float slots)
// ---------------------------------------------------------------------------
constexpr size_t oA  = 0;
constexpr size_t oB  = oA  + (size_t)Bn * 64 * P1;          // 21,356,544
constexpr size_t oW2 = oB  + (size_t)Bn * 62 * P1;          // +20,689,152
constexpr size_t oW3 = oW2 + 245760;                        // bf16 wq2 (491,520 el)
constexpr size_t oW1 = oW3 + 163840;                        // bf16 wq3 (327,680 el)
constexpr size_t oP  = oW1 + 5120;                          // bf16 wq1 (10,240 el)
constexpr size_t oSt = oP  + (size_t)FCCH * 8192;           // stats 9x128
constexpr size_t oF  = oSt + 9 * 128;                       // fc1 out (8192)

__device__ __forceinline__ float wred(float v) {
    #pragma unroll
    for (int o = 32; o > 0; o >>= 1) v += __shfl_down(v, o);
    return v;
}
__device__ __forceinline__ float bfly(float v) {
    #pragma unroll
    for (int o = 1; o < 64; o <<= 1) v += __shfl_xor(v, o);
    return v;
}

// ---------------------------------------------------------------------------
// combined prep: zero stats + pack wq1/wq2/wq3 (one dispatch)
// ---------------------------------------------------------------------------
constexpr int NZ  = 9 * 128;
constexpr int NW1 = 10240;
constexpr int NW2 = KH2 * KW2 * 4096;        // 491520
constexpr int NW3 = KH3 * KW3 * 4096;        // 327680
constexpr int NPREP = NZ + NW1 + NW2 + NW3;
__global__ __launch_bounds__(256) void k_prep_all(
    const float* __restrict__ W11, const float* __restrict__ W21,
    const float* __restrict__ W31, __bf16* __restrict__ wq1,
    __bf16* __restrict__ wq2, __bf16* __restrict__ wq3,
    float* __restrict__ st)
{
    int idx = blockIdx.x * 256 + threadIdx.x;
    if (idx < NZ) { st[idx] = 0.f; return; }
    idx -= NZ;
    if (idx < NW1) {
        int j = idx & 7, oc = (idx >> 3) & 63, khh = idx >> 9;
        wq1[idx] = (__bf16)W11[(size_t)oc * 160 + khh * 8 + j];
        return;
    }
    idx -= NW1;
    if (idx < NW2) {
        int j = idx & 7, oc = (idx >> 3) & 63, sub = (idx >> 9) & 1;
        int c = (idx >> 10) & 3, pos = idx >> 12;
        int kh = pos >> 3, kw = pos & 7;
        int ic = c * 16 + sub * 8 + j;
        wq2[idx] = (__bf16)W21[(((size_t)oc * 64 + ic) * KH2 + kh) * 8 + kw];
        return;
    }
    idx -= NW2;
    if (idx < NW3) {
        int j = idx & 7, oc = (idx >> 3) & 63, sub = (idx >> 9) & 1;
        int c = (idx >> 10) & 3, pos = idx >> 12;
        int kh = pos >> 3, kw = pos & 7;
        int ic = c * 16 + sub * 8 + j;
        wq3[idx] = (__bf16)W31[(((size_t)oc * 64 + ic) * KH3 + kh) * 8 + kw];
    }
}

// ---------------------------------------------------------------------------
// conv1 MFMA: x (128,1,98,40) -> (128,64,P1) + bias, fused ch-stats
// ---------------------------------------------------------------------------
constexpr int C1COPY = 1736;   // 217 chunks per copy (217%8=1)
__global__ __launch_bounds__(256, 2) void k_conv1m(
    const float* __restrict__ x, const __bf16* __restrict__ wq,
    const float* __restrict__ bias, float* __restrict__ out,
    float* __restrict__ sto)
{
    const int b = blockIdx.y;
    const int m0 = blockIdx.x * 512;
    const int t = threadIdx.x, lane = t & 63, wv = t >> 6;
    const int l31 = lane & 31, lh = lane >> 5;
    __shared__ __align__(16) __bf16 X8[8 * C1COPY];

    const int oh_lo = m0 / Wo1;
    int abase[4];
    #pragma unroll
    for (int mt = 0; mt < 4; ++mt) {
        int m = m0 + wv * 128 + mt * 32 + l31;
        int mc = m > P1 - 1 ? P1 - 1 : m;
        int oh = mc / Wo1, ow = mc - oh * Wo1;
        int s = ow & 7;
        abase[mt] = s * C1COPY + (oh - oh_lo) * 48 + (ow - s);
    }
    for (int idx = t; idx < 8 * 36 * 6; idx += 256) {
        int s = idx / 216; int rr = idx - s * 216;
        int r = rr / 6, q = rr - r * 6;
        int ih = oh_lo + r; if (ih > H0 - 1) ih = H0 - 1;
        const float* src = x + ((size_t)b * H0 + ih) * Wi0;
        __bf16 tmp[8] __attribute__((aligned(16)));
        #pragma unroll
        for (int j = 0; j < 8; ++j) {
            int col = q * 8 + s + j; if (col > Wi0 - 1) col = Wi0 - 1;
            tmp[j] = (__bf16)src[col];
        }
        *(uint4*)&X8[s * C1COPY + r * 48 + q * 8] = *(uint4*)tmp;
    }
    __syncthreads();

    ffrag acc[4][2] = {};
    #pragma unroll 1
    for (int st2 = 0; st2 < 10; ++st2) {
        const int khl = st2 * 2 + lh;
        const __bf16* wp = wq + ((size_t)khl * 64 + l31) * 8;
        bfrag b0 = *(const bfrag*)(wp);
        bfrag b1 = *(const bfrag*)(wp + 256);
        #pragma unroll
        for (int mt = 0; mt < 4; ++mt) {
            bfrag a = *(const bfrag*)&X8[abase[mt] + khl * 48];
            acc[mt][0] = __builtin_amdgcn_mfma_f32_32x32x16_bf16(a, b0, acc[mt][0], 0, 0, 0);
            acc[mt][1] = __builtin_amdgcn_mfma_f32_32x32x16_bf16(a, b1, acc[mt][1], 0, 0, 0);
        }
    }

    float sS[2] = {0.f, 0.f}, sSS[2] = {0.f, 0.f};
    #pragma unroll
    for (int nt = 0; nt < 2; ++nt) {
        int oc = nt * 32 + l31;
        float bv = bias[oc];
        float* op = out + ((size_t)b * 64 + oc) * P1;
        #pragma unroll
        for (int mt = 0; mt < 4; ++mt) {
            int mbase = m0 + wv * 128 + mt * 32 + lh * 4;
            #pragma unroll
            for (int g = 0; g < 4; ++g) {
                int mr = mbase + g * 8;
                float v0 = acc[mt][nt][g * 4 + 0] + bv;
                float v1 = acc[mt][nt][g * 4 + 1] + bv;
                float v2 = acc[mt][nt][g * 4 + 2] + bv;
                float v3 = acc[mt][nt][g * 4 + 3] + bv;
                if (mr + 1 < P1) {
                    *(float2*)(op + mr) = make_float2(v0, v1);
                    sS[nt] += v0 + v1; sSS[nt] += v0 * v0 + v1 * v1;
                    if (mr + 3 < P1) {
                        *(float2*)(op + mr + 2) = make_float2(v2, v3);
                        sS[nt] += v2 + v3; sSS[nt] += v2 * v2 + v3 * v3;
                    } else if (mr + 2 < P1) {
                        op[mr + 2] = v2; sS[nt] += v2; sSS[nt] += v2 * v2;
                    }
                } else if (mr < P1) {
                    op[mr] = v0; sS[nt] += v0; sSS[nt] += v0 * v0;
                }
            }
        }
    }
    #pragma unroll
    for (int nt = 0; nt < 2; ++nt) {
        sS[nt]  += __shfl_down(sS[nt], 32);
        sSS[nt] += __shfl_down(sSS[nt], 32);
    }
    __syncthreads();
    float* redS  = (float*)X8;
    float* redSS = redS + 256;
    if (lane < 32) {
        #pragma unroll
        for (int nt = 0; nt < 2; ++nt) {
            redS[wv * 64 + nt * 32 + l31]  = sS[nt];
            redSS[wv * 64 + nt * 32 + l31] = sSS[nt];
        }
    }
    __syncthreads();
    if (t < 64) {
        atomicAdd(&sto[t],      redS[t] + redS[64 + t] + redS[128 + t] + redS[192 + t]);
        atomicAdd(&sto[64 + t], redSS[t] + redSS[64 + t] + redSS[128 + t] + redSS[192 + t]);
    }
}

// ---------------------------------------------------------------------------
// lc: per-ch affine + relu on load, 3-tap conv -> 62ch, fused global stats
// ---------------------------------------------------------------------------
template <int POS>
__global__ __launch_bounds__(256) void k_lc(const float* __restrict__ in,
                                            const float* __restrict__ stp,
                                            const float* __restrict__ g,
                                            const float* __restrict__ be,
                                            float inv,
                                            const float* __restrict__ lcw,
                                            const float* __restrict__ lcb,
                                            float* __restrict__ out,
                                            float* __restrict__ sto) {
    __shared__ float sAff[128];
    __shared__ float sred[4], ssred[4];
    if (threadIdx.x < 64) {
        int tt = threadIdx.x;
        float mm = stp[tt] * inv;
        float vv = stp[64 + tt] * inv - mm * mm;
        float sc = g[tt] * rsqrtf(vv + EPSF);
        sAff[tt] = sc;
        sAff[64 + tt] = be[tt] - mm * sc;
    }
    __syncthreads();
    int morig = blockIdx.x * 256 + threadIdx.x;
    bool valid = morig < Bn * POS;
    int m = valid ? morig : Bn * POS - 1;
    int b = m / POS; int p = m - b * POS;
    const float* ip = in + (size_t)b * 64 * POS + p;
    float* op = out + (size_t)b * 62 * POS + p;
    float ts = 0.f, tss = 0.f;
    float y0 = fmaxf(sAff[0] * ip[0]           + sAff[64], 0.f);
    float y1 = fmaxf(sAff[1] * ip[(size_t)POS] + sAff[65], 0.f);
    for (int c = 0; c < 62; ++c) {
        float y2 = fmaxf(sAff[c + 2] * ip[(size_t)(c + 2) * POS] + sAff[64 + c + 2], 0.f);
        float o = lcb[c] + y0 * lcw[c * 3] + y1 * lcw[c * 3 + 1] + y2 * lcw[c * 3 + 2];
        op[(size_t)c * POS] = o;
        if (valid) { ts += o; tss += o * o; }
        y0 = y1; y1 = y2;
    }
    ts = wred(ts); tss = wred(tss);
    int wv = threadIdx.x >> 6, ln = threadIdx.x & 63;
    if (ln == 0) { sred[wv] = ts; ssred[wv] = tss; }
    __syncthreads();
    if (threadIdx.x == 0) {
        atomicAdd(&sto[0],  sred[0] + sred[1] + sred[2] + sred[3]);
        atomicAdd(&sto[64], ssred[0] + ssred[1] + ssred[2] + ssred[3]);
    }
}

// ---------------------------------------------------------------------------
// mix: scalar affine+relu, channel-mix 62->64, fused per-channel stats
// ---------------------------------------------------------------------------
template <int POS>
__global__ __launch_bounds__(256) void k_mix(const float* __restrict__ in,
                                             const float* __restrict__ stp,
                                             const float* __restrict__ g,
                                             const float* __restrict__ be,
                                             float inv,
                                             const float* __restrict__ Wm,
                                             const float* __restrict__ bm,
                                             float* __restrict__ out,
                                             float* __restrict__ sto) {
    __shared__ float redS[4][64], redSS[4][64];
    float mm = stp[0] * inv;
    float vv = stp[64] * inv - mm * mm;
    float s0 = g[0] * rsqrtf(vv + EPSF);
    float t0 = be[0] - mm * s0;

    int morig = blockIdx.x * 256 + threadIdx.x;
    bool valid = morig < Bn * POS;
    int m = valid ? morig : Bn * POS - 1;
    int b = m / POS; int p = m - b * POS;
    const float* ip = in + (size_t)b * 62 * POS + p;
    float z[62];
    #pragma unroll
    for (int d = 0; d < 62; ++d)
        z[d] = fmaxf(s0 * ip[(size_t)d * POS] + t0, 0.f);
    float* op = out + (size_t)b * 64 * POS + p;
    int lane = threadIdx.x & 63, wv = threadIdx.x >> 6;
    float myS = 0.f, mySS = 0.f;
    for (int c = 0; c < 64; ++c) {
        float acc = bm[c];
        #pragma unroll
        for (int d = 0; d < 62; ++d) acc += z[d] * Wm[c * 62 + d];
        op[(size_t)c * POS] = acc;
        float vvv = valid ? acc : 0.f;
        float sT  = bfly(vvv);
        float ssT = bfly(vvv * vvv);
        if (lane == c) { myS = sT; mySS = ssT; }
    }
    redS[wv][lane] = myS; redSS[wv][lane] = mySS;
    __syncthreads();
    if (threadIdx.x < 64) {
        int tt = threadIdx.x;
        atomicAdd(&sto[tt],      redS[0][tt] + redS[1][tt] + redS[2][tt] + redS[3][tt]);
        atomicAdd(&sto[64 + tt], redSS[0][tt] + redSS[1][tt] + redSS[2][tt] + redSS[3][tt]);
    }
}

// ---------------------------------------------------------------------------
// prep: fp32 [b][64][P] + affine(from stats) -> bf16 channel-last halves
// ---------------------------------------------------------------------------
template <int IH, int IW>
__global__ __launch_bounds__(256) void k_prep_in(const float* __restrict__ in,
                                                 const float* __restrict__ stp,
                                                 const float* __restrict__ g,
                                                 const float* __restrict__ be,
                                                 float inv,
                                                 __bf16* __restrict__ out) {
    constexpr int P = IH * IW;
    __shared__ float tile[64][65];
    const int b = blockIdx.y, p0 = blockIdx.x * 64;
    const int pl = threadIdx.x & 63, ch4 = threadIdx.x >> 6;
    #pragma unroll
    for (int i = 0; i < 16; ++i) {
        int c = i * 4 + ch4;
        int p = p0 + pl; if (p > P - 1) p = P - 1;
        tile[pl][c] = in[((size_t)b * 64 + c) * P + p];
    }
    __syncthreads();
    const int cl = threadIdx.x & 63;
    float mm = stp[cl] * inv;
    float vv = stp[64 + cl] * inv - mm * mm;
    float sc = g[cl] * rsqrtf(vv + EPSF);
    float sh = be[cl] - mm * sc;
    #pragma unroll
    for (int i = 0; i < 16; ++i) {
        int plocal = i * 4 + ch4;
        int p = p0 + plocal; if (p > P - 1) p = P - 1;
        int ih = p / IW, iw = p - ih * IW;
        float v = sc * tile[plocal][cl] + sh;
        out[(((size_t)b * IH + ih) * 2 + (cl >> 5)) * (IW * 32) + iw * 32 + (cl & 31)] = (__bf16)v;
    }
}

// ---------------------------------------------------------------------------
// implicit-GEMM conv, bf16 MFMA 32x32x16; M=512/block, proven swizzle,
// fused ch-stats
// ---------------------------------------------------------------------------
template <int KH, int KW, int IH, int IW, int OH, int OW, int NR>
__global__ __launch_bounds__(256, 2) void k_convmfma(
    const __bf16* __restrict__ in,
    const __bf16* __restrict__ wq,
    const float* __restrict__ bias,
    float* __restrict__ out,
    float* __restrict__ sto)
{
    constexpr int P = OH * OW;
    const int b  = blockIdx.y;
    const int m0 = blockIdx.x * 512;
    const int t  = threadIdx.x;
    const int lane = t & 63;
    const int wv = t >> 6;
    const int l31 = lane & 31, lh = lane >> 5;

    __shared__ __align__(16) __bf16 As[NR * IW * 32 + 64];

    const int oh_lo = m0 / OW;
    int posm[4];
    #pragma unroll
    for (int mt = 0; mt < 4; ++mt) {
        int m = m0 + wv * 128 + mt * 32 + l31;
        int mc = m > P - 1 ? P - 1 : m;
        int oh = mc / OW, ow = mc - oh * OW;
        posm[mt] = (oh - oh_lo) * IW + ow;
    }

    ffrag acc[4][2] = {};

    for (int ich = 0; ich < 2; ++ich) {
        __syncthreads();
        constexpr int ROWCH = IW * 4;
        constexpr int CH = NR * ROWCH;
        for (int idx = t; idx < CH; idx += 256) {
            int r = idx / ROWCH, o = idx - r * ROWCH;
            int ih = oh_lo + r; if (ih > IH - 1) ih = IH - 1;
            const __bf16* src = in + ((size_t)(b * IH + ih) * 2 + ich) * (IW * 32) + o * 8;
            int sw = idx ^ ((idx >> 2) & 7);       // proven bijective swizzle
            *(uint4*)&As[sw * 8] = *(const uint4*)src;
        }
        __syncthreads();

        const __bf16* wich = wq + ich * 2048;
        for (int kh = 0; kh < KH; ++kh) {
            const int rowoff = kh * IW;
            const __bf16* wkh = wich + (size_t)(kh * KW) * 4096 + lh * 512 + l31 * 8;
            #pragma unroll 1
            for (int kw = 0; kw < KW; ++kw) {
                const __bf16* wp = wkh + kw * 4096;
                #pragma unroll
                for (int cc = 0; cc < 2; ++cc) {
                    bfrag b0 = *(const bfrag*)(wp + cc * 1024);
                    bfrag b1 = *(const bfrag*)(wp + cc * 1024 + 256);
                    #pragma unroll
                    for (int mt = 0; mt < 4; ++mt) {
                        int X = posm[mt] + rowoff + kw;
                        int gc = (X << 2) + cc * 2 + lh;
                        bfrag a = *(const bfrag*)&As[(gc ^ (X & 7)) * 8];
                        acc[mt][0] = __builtin_amdgcn_mfma_f32_32x32x16_bf16(a, b0, acc[mt][0], 0, 0, 0);
                        acc[mt][1] = __builtin_amdgcn_mfma_f32_32x32x16_bf16(a, b1, acc[mt][1], 0, 0, 0);
                    }
                }
            }
        }
    }

    float sS[2] = {0.f, 0.f}, sSS[2] = {0.f, 0.f};
    #pragma unroll
    for (int nt = 0; nt < 2; ++nt) {
        int oc = nt * 32 + l31;
        float bv = bias[oc];
        float* op = out + ((size_t)b * 64 + oc) * P;
        #pragma unroll
        for (int mt = 0; mt < 4; ++mt) {
            int mbase = m0 + wv * 128 + mt * 32 + lh * 4;
            #pragma unroll
            for (int g = 0; g < 4; ++g) {
                int mr = mbase + g * 8;
                if (mr < P) {
                    float v0 = acc[mt][nt][g * 4 + 0] + bv;
                    float v1 = acc[mt][nt][g * 4 + 1] + bv;
                    *(float2*)(op + mr) = make_float2(v0, v1);
                    sS[nt] += v0 + v1; sSS[nt] += v0 * v0 + v1 * v1;
                    if (mr + 2 < P) {
                        float v2 = acc[mt][nt][g * 4 + 2] + bv;
                        float v3 = acc[mt][nt][g * 4 + 3] + bv;
                        *(float2*)(op + mr + 2) = make_float2(v2, v3);
                        sS[nt] += v2 + v3; sSS[nt] += v2 * v2 + v3 * v3;
                    }
                }
            }
        }
    }
    #pragma unroll
    for (int nt = 0; nt < 2; ++nt) {
        sS[nt]  += __shfl_down(sS[nt], 32);
        sSS[nt] += __shfl_down(sSS[nt], 32);
    }
    __syncthreads();
    float* redS  = (float*)As;
    float* redSS = redS + 256;
    if (lane < 32) {
        #pragma unroll
        for (int nt = 0; nt < 2; ++nt) {
            redS[wv * 64 + nt * 32 + l31]  = sS[nt];
            redSS[wv * 64 + nt * 32 + l31] = sSS[nt];
        }
    }
    __syncthreads();
    if (t < 64) {
        atomicAdd(&sto[t],      redS[t] + redS[64 + t] + redS[128 + t] + redS[192 + t]);
        atomicAdd(&sto[64 + t], redSS[t] + redSS[64 + t] + redSS[128 + t] + redSS[192 + t]);
    }
}

// ---------------------------------------------------------------------------
// FC head
// ---------------------------------------------------------------------------
__global__ __launch_bounds__(256) void k_transpose(const float* __restrict__ in,
                                                   const float* __restrict__ stp,
                                                   const float* __restrict__ g,
                                                   const float* __restrict__ be,
                                                   float inv,
                                                   float* __restrict__ hT) {
    __shared__ float tile[32][33];
    int j0 = blockIdx.x * 32, b0 = blockIdx.y * 32;
    int lo = threadIdx.x & 31, hi = threadIdx.x >> 5;
    int c  = (j0 + lo) / P3;
    float mm = stp[c] * inv;
    float vv = stp[64 + c] * inv - mm * mm;
    float sc = g[c] * rsqrtf(vv + EPSF);
    float sh = be[c] - mm * sc;
    #pragma unroll
    for (int tt = 0; tt < 4; ++tt) {
        int bl = tt * 8 + hi;
        tile[bl][lo] = sc * in[(size_t)(b0 + bl) * KFC + (j0 + lo)] + sh;
    }
    __syncthreads();
    #pragma unroll
    for (int tt = 0; tt < 4; ++tt) {
        int jl = tt * 8 + hi;
        hT[(size_t)(j0 + jl) * Bn + b0 + lo] = tile[lo][jl];
    }
}

__global__ __launch_bounds__(256) void k_fc1(const float* __restrict__ hT,
                                             const float* __restrict__ Wf1,
                                             float* __restrict__ Pb) {
    int lane = threadIdx.x & 63;
    int f0 = __builtin_amdgcn_readfirstlane((threadIdx.x >> 6) * 16);
    int b  = blockIdx.y * 64 + lane;
    int kc = blockIdx.x;
    int k0 = kc * FCKL;
    float acc[16] = {};
    for (int k = k0; k < k0 + FCKL; ++k) {
        float hv = hT[(size_t)k * Bn + b];
        #pragma unroll
        for (int f = 0; f < 16; ++f)
            acc[f] += hv * Wf1[(size_t)(f0 + f) * KFC + k];
    }
    float* pp = Pb + (size_t)kc * 8192 + (size_t)b * 64 + f0;
    #pragma unroll
    for (int f = 0; f < 16; ++f) pp[f] = acc[f];
}

__global__ __launch_bounds__(256) void k_fc1red(const float* __restrict__ Pb,
                                                float* __restrict__ F) {
    int m = blockIdx.x * 256 + threadIdx.x;   // 8192
    float s = 0.f;
    for (int kc = 0; kc < FCCH; ++kc) s += Pb[(size_t)kc * 8192 + m];
    F[m] = s;
}

// batch-BN + relu + fc2, single block (F is 32 KB -> LDS)
__global__ __launch_bounds__(256) void k_fcfin(const float* __restrict__ F,
                                               const float* __restrict__ bf1,
                                               const float* __restrict__ gf,
                                               const float* __restrict__ bef,
                                               const float* __restrict__ Wf2,
                                               const float* __restrict__ bf2,
                                               float* __restrict__ out) {
    __shared__ float sF[8192];
    __shared__ float sfa[128];
    const int t = threadIdx.x;
    for (int m = t; m < 8192; m += 256) sF[m] = F[m];
    __syncthreads();
    if (t < 64) {
        float s = 0.f, ss = 0.f;
        for (int b = 0; b < Bn; ++b) {
            float v = sF[b * 64 + t] + bf1[t];
            s += v; ss += v * v;
        }
        float m  = s / 128.f;
        float va = ss / 128.f - m * m;
        float sc = gf[t] * rsqrtf(va + EPSF);
        sfa[t] = sc;
        sfa[64 + t] = sc * bf1[t] + bef[t] - m * sc;   // folded bf1
    }
    __syncthreads();
    for (int m = t; m < Bn * 35; m += 256) {
        int b = m / 35, o = m - b * 35;
        float acc = bf2[o];
        for (int ff = 0; ff < 64; ++ff) {
            int f = (ff + t) & 63;
            float z = fmaxf(sfa[f] * sF[b * 64 + f] + sfa[64 + f], 0.f);
            acc += z * Wf2[o * 64 + f];
        }
        out[m] = acc;
    }
}

// ---------------------------------------------------------------------------
// launch
// ---------------------------------------------------------------------------
extern "C" void kernel_launch(void* const* d_in, const int* in_sizes, int n_in,
                              void* d_out, int out_size, void* d_ws, size_t ws_size,
                              hipStream_t stream) {
    const float* x    = (const float*)d_in[0];
    const float* W11  = (const float*)d_in[1];
    const float* b11  = (const float*)d_in[2];
    const float* g11  = (const float*)d_in[3];
    const float* be11 = (const float*)d_in[4];
    const float* lc1w = (const float*)d_in[5];
    const float* lc1b = (const float*)d_in[6];
    const float* g12  = (const float*)d_in[7];
    const float* be12 = (const float*)d_in[8];
    const float* W13  = (const float*)d_in[9];
    const float* b13  = (const float*)d_in[10];
    const float* g13  = (const float*)d_in[11];
    const float* be13 = (const float*)d_in[12];
    const float* W21  = (const float*)d_in[13];
    const float* b21  = (const float*)d_in[14];
    const float* g21  = (const float*)d_in[15];
    const float* be21 = (const float*)d_in[16];
    const float* lc2w = (const float*)d_in[17];
    const float* lc2b = (const float*)d_in[18];
    const float* g22  = (const float*)d_in[19];
    const float* be22 = (const float*)d_in[20];
    const float* W23  = (const float*)d_in[21];
    const float* b23  = (const float*)d_in[22];
    const float* g23  = (const float*)d_in[23];
    const float* be23 = (const float*)d_in[24];
    const float* W31  = (const float*)d_in[25];
    const float* b31  = (const float*)d_in[26];
    const float* g31  = (const float*)d_in[27];
    const float* be31 = (const float*)d_in[28];
    const float* lc3w = (const float*)d_in[29];
    const float* lc3b = (const float*)d_in[30];
    const float* g32  = (const float*)d_in[31];
    const float* be32 = (const float*)d_in[32];
    const float* W33  = (const float*)d_in[33];
    const float* b33  = (const float*)d_in[34];
    const float* g33  = (const float*)d_in[35];
    const float* be33 = (const float*)d_in[36];
    const float* Wf1  = (const float*)d_in[37];
    const float* bf1  = (const float*)d_in[38];
    const float* gf   = (const float*)d_in[39];
    const float* bef  = (const float*)d_in[40];
    const float* Wf2  = (const float*)d_in[41];
    const float* bf2  = (const float*)d_in[42];

    float* ws  = (float*)d_ws;
    float* A   = ws + oA;
    float* Bb  = ws + oB;
    __bf16* Bcl = (__bf16*)(ws + oB);
    __bf16* wq2 = (__bf16*)(ws + oW2);
    __bf16* wq3 = (__bf16*)(ws + oW3);
    __bf16* wq1 = (__bf16*)(ws + oW1);
    float* Pb  = ws + oP;
    float* st  = ws + oSt;
    float* F   = ws + oF;

    const int blk1 = (M1 + 255) / 256;
    const int blk2 = M2 / 256;
    const int blk3 = M3 / 256;

    k_prep_all<<<(NPREP + 255) / 256, 256, 0, stream>>>(W11, W21, W31, wq1, wq2, wq3, st);

    // ---- stage 1 ----
    k_conv1m<<<dim3((P1 + 511) / 512, Bn), 256, 0, stream>>>(x, wq1, b11, A, st + 0 * 128);
    k_lc<P1><<<blk1, 256, 0, stream>>>(A, st + 0 * 128, g11, be11, 1.0f / (float)M1,
                                       lc1w, lc1b, Bb, st + 1 * 128);
    k_mix<P1><<<blk1, 256, 0, stream>>>(Bb, st + 1 * 128, g12, be12, 1.0f / (62.0f * (float)M1),
                                        W13, b13, A, st + 2 * 128);

    // ---- stage 2 ----
    k_prep_in<H1, Wo1><<<dim3((P1 + 63) / 64, Bn), 256, 0, stream>>>(
        A, st + 2 * 128, g13, be13, 1.0f / (float)M1, Bcl);
    k_convmfma<KH2, KW2, H1, Wo1, H2, Wo2, 35>
        <<<dim3((P2 + 511) / 512, Bn), 256, 0, stream>>>(Bcl, wq2, b21, A, st + 3 * 128);
    k_lc<P2><<<blk2, 256, 0, stream>>>(A, st + 3 * 128, g21, be21, 1.0f / (float)M2,
                                       lc2w, lc2b, Bb, st + 4 * 128);
    k_mix<P2><<<blk2, 256, 0, stream>>>(Bb, st + 4 * 128, g22, be22, 1.0f / (62.0f * (float)M2),
                                        W23, b23, A, st + 5 * 128);

    // ---- stage 3 ----
    k_prep_in<H2, Wo2><<<dim3((P2 + 63) / 64, Bn), 256, 0, stream>>>(
        A, st + 5 * 128, g23, be23, 1.0f / (float)M2, Bcl);
    k_convmfma<KH3, KW3, H2, Wo2, H3, Wo3, 37>
        <<<dim3((P3 + 511) / 512, Bn), 256, 0, stream>>>(Bcl, wq3, b31, A, st + 6 * 128);
    k_lc<P3><<<blk3, 256, 0, stream>>>(A, st + 6 * 128, g31, be31, 1.0f / (float)M3,
                                       lc3w, lc3b, Bb, st + 7 * 128);
    k_mix<P3><<<blk3, 256, 0, stream>>>(Bb, st + 7 * 128, g32, be32, 1.0f / (62.0f * (float)M3),
                                        W33, b33, A, st + 8 * 128);

    // ---- FC head ----
    k_transpose<<<dim3(KFC / 32, Bn / 32), 256, 0, stream>>>(
        A, st + 8 * 128, g33, be33, 1.0f / (float)M3, Bb);
    k_fc1<<<dim3(FCCH, 2), 256, 0, stream>>>(Bb, Wf1, Pb);
    k_fc1red<<<32, 256, 0, stream>>>(Pb, F);
    k_fcfin<<<1, 256, 0, stream>>>(F, bf1, gf, bef, Wf2, bf2, (float*)d_out);
}

// Round 8
// 1068.276 us; speedup vs baseline: 2.1194x; 1.1439x over previous
//
#include <hip/hip_runtime.h>

typedef __bf16 bfrag __attribute__((ext_vector_type(8)));
typedef float ffrag __attribute__((ext_vector_type(16)));

// ---------------------------------------------------------------------------
// Shapes / constants
// ---------------------------------------------------------------------------
constexpr int Bn  = 128;
constexpr int H0  = 98, Wi0 = 40;
constexpr int KH1 = 20, KW1 = 8, H1 = 79, Wo1 = 33, P1 = H1 * Wo1;   // 2607
constexpr int KH2 = 15, KW2 = 8, H2 = 65, Wo2 = 26, P2 = H2 * Wo2;   // 1690
constexpr int KH3 = 10, KW3 = 8, H3 = 56, Wo3 = 19, P3 = H3 * Wo3;   // 1064
constexpr int M1  = Bn * P1;
constexpr int M2  = Bn * P2;
constexpr int M3  = Bn * P3;
constexpr int KFC = 64 * P3;   // 68096
constexpr int FCCH = 128;
constexpr int FCKL = KFC / FCCH;   // 532
constexpr float EPSF = 1e-5f;

// ---------------------------------------------------------------------------
// Workspace layout (float slots)
// ---------------------------------------------------------------------------
constexpr size_t oA  = 0;
constexpr size_t oB  = oA  + (size_t)Bn * 64 * P1;          // 21,356,544
constexpr size_t oW2 = oB  + (size_t)Bn * 62 * P1;          // wq2f (245,760 fl)
constexpr size_t oW3 = oW2 + 245760;                        // wq3f (163,840 fl)
constexpr size_t oW1 = oW3 + 163840;                        // wq1 (5,120 fl)
constexpr size_t oWM = oW1 + 5120;                          // wqm1/2/3 (3x2048 fl)
constexpr size_t oBF = oWM + 6144;                          // b21f(64) + b31f(64)
constexpr size_t oP  = oBF + 128;                           // Pb (128x8192)
constexpr size_t oSt = oP  + (size_t)FCCH * 8192;           // stats 9x128
constexpr size_t oF  = oSt + 9 * 128;                       // fc1 out (8192)

__device__ __forceinline__ float wred(float v) {
    #pragma unroll
    for (int o = 32; o > 0; o >>= 1) v += __shfl_down(v, o);
    return v;
}

// ---------------------------------------------------------------------------
// prep: zero stats + pack wq1 + pack mix matrices (62->64, zero-padded)
// ---------------------------------------------------------------------------
constexpr int NZ  = 9 * 128;
constexpr int NW1 = 10240;
constexpr int NWM = 3 * 4096;
constexpr int NPREP = NZ + NW1 + NWM;
__global__ __launch_bounds__(256) void k_prep_all(
    const float* __restrict__ W11, const float* __restrict__ W13,
    const float* __restrict__ W23, const float* __restrict__ W33,
    __bf16* __restrict__ wq1, __bf16* __restrict__ wqm,
    float* __restrict__ st)
{
    int idx = blockIdx.x * 256 + threadIdx.x;
    if (idx < NZ) { st[idx] = 0.f; return; }
    idx -= NZ;
    if (idx < NW1) {
        int j = idx & 7, oc = (idx >> 3) & 63, khh = idx >> 9;
        wq1[idx] = (__bf16)W11[(size_t)oc * 160 + khh * 8 + j];
        return;
    }
    idx -= NW1;
    if (idx < NWM) {
        int which = idx >> 12, r = idx & 4095;
        int j = r & 7, oc = (r >> 3) & 63, sub = (r >> 9) & 1, ks = r >> 10;
        int k = ks * 16 + sub * 8 + j;
        const float* Wm = which == 0 ? W13 : (which == 1 ? W23 : W33);
        wqm[idx] = (k < 62) ? (__bf16)Wm[oc * 62 + k] : (__bf16)0.f;
    }
}

// ---------------------------------------------------------------------------
// fold BN affine into conv weights: wqf = pack(W * scale[ic]); biasf = bias +
// sum W*shift[ic].  One block per oc.
// ---------------------------------------------------------------------------
template <int KH, int KW>
__global__ __launch_bounds__(256) void k_foldw(
    const float* __restrict__ W, const float* __restrict__ stp,
    const float* __restrict__ g, const float* __restrict__ be,
    float inv, const float* __restrict__ bias,
    __bf16* __restrict__ wqf, float* __restrict__ biasf)
{
    constexpr int KK = KH * KW;
    __shared__ float sSc[64], sSh[64], ls[4];
    const int t = threadIdx.x;
    if (t < 64) {
        float mm = stp[t] * inv;
        float vv = stp[64 + t] * inv - mm * mm;
        float sc = g[t] * rsqrtf(vv + EPSF);
        sSc[t] = sc;
        sSh[t] = be[t] - mm * sc;
    }
    __syncthreads();
    const int oc = blockIdx.x;
    float local = 0.f;
    for (int i = t; i < 64 * KK; i += 256) {
        int ic = i / KK, rem = i - ic * KK;
        int kh = rem / KW, kw = rem - kh * KW;
        float wv = W[(((size_t)oc * 64 + ic) * KH + kh) * KW + kw];
        int c = ic >> 4, sub = (ic >> 3) & 1, j = ic & 7, pos = kh * KW + kw;
        wqf[(size_t)pos * 4096 + c * 1024 + sub * 512 + oc * 8 + j] = (__bf16)(wv * sSc[ic]);
        local += wv * sSh[ic];
    }
    local = wred(local);
    int wv2 = t >> 6, ln = t & 63;
    if (ln == 0) ls[wv2] = local;
    __syncthreads();
    if (t == 0) biasf[oc] = bias[oc] + ls[0] + ls[1] + ls[2] + ls[3];
}

// ---------------------------------------------------------------------------
// conv1 MFMA (unchanged): x (128,1,98,40) -> A fp32 [b][64][P1], fused stats
// ---------------------------------------------------------------------------
constexpr int C1COPY = 1736;
__global__ __launch_bounds__(256, 2) void k_conv1m(
    const float* __restrict__ x, const __bf16* __restrict__ wq,
    const float* __restrict__ bias, float* __restrict__ out,
    float* __restrict__ sto)
{
    const int b = blockIdx.y;
    const int m0 = blockIdx.x * 512;
    const int t = threadIdx.x, lane = t & 63, wv = t >> 6;
    const int l31 = lane & 31, lh = lane >> 5;
    __shared__ __align__(16) __bf16 X8[8 * C1COPY];

    const int oh_lo = m0 / Wo1;
    int abase[4];
    #pragma unroll
    for (int mt = 0; mt < 4; ++mt) {
        int m = m0 + wv * 128 + mt * 32 + l31;
        int mc = m > P1 - 1 ? P1 - 1 : m;
        int oh = mc / Wo1, ow = mc - oh * Wo1;
        int s = ow & 7;
        abase[mt] = s * C1COPY + (oh - oh_lo) * 48 + (ow - s);
    }
    for (int idx = t; idx < 8 * 36 * 6; idx += 256) {
        int s = idx / 216; int rr = idx - s * 216;
        int r = rr / 6, q = rr - r * 6;
        int ih = oh_lo + r; if (ih > H0 - 1) ih = H0 - 1;
        const float* src = x + ((size_t)b * H0 + ih) * Wi0;
        __bf16 tmp[8] __attribute__((aligned(16)));
        #pragma unroll
        for (int j = 0; j < 8; ++j) {
            int col = q * 8 + s + j; if (col > Wi0 - 1) col = Wi0 - 1;
            tmp[j] = (__bf16)src[col];
        }
        *(uint4*)&X8[s * C1COPY + r * 48 + q * 8] = *(uint4*)tmp;
    }
    __syncthreads();

    ffrag acc[4][2] = {};
    #pragma unroll 1
    for (int st2 = 0; st2 < 10; ++st2) {
        const int khl = st2 * 2 + lh;
        const __bf16* wp = wq + ((size_t)khl * 64 + l31) * 8;
        bfrag b0 = *(const bfrag*)(wp);
        bfrag b1 = *(const bfrag*)(wp + 256);
        #pragma unroll
        for (int mt = 0; mt < 4; ++mt) {
            bfrag a = *(const bfrag*)&X8[abase[mt] + khl * 48];
            acc[mt][0] = __builtin_amdgcn_mfma_f32_32x32x16_bf16(a, b0, acc[mt][0], 0, 0, 0);
            acc[mt][1] = __builtin_amdgcn_mfma_f32_32x32x16_bf16(a, b1, acc[mt][1], 0, 0, 0);
        }
    }

    float sS[2] = {0.f, 0.f}, sSS[2] = {0.f, 0.f};
    #pragma unroll
    for (int nt = 0; nt < 2; ++nt) {
        int oc = nt * 32 + l31;
        float bv = bias[oc];
        float* op = out + ((size_t)b * 64 + oc) * P1;
        #pragma unroll
        for (int mt = 0; mt < 4; ++mt) {
            int mbase = m0 + wv * 128 + mt * 32 + lh * 4;
            #pragma unroll
            for (int g = 0; g < 4; ++g) {
                int mr = mbase + g * 8;
                float v0 = acc[mt][nt][g * 4 + 0] + bv;
                float v1 = acc[mt][nt][g * 4 + 1] + bv;
                float v2 = acc[mt][nt][g * 4 + 2] + bv;
                float v3 = acc[mt][nt][g * 4 + 3] + bv;
                if (mr + 1 < P1) {
                    *(float2*)(op + mr) = make_float2(v0, v1);
                    sS[nt] += v0 + v1; sSS[nt] += v0 * v0 + v1 * v1;
                    if (mr + 3 < P1) {
                        *(float2*)(op + mr + 2) = make_float2(v2, v3);
                        sS[nt] += v2 + v3; sSS[nt] += v2 * v2 + v3 * v3;
                    } else if (mr + 2 < P1) {
                        op[mr + 2] = v2; sS[nt] += v2; sSS[nt] += v2 * v2;
                    }
                } else if (mr < P1) {
                    op[mr] = v0; sS[nt] += v0; sSS[nt] += v0 * v0;
                }
            }
        }
    }
    #pragma unroll
    for (int nt = 0; nt < 2; ++nt) {
        sS[nt]  += __shfl_down(sS[nt], 32);
        sSS[nt] += __shfl_down(sSS[nt], 32);
    }
    __syncthreads();
    float* redS  = (float*)X8;
    float* redSS = redS + 256;
    if (lane < 32) {
        #pragma unroll
        for (int nt = 0; nt < 2; ++nt) {
            redS[wv * 64 + nt * 32 + l31]  = sS[nt];
            redSS[wv * 64 + nt * 32 + l31] = sSS[nt];
        }
    }
    __syncthreads();
    if (t < 64) {
        atomicAdd(&sto[t],      redS[t] + redS[64 + t] + redS[128 + t] + redS[192 + t]);
        atomicAdd(&sto[64 + t], redSS[t] + redSS[64 + t] + redSS[128 + t] + redSS[192 + t]);
    }
}

// ---------------------------------------------------------------------------
// lc: per-ch affine + relu on load, 3-tap conv -> bf16 channel-last Z[m][64]
// (channels 62,63 zero), fused global stats
// ---------------------------------------------------------------------------
template <int POS>
__global__ __launch_bounds__(256) void k_lc(const float* __restrict__ in,
                                            const float* __restrict__ stp,
                                            const float* __restrict__ g,
                                            const float* __restrict__ be,
                                            float inv,
                                            const float* __restrict__ lcw,
                                            const float* __restrict__ lcb,
                                            __bf16* __restrict__ Z,
                                            float* __restrict__ sto) {
    __shared__ float sAff[128];
    __shared__ float sred[4], ssred[4];
    if (threadIdx.x < 64) {
        int tt = threadIdx.x;
        float mm = stp[tt] * inv;
        float vv = stp[64 + tt] * inv - mm * mm;
        float sc = g[tt] * rsqrtf(vv + EPSF);
        sAff[tt] = sc;
        sAff[64 + tt] = be[tt] - mm * sc;
    }
    __syncthreads();
    int morig = blockIdx.x * 256 + threadIdx.x;
    bool valid = morig < Bn * POS;
    int m = valid ? morig : Bn * POS - 1;
    int b = m / POS; int p = m - b * POS;
    const float* ip = in + (size_t)b * 64 * POS + p;
    __bf16 zb[64] __attribute__((aligned(16)));
    zb[62] = (__bf16)0.f; zb[63] = (__bf16)0.f;
    float ts = 0.f, tss = 0.f;
    float y0 = fmaxf(sAff[0] * ip[0]           + sAff[64], 0.f);
    float y1 = fmaxf(sAff[1] * ip[(size_t)POS] + sAff[65], 0.f);
    for (int c = 0; c < 62; ++c) {
        float y2 = fmaxf(sAff[c + 2] * ip[(size_t)(c + 2) * POS] + sAff[64 + c + 2], 0.f);
        float o = lcb[c] + y0 * lcw[c * 3] + y1 * lcw[c * 3 + 1] + y2 * lcw[c * 3 + 2];
        zb[c] = (__bf16)o;
        if (valid) { ts += o; tss += o * o; }
        y0 = y1; y1 = y2;
    }
    __bf16* zp = Z + (size_t)m * 64;
    #pragma unroll
    for (int j = 0; j < 8; ++j)
        *(uint4*)(zp + j * 8) = *(uint4*)(zb + j * 8);
    ts = wred(ts); tss = wred(tss);
    int wv = threadIdx.x >> 6, ln = threadIdx.x & 63;
    if (ln == 0) { sred[wv] = ts; ssred[wv] = tss; }
    __syncthreads();
    if (threadIdx.x == 0) {
        atomicAdd(&sto[0],  sred[0] + sred[1] + sred[2] + sred[3]);
        atomicAdd(&sto[64], ssred[0] + ssred[1] + ssred[2] + ssred[3]);
    }
}

// ---------------------------------------------------------------------------
// mix as MFMA: Z[m][64] bf16 (pre-bn_all) -> scalar affine+relu in-register ->
// 62->64 matmul (+bm) -> out. OUTBF: bf16 conv-layout; else fp32 [b][64][POS].
// Fused per-channel stats.
// ---------------------------------------------------------------------------
template <int POS, int IH, int IW, bool OUTBF>
__global__ __launch_bounds__(256, 2) void k_mixm(
    const __bf16* __restrict__ Z, const float* __restrict__ stp,
    const float* __restrict__ g, const float* __restrict__ be,
    float inv, const __bf16* __restrict__ wqm,
    const float* __restrict__ bm, void* __restrict__ outv,
    float* __restrict__ sto)
{
    const int b = blockIdx.y;
    const int m0 = blockIdx.x * 512;
    const int t = threadIdx.x, lane = t & 63, wv = t >> 6;
    const int l31 = lane & 31, lh = lane >> 5;

    float mm = stp[0] * inv;
    float vv = stp[64] * inv - mm * mm;
    float s0 = g[0] * rsqrtf(vv + EPSF);
    float t0 = be[0] - mm * s0;

    size_t zbase[4];
    #pragma unroll
    for (int mt = 0; mt < 4; ++mt) {
        int m = m0 + wv * 128 + mt * 32 + l31;
        int mc = m > POS - 1 ? POS - 1 : m;
        zbase[mt] = ((size_t)b * POS + mc) * 64;
    }

    ffrag acc[4][2] = {};
    #pragma unroll
    for (int ks = 0; ks < 4; ++ks) {
        const __bf16* wp = wqm + ks * 1024 + lh * 512 + l31 * 8;
        bfrag b0 = *(const bfrag*)wp;
        bfrag b1 = *(const bfrag*)(wp + 256);
        #pragma unroll
        for (int mt = 0; mt < 4; ++mt) {
            uint4 raw = *(const uint4*)(Z + zbase[mt] + ks * 16 + lh * 8);
            const __bf16* zin = (const __bf16*)&raw;
            __bf16 zout[8] __attribute__((aligned(16)));
            #pragma unroll
            for (int j = 0; j < 8; ++j) {
                float f = (float)zin[j];
                zout[j] = (__bf16)fmaxf(fmaf(s0, f, t0), 0.f);
            }
            bfrag a = *(const bfrag*)zout;
            acc[mt][0] = __builtin_amdgcn_mfma_f32_32x32x16_bf16(a, b0, acc[mt][0], 0, 0, 0);
            acc[mt][1] = __builtin_amdgcn_mfma_f32_32x32x16_bf16(a, b1, acc[mt][1], 0, 0, 0);
        }
    }

    float sS[2] = {0.f, 0.f}, sSS[2] = {0.f, 0.f};
    #pragma unroll
    for (int nt = 0; nt < 2; ++nt) {
        int oc = nt * 32 + l31;
        float bv = bm[oc];
        if constexpr (OUTBF) {
            __bf16* op = (__bf16*)outv;
            #pragma unroll
            for (int mt = 0; mt < 4; ++mt) {
                int mbase = m0 + wv * 128 + mt * 32 + lh * 4;
                #pragma unroll
                for (int g4 = 0; g4 < 4; ++g4) {
                    #pragma unroll
                    for (int q = 0; q < 4; ++q) {
                        int mr = mbase + g4 * 8 + q;
                        if (mr < POS) {
                            float v = acc[mt][nt][g4 * 4 + q] + bv;
                            int ih = mr / IW, iw = mr - ih * IW;
                            op[((size_t)(b * IH + ih) * 2 + nt) * (IW * 32) + iw * 32 + l31] = (__bf16)v;
                            sS[nt] += v; sSS[nt] += v * v;
                        }
                    }
                }
            }
        } else {
            float* op = (float*)outv + ((size_t)b * 64 + oc) * POS;
            #pragma unroll
            for (int mt = 0; mt < 4; ++mt) {
                int mbase = m0 + wv * 128 + mt * 32 + lh * 4;
                #pragma unroll
                for (int g4 = 0; g4 < 4; ++g4) {
                    int mr = mbase + g4 * 8;
                    if (mr < POS) {
                        float v0 = acc[mt][nt][g4 * 4 + 0] + bv;
                        float v1 = acc[mt][nt][g4 * 4 + 1] + bv;
                        *(float2*)(op + mr) = make_float2(v0, v1);
                        sS[nt] += v0 + v1; sSS[nt] += v0 * v0 + v1 * v1;
                        if (mr + 2 < POS) {
                            float v2 = acc[mt][nt][g4 * 4 + 2] + bv;
                            float v3 = acc[mt][nt][g4 * 4 + 3] + bv;
                            *(float2*)(op + mr + 2) = make_float2(v2, v3);
                            sS[nt] += v2 + v3; sSS[nt] += v2 * v2 + v3 * v3;
                        }
                    }
                }
            }
        }
    }
    #pragma unroll
    for (int nt = 0; nt < 2; ++nt) {
        sS[nt]  += __shfl_down(sS[nt], 32);
        sSS[nt] += __shfl_down(sSS[nt], 32);
    }
    __shared__ float red[512];
    if (lane < 32) {
        #pragma unroll
        for (int nt = 0; nt < 2; ++nt) {
            red[wv * 64 + nt * 32 + l31]       = sS[nt];
            red[256 + wv * 64 + nt * 32 + l31] = sSS[nt];
        }
    }
    __syncthreads();
    if (t < 64) {
        atomicAdd(&sto[t],      red[t] + red[64 + t] + red[128 + t] + red[192 + t]);
        atomicAdd(&sto[64 + t], red[256 + t] + red[320 + t] + red[384 + t] + red[448 + t]);
    }
}

// ---------------------------------------------------------------------------
// implicit-GEMM conv (unchanged): bf16 MFMA 32x32x16, M=512/block, swizzled
// ---------------------------------------------------------------------------
template <int KH, int KW, int IH, int IW, int OH, int OW, int NR>
__global__ __launch_bounds__(256, 2) void k_convmfma(
    const __bf16* __restrict__ in,
    const __bf16* __restrict__ wq,
    const float* __restrict__ bias,
    float* __restrict__ out,
    float* __restrict__ sto)
{
    constexpr int P = OH * OW;
    const int b  = blockIdx.y;
    const int m0 = blockIdx.x * 512;
    const int t  = threadIdx.x;
    const int lane = t & 63;
    const int wv = t >> 6;
    const int l31 = lane & 31, lh = lane >> 5;

    __shared__ __align__(16) __bf16 As[NR * IW * 32 + 64];

    const int oh_lo = m0 / OW;
    int posm[4];
    #pragma unroll
    for (int mt = 0; mt < 4; ++mt) {
        int m = m0 + wv * 128 + mt * 32 + l31;
        int mc = m > P - 1 ? P - 1 : m;
        int oh = mc / OW, ow = mc - oh * OW;
        posm[mt] = (oh - oh_lo) * IW + ow;
    }

    ffrag acc[4][2] = {};

    for (int ich = 0; ich < 2; ++ich) {
        __syncthreads();
        constexpr int ROWCH = IW * 4;
        constexpr int CH = NR * ROWCH;
        for (int idx = t; idx < CH; idx += 256) {
            int r = idx / ROWCH, o = idx - r * ROWCH;
            int ih = oh_lo + r; if (ih > IH - 1) ih = IH - 1;
            const __bf16* src = in + ((size_t)(b * IH + ih) * 2 + ich) * (IW * 32) + o * 8;
            int sw = idx ^ ((idx >> 2) & 7);
            *(uint4*)&As[sw * 8] = *(const uint4*)src;
        }
        __syncthreads();

        const __bf16* wich = wq + ich * 2048;
        for (int kh = 0; kh < KH; ++kh) {
            const int rowoff = kh * IW;
            const __bf16* wkh = wich + (size_t)(kh * KW) * 4096 + lh * 512 + l31 * 8;
            #pragma unroll 1
            for (int kw = 0; kw < KW; ++kw) {
                const __bf16* wp = wkh + kw * 4096;
                #pragma unroll
                for (int cc = 0; cc < 2; ++cc) {
                    bfrag b0 = *(const bfrag*)(wp + cc * 1024);
                    bfrag b1 = *(const bfrag*)(wp + cc * 1024 + 256);
                    #pragma unroll
                    for (int mt = 0; mt < 4; ++mt) {
                        int X = posm[mt] + rowoff + kw;
                        int gc = (X << 2) + cc * 2 + lh;
                        bfrag a = *(const bfrag*)&As[(gc ^ (X & 7)) * 8];
                        acc[mt][0] = __builtin_amdgcn_mfma_f32_32x32x16_bf16(a, b0, acc[mt][0], 0, 0, 0);
                        acc[mt][1] = __builtin_amdgcn_mfma_f32_32x32x16_bf16(a, b1, acc[mt][1], 0, 0, 0);
                    }
                }
            }
        }
    }

    float sS[2] = {0.f, 0.f}, sSS[2] = {0.f, 0.f};
    #pragma unroll
    for (int nt = 0; nt < 2; ++nt) {
        int oc = nt * 32 + l31;
        float bv = bias[oc];
        float* op = out + ((size_t)b * 64 + oc) * P;
        #pragma unroll
        for (int mt = 0; mt < 4; ++mt) {
            int mbase = m0 + wv * 128 + mt * 32 + lh * 4;
            #pragma unroll
            for (int g = 0; g < 4; ++g) {
                int mr = mbase + g * 8;
                if (mr < P) {
                    float v0 = acc[mt][nt][g * 4 + 0] + bv;
                    float v1 = acc[mt][nt][g * 4 + 1] + bv;
                    *(float2*)(op + mr) = make_float2(v0, v1);
                    sS[nt] += v0 + v1; sSS[nt] += v0 * v0 + v1 * v1;
                    if (mr + 2 < P) {
                        float v2 = acc[mt][nt][g * 4 + 2] + bv;
                        float v3 = acc[mt][nt][g * 4 + 3] + bv;
                        *(float2*)(op + mr + 2) = make_float2(v2, v3);
                        sS[nt] += v2 + v3; sSS[nt] += v2 * v2 + v3 * v3;
                    }
                }
            }
        }
    }
    #pragma unroll
    for (int nt = 0; nt < 2; ++nt) {
        sS[nt]  += __shfl_down(sS[nt], 32);
        sSS[nt] += __shfl_down(sSS[nt], 32);
    }
    __syncthreads();
    float* redS  = (float*)As;
    float* redSS = redS + 256;
    if (lane < 32) {
        #pragma unroll
        for (int nt = 0; nt < 2; ++nt) {
            redS[wv * 64 + nt * 32 + l31]  = sS[nt];
            redSS[wv * 64 + nt * 32 + l31] = sSS[nt];
        }
    }
    __syncthreads();
    if (t < 64) {
        atomicAdd(&sto[t],      redS[t] + redS[64 + t] + redS[128 + t] + redS[192 + t]);
        atomicAdd(&sto[64 + t], redSS[t] + redSS[64 + t] + redSS[128 + t] + redSS[192 + t]);
    }
}

// ---------------------------------------------------------------------------
// FC head (unchanged)
// ---------------------------------------------------------------------------
__global__ __launch_bounds__(256) void k_transpose(const float* __restrict__ in,
                                                   const float* __restrict__ stp,
                                                   const float* __restrict__ g,
                                                   const float* __restrict__ be,
                                                   float inv,
                                                   float* __restrict__ hT) {
    __shared__ float tile[32][33];
    int j0 = blockIdx.x * 32, b0 = blockIdx.y * 32;
    int lo = threadIdx.x & 31, hi = threadIdx.x >> 5;
    int c  = (j0 + lo) / P3;
    float mm = stp[c] * inv;
    float vv = stp[64 + c] * inv - mm * mm;
    float sc = g[c] * rsqrtf(vv + EPSF);
    float sh = be[c] - mm * sc;
    #pragma unroll
    for (int tt = 0; tt < 4; ++tt) {
        int bl = tt * 8 + hi;
        tile[bl][lo] = sc * in[(size_t)(b0 + bl) * KFC + (j0 + lo)] + sh;
    }
    __syncthreads();
    #pragma unroll
    for (int tt = 0; tt < 4; ++tt) {
        int jl = tt * 8 + hi;
        hT[(size_t)(j0 + jl) * Bn + b0 + lo] = tile[lo][jl];
    }
}

__global__ __launch_bounds__(256) void k_fc1(const float* __restrict__ hT,
                                             const float* __restrict__ Wf1,
                                             float* __restrict__ Pb) {
    int lane = threadIdx.x & 63;
    int f0 = __builtin_amdgcn_readfirstlane((threadIdx.x >> 6) * 16);
    int b  = blockIdx.y * 64 + lane;
    int kc = blockIdx.x;
    int k0 = kc * FCKL;
    float acc[16] = {};
    for (int k = k0; k < k0 + FCKL; ++k) {
        float hv = hT[(size_t)k * Bn + b];
        #pragma unroll
        for (int f = 0; f < 16; ++f)
            acc[f] += hv * Wf1[(size_t)(f0 + f) * KFC + k];
    }
    float* pp = Pb + (size_t)kc * 8192 + (size_t)b * 64 + f0;
    #pragma unroll
    for (int f = 0; f < 16; ++f) pp[f] = acc[f];
}

__global__ __launch_bounds__(256) void k_fc1red(const float* __restrict__ Pb,
                                                float* __restrict__ F) {
    int m = blockIdx.x * 256 + threadIdx.x;
    float s = 0.f;
    for (int kc = 0; kc < FCCH; ++kc) s += Pb[(size_t)kc * 8192 + m];
    F[m] = s;
}

__global__ __launch_bounds__(256) void k_fcfin(const float* __restrict__ F,
                                               const float* __restrict__ bf1,
                                               const float* __restrict__ gf,
                                               const float* __restrict__ bef,
                                               const float* __restrict__ Wf2,
                                               const float* __restrict__ bf2,
                                               float* __restrict__ out) {
    __shared__ float sF[8192];
    __shared__ float sfa[128];
    const int t = threadIdx.x;
    for (int m = t; m < 8192; m += 256) sF[m] = F[m];
    __syncthreads();
    if (t < 64) {
        float s = 0.f, ss = 0.f;
        for (int b = 0; b < Bn; ++b) {
            float v = sF[b * 64 + t] + bf1[t];
            s += v; ss += v * v;
        }
        float m  = s / 128.f;
        float va = ss / 128.f - m * m;
        float sc = gf[t] * rsqrtf(va + EPSF);
        sfa[t] = sc;
        sfa[64 + t] = sc * bf1[t] + bef[t] - m * sc;
    }
    __syncthreads();
    for (int m = t; m < Bn * 35; m += 256) {
        int b = m / 35, o = m - b * 35;
        float acc = bf2[o];
        for (int ff = 0; ff < 64; ++ff) {
            int f = (ff + t) & 63;
            float z = fmaxf(sfa[f] * sF[b * 64 + f] + sfa[64 + f], 0.f);
            acc += z * Wf2[o * 64 + f];
        }
        out[m] = acc;
    }
}

// ---------------------------------------------------------------------------
// launch
// ---------------------------------------------------------------------------
extern "C" void kernel_launch(void* const* d_in, const int* in_sizes, int n_in,
                              void* d_out, int out_size, void* d_ws, size_t ws_size,
                              hipStream_t stream) {
    const float* x    = (const float*)d_in[0];
    const float* W11  = (const float*)d_in[1];
    const float* b11  = (const float*)d_in[2];
    const float* g11  = (const float*)d_in[3];
    const float* be11 = (const float*)d_in[4];
    const float* lc1w = (const float*)d_in[5];
    const float* lc1b = (const float*)d_in[6];
    const float* g12  = (const float*)d_in[7];
    const float* be12 = (const float*)d_in[8];
    const float* W13  = (const float*)d_in[9];
    const float* b13  = (const float*)d_in[10];
    const float* g13  = (const float*)d_in[11];
    const float* be13 = (const float*)d_in[12];
    const float* W21  = (const float*)d_in[13];
    const float* b21  = (const float*)d_in[14];
    const float* g21  = (const float*)d_in[15];
    const float* be21 = (const float*)d_in[16];
    const float* lc2w = (const float*)d_in[17];
    const float* lc2b = (const float*)d_in[18];
    const float* g22  = (const float*)d_in[19];
    const float* be22 = (const float*)d_in[20];
    const float* W23  = (const float*)d_in[21];
    const float* b23  = (const float*)d_in[22];
    const float* g23  = (const float*)d_in[23];
    const float* be23 = (const float*)d_in[24];
    const float* W31  = (const float*)d_in[25];
    const float* b31  = (const float*)d_in[26];
    const float* g31  = (const float*)d_in[27];
    const float* be31 = (const float*)d_in[28];
    const float* lc3w = (const float*)d_in[29];
    const float* lc3b = (const float*)d_in[30];
    const float* g32  = (const float*)d_in[31];
    const float* be32 = (const float*)d_in[32];
    const float* W33  = (const float*)d_in[33];
    const float* b33  = (const float*)d_in[34];
    const float* g33  = (const float*)d_in[35];
    const float* be33 = (const float*)d_in[36];
    const float* Wf1  = (const float*)d_in[37];
    const float* bf1  = (const float*)d_in[38];
    const float* gf   = (const float*)d_in[39];
    const float* bef  = (const float*)d_in[40];
    const float* Wf2  = (const float*)d_in[41];
    const float* bf2  = (const float*)d_in[42];

    float* ws  = (float*)d_ws;
    float* A   = ws + oA;
    float* Bb  = ws + oB;
    __bf16* Abf = (__bf16*)(ws + oA);
    __bf16* Bbf = (__bf16*)(ws + oB);
    __bf16* wq2f = (__bf16*)(ws + oW2);
    __bf16* wq3f = (__bf16*)(ws + oW3);
    __bf16* wq1  = (__bf16*)(ws + oW1);
    __bf16* wqm  = (__bf16*)(ws + oWM);
    float* bfold = ws + oBF;           // b21f @0, b31f @64
    float* Pb  = ws + oP;
    float* st  = ws + oSt;
    float* F   = ws + oF;

    const int blk1 = (M1 + 255) / 256;
    const int blk2 = M2 / 256;
    const int blk3 = M3 / 256;

    k_prep_all<<<(NPREP + 255) / 256, 256, 0, stream>>>(W11, W13, W23, W33, wq1, wqm, st);

    // ---- stage 1 ----
    k_conv1m<<<dim3((P1 + 511) / 512, Bn), 256, 0, stream>>>(x, wq1, b11, A, st + 0 * 128);
    k_lc<P1><<<blk1, 256, 0, stream>>>(A, st + 0 * 128, g11, be11, 1.0f / (float)M1,
                                       lc1w, lc1b, Bbf, st + 1 * 128);                    // Z1 -> Bb
    k_mixm<P1, H1, Wo1, true><<<dim3((P1 + 511) / 512, Bn), 256, 0, stream>>>(
        Bbf, st + 1 * 128, g12, be12, 1.0f / (62.0f * (float)M1),
        wqm + 0 * 4096, b13, (void*)Abf, st + 2 * 128);                                   // X2 -> A

    // ---- stage 2 ----
    k_foldw<KH2, KW2><<<64, 256, 0, stream>>>(W21, st + 2 * 128, g13, be13,
                                              1.0f / (float)M1, b21, wq2f, bfold + 0);
    k_convmfma<KH2, KW2, H1, Wo1, H2, Wo2, 35>
        <<<dim3((P2 + 511) / 512, Bn), 256, 0, stream>>>(Abf, wq2f, bfold + 0, Bb, st + 3 * 128);
    k_lc<P2><<<blk2, 256, 0, stream>>>(Bb, st + 3 * 128, g21, be21, 1.0f / (float)M2,
                                       lc2w, lc2b, Abf, st + 4 * 128);                    // Z2 -> A
    k_mixm<P2, H2, Wo2, true><<<dim3((P2 + 511) / 512, Bn), 256, 0, stream>>>(
        Abf, st + 4 * 128, g22, be22, 1.0f / (62.0f * (float)M2),
        wqm + 1 * 4096, b23, (void*)Bbf, st + 5 * 128);                                   // X3 -> Bb

    // ---- stage 3 ----
    k_foldw<KH3, KW3><<<64, 256, 0, stream>>>(W31, st + 5 * 128, g23, be23,
                                              1.0f / (float)M2, b31, wq3f, bfold + 64);
    k_convmfma<KH3, KW3, H2, Wo2, H3, Wo3, 37>
        <<<dim3((P3 + 511) / 512, Bn), 256, 0, stream>>>(Bbf, wq3f, bfold + 64, A, st + 6 * 128);
    k_lc<P3><<<blk3, 256, 0, stream>>>(A, st + 6 * 128, g31, be31, 1.0f / (float)M3,
                                       lc3w, lc3b, Bbf, st + 7 * 128);                    // Z3 -> Bb
    k_mixm<P3, 1, 1, false><<<dim3((P3 + 511) / 512, Bn), 256, 0, stream>>>(
        Bbf, st + 7 * 128, g32, be32, 1.0f / (62.0f * (float)M3),
        wqm + 2 * 4096, b33, (void*)A, st + 8 * 128);                                     // Y -> A fp32

    // ---- FC head ----
    k_transpose<<<dim3(KFC / 32, Bn / 32), 256, 0, stream>>>(
        A, st + 8 * 128, g33, be33, 1.0f / (float)M3, Bb);
    k_fc1<<<dim3(FCCH, 2), 256, 0, stream>>>(Bb, Wf1, Pb);
    k_fc1red<<<32, 256, 0, stream>>>(Pb, F);
    k_fcfin<<<1, 256, 0, stream>>>(F, bf1, gf, bef, Wf2, bf2, (float*)d_out);
}

// Round 10
// 909.640 us; speedup vs baseline: 2.4890x; 1.1744x over previous
//
#include <hip/hip_runtime.h>

typedef __bf16 bfrag __attribute__((ext_vector_type(8)));
typedef float ffrag __attribute__((ext_vector_type(16)));

// ---------------------------------------------------------------------------
// Shapes / constants
// ---------------------------------------------------------------------------
constexpr int Bn  = 128;
constexpr int H0  = 98, Wi0 = 40;
constexpr int KH1 = 20, KW1 = 8, H1 = 79, Wo1 = 33, P1 = H1 * Wo1;   // 2607
constexpr int KH2 = 15, KW2 = 8, H2 = 65, Wo2 = 26, P2 = H2 * Wo2;   // 1690
constexpr int KH3 = 10, KW3 = 8, H3 = 56, Wo3 = 19, P3 = H3 * Wo3;   // 1064
constexpr int M1  = Bn * P1;
constexpr int M2  = Bn * P2;
constexpr int M3  = Bn * P3;
constexpr int KFC = 64 * P3;       // 68096
constexpr int FCCH = 112;          // split-K chunks
constexpr int FCKL = KFC / FCCH;   // 608 = 38 k-steps * 16
constexpr int FCKS = FCKL / 16;    // 38
constexpr float EPSF = 1e-5f;

// ---------------------------------------------------------------------------
// Workspace layout (float slots)
//   hb  = M3*64 bf16 = 8,716,288 bf16 = 4,358,144 FLOATS  (round-9 bug: was
//         sized 2.18M -> wf1b overlapped hb tail. Fixed below.)
// ---------------------------------------------------------------------------
constexpr size_t oA   = 0;
constexpr size_t oB   = oA  + (size_t)Bn * 64 * P1;          // 21,356,544
constexpr size_t oHB  = oB;                                  // hb bf16 (4,358,144 fl)
constexpr size_t oWF  = oB  + 4358144;                       // Wf1b bf16 (2,179,072 fl)
constexpr size_t oW2  = oB  + (size_t)Bn * 62 * P1;          // wq2f (245,760 fl) @ +20.69M
constexpr size_t oW3  = oW2 + 245760;                        // wq3f (163,840 fl)
constexpr size_t oW1  = oW3 + 163840;                        // wq1 (5,120 fl)
constexpr size_t oWM  = oW1 + 5120;                          // wqm (3x2048 fl)
constexpr size_t oBF  = oWM + 6144;                          // folded biases
constexpr size_t oP   = oBF + 128;                           // Pb (112x8192)
constexpr size_t oSt  = oP  + (size_t)FCCH * 8192;           // stats 9x512
constexpr size_t oF   = oSt + 9 * 512;                       // fc1 out (8192)

__device__ __forceinline__ float wred(float v) {
    #pragma unroll
    for (int o = 32; o > 0; o >>= 1) v += __shfl_down(v, o);
    return v;
}

// sum a 4-banked per-channel stat:  val[c] = sum_k st[k*128 + c]
__device__ __forceinline__ float bank4(const float* stp, int c) {
    return stp[c] + stp[128 + c] + stp[256 + c] + stp[384 + c];
}

// ---------------------------------------------------------------------------
// prep: zero stats + pack wq1 + pack mix matrices
// ---------------------------------------------------------------------------
constexpr int NZ  = 9 * 512;
constexpr int NW1 = 10240;
constexpr int NWM = 3 * 4096;
constexpr int NPREP = NZ + NW1 + NWM;
__global__ __launch_bounds__(256) void k_prep_all(
    const float* __restrict__ W11, const float* __restrict__ W13,
    const float* __restrict__ W23, const float* __restrict__ W33,
    __bf16* __restrict__ wq1, __bf16* __restrict__ wqm,
    float* __restrict__ st)
{
    int idx = blockIdx.x * 256 + threadIdx.x;
    if (idx < NZ) { st[idx] = 0.f; return; }
    idx -= NZ;
    if (idx < NW1) {
        int j = idx & 7, oc = (idx >> 3) & 63, khh = idx >> 9;
        wq1[idx] = (__bf16)W11[(size_t)oc * 160 + khh * 8 + j];
        return;
    }
    idx -= NW1;
    if (idx < NWM) {
        int which = idx >> 12, r = idx & 4095;
        int j = r & 7, oc = (r >> 3) & 63, sub = (r >> 9) & 1, ks = r >> 10;
        int k = ks * 16 + sub * 8 + j;
        const float* Wm = which == 0 ? W13 : (which == 1 ? W23 : W33);
        wqm[idx] = (k < 62) ? (__bf16)Wm[oc * 62 + k] : (__bf16)0.f;
    }
}

// ---------------------------------------------------------------------------
// fold BN affine into conv weights (stats 4-banked)
// ---------------------------------------------------------------------------
template <int KH, int KW>
__global__ __launch_bounds__(256) void k_foldw(
    const float* __restrict__ W, const float* __restrict__ stp,
    const float* __restrict__ g, const float* __restrict__ be,
    float inv, const float* __restrict__ bias,
    __bf16* __restrict__ wqf, float* __restrict__ biasf)
{
    constexpr int KK = KH * KW;
    __shared__ float sSc[64], sSh[64], ls[4];
    const int t = threadIdx.x;
    if (t < 64) {
        float mm = bank4(stp, t) * inv;
        float vv = bank4(stp, 64 + t) * inv - mm * mm;
        float sc = g[t] * rsqrtf(vv + EPSF);
        sSc[t] = sc;
        sSh[t] = be[t] - mm * sc;
    }
    __syncthreads();
    const int oc = blockIdx.x;
    float local = 0.f;
    for (int i = t; i < 64 * KK; i += 256) {
        int ic = i / KK, rem = i - ic * KK;
        int kh = rem / KW, kw = rem - kh * KW;
        float wv = W[(((size_t)oc * 64 + ic) * KH + kh) * KW + kw];
        int c = ic >> 4, sub = (ic >> 3) & 1, j = ic & 7, pos = kh * KW + kw;
        wqf[(size_t)pos * 4096 + c * 1024 + sub * 512 + oc * 8 + j] = (__bf16)(wv * sSc[ic]);
        local += wv * sSh[ic];
    }
    local = wred(local);
    int wv2 = t >> 6, ln = t & 63;
    if (ln == 0) ls[wv2] = local;
    __syncthreads();
    if (t == 0) biasf[oc] = bias[oc] + ls[0] + ls[1] + ls[2] + ls[3];
}

// ---------------------------------------------------------------------------
// conv1 MFMA: x -> A fp32 [b][64][P1], fused 4-banked ch-stats
// ---------------------------------------------------------------------------
constexpr int C1COPY = 1736;
__global__ __launch_bounds__(256, 2) void k_conv1m(
    const float* __restrict__ x, const __bf16* __restrict__ wq,
    const float* __restrict__ bias, float* __restrict__ out,
    float* __restrict__ sto)
{
    const int b = blockIdx.y;
    const int m0 = blockIdx.x * 512;
    const int t = threadIdx.x, lane = t & 63, wv = t >> 6;
    const int l31 = lane & 31, lh = lane >> 5;
    __shared__ __align__(16) __bf16 X8[8 * C1COPY];

    const int oh_lo = m0 / Wo1;
    int abase[4];
    #pragma unroll
    for (int mt = 0; mt < 4; ++mt) {
        int m = m0 + wv * 128 + mt * 32 + l31;
        int mc = m > P1 - 1 ? P1 - 1 : m;
        int oh = mc / Wo1, ow = mc - oh * Wo1;
        int s = ow & 7;
        abase[mt] = s * C1COPY + (oh - oh_lo) * 48 + (ow - s);
    }
    for (int idx = t; idx < 8 * 36 * 6; idx += 256) {
        int s = idx / 216; int rr = idx - s * 216;
        int r = rr / 6, q = rr - r * 6;
        int ih = oh_lo + r; if (ih > H0 - 1) ih = H0 - 1;
        const float* src = x + ((size_t)b * H0 + ih) * Wi0;
        __bf16 tmp[8] __attribute__((aligned(16)));
        #pragma unroll
        for (int j = 0; j < 8; ++j) {
            int col = q * 8 + s + j; if (col > Wi0 - 1) col = Wi0 - 1;
            tmp[j] = (__bf16)src[col];
        }
        *(uint4*)&X8[s * C1COPY + r * 48 + q * 8] = *(uint4*)tmp;
    }
    __syncthreads();

    ffrag acc[4][2] = {};
    #pragma unroll 1
    for (int st2 = 0; st2 < 10; ++st2) {
        const int khl = st2 * 2 + lh;
        const __bf16* wp = wq + ((size_t)khl * 64 + l31) * 8;
        bfrag b0 = *(const bfrag*)(wp);
        bfrag b1 = *(const bfrag*)(wp + 256);
        #pragma unroll
        for (int mt = 0; mt < 4; ++mt) {
            bfrag a = *(const bfrag*)&X8[abase[mt] + khl * 48];
            acc[mt][0] = __builtin_amdgcn_mfma_f32_32x32x16_bf16(a, b0, acc[mt][0], 0, 0, 0);
            acc[mt][1] = __builtin_amdgcn_mfma_f32_32x32x16_bf16(a, b1, acc[mt][1], 0, 0, 0);
        }
    }

    float sS[2] = {0.f, 0.f}, sSS[2] = {0.f, 0.f};
    #pragma unroll
    for (int nt = 0; nt < 2; ++nt) {
        int oc = nt * 32 + l31;
        float bv = bias[oc];
        float* op = out + ((size_t)b * 64 + oc) * P1;
        #pragma unroll
        for (int mt = 0; mt < 4; ++mt) {
            int mbase = m0 + wv * 128 + mt * 32 + lh * 4;
            #pragma unroll
            for (int g = 0; g < 4; ++g) {
                int mr = mbase + g * 8;
                float v0 = acc[mt][nt][g * 4 + 0] + bv;
                float v1 = acc[mt][nt][g * 4 + 1] + bv;
                float v2 = acc[mt][nt][g * 4 + 2] + bv;
                float v3 = acc[mt][nt][g * 4 + 3] + bv;
                if (mr + 1 < P1) {
                    *(float2*)(op + mr) = make_float2(v0, v1);
                    sS[nt] += v0 + v1; sSS[nt] += v0 * v0 + v1 * v1;
                    if (mr + 3 < P1) {
                        *(float2*)(op + mr + 2) = make_float2(v2, v3);
                        sS[nt] += v2 + v3; sSS[nt] += v2 * v2 + v3 * v3;
                    } else if (mr + 2 < P1) {
                        op[mr + 2] = v2; sS[nt] += v2; sSS[nt] += v2 * v2;
                    }
                } else if (mr < P1) {
                    op[mr] = v0; sS[nt] += v0; sSS[nt] += v0 * v0;
                }
            }
        }
    }
    #pragma unroll
    for (int nt = 0; nt < 2; ++nt) {
        sS[nt]  += __shfl_down(sS[nt], 32);
        sSS[nt] += __shfl_down(sSS[nt], 32);
    }
    __syncthreads();
    float* redS  = (float*)X8;
    float* redSS = redS + 256;
    if (lane < 32) {
        #pragma unroll
        for (int nt = 0; nt < 2; ++nt) {
            redS[wv * 64 + nt * 32 + l31]  = sS[nt];
            redSS[wv * 64 + nt * 32 + l31] = sSS[nt];
        }
    }
    __syncthreads();
    if (t < 64) {
        int bank = ((blockIdx.x ^ blockIdx.y) & 3) * 128;
        atomicAdd(&sto[bank + t],      redS[t] + redS[64 + t] + redS[128 + t] + redS[192 + t]);
        atomicAdd(&sto[bank + 64 + t], redSS[t] + redSS[64 + t] + redSS[128 + t] + redSS[192 + t]);
    }
}

// ---------------------------------------------------------------------------
// lc: per-ch affine (4-bank stats) + relu, 3-tap -> bf16 Z[m][64],
// fused global stats spread over 64 slots
// ---------------------------------------------------------------------------
template <int POS>
__global__ __launch_bounds__(256) void k_lc(const float* __restrict__ in,
                                            const float* __restrict__ stp,
                                            const float* __restrict__ g,
                                            const float* __restrict__ be,
                                            float inv,
                                            const float* __restrict__ lcw,
                                            const float* __restrict__ lcb,
                                            __bf16* __restrict__ Z,
                                            float* __restrict__ sto) {
    __shared__ float sAff[128];
    __shared__ float sred[4], ssred[4];
    if (threadIdx.x < 64) {
        int tt = threadIdx.x;
        float mm = bank4(stp, tt) * inv;
        float vv = bank4(stp, 64 + tt) * inv - mm * mm;
        float sc = g[tt] * rsqrtf(vv + EPSF);
        sAff[tt] = sc;
        sAff[64 + tt] = be[tt] - mm * sc;
    }
    __syncthreads();
    int morig = blockIdx.x * 256 + threadIdx.x;
    bool valid = morig < Bn * POS;
    int m = valid ? morig : Bn * POS - 1;
    int b = m / POS; int p = m - b * POS;
    const float* ip = in + (size_t)b * 64 * POS + p;
    __bf16 zb[64] __attribute__((aligned(16)));
    zb[62] = (__bf16)0.f; zb[63] = (__bf16)0.f;
    float ts = 0.f, tss = 0.f;
    float y0 = fmaxf(sAff[0] * ip[0]           + sAff[64], 0.f);
    float y1 = fmaxf(sAff[1] * ip[(size_t)POS] + sAff[65], 0.f);
    for (int c = 0; c < 62; ++c) {
        float y2 = fmaxf(sAff[c + 2] * ip[(size_t)(c + 2) * POS] + sAff[64 + c + 2], 0.f);
        float o = lcb[c] + y0 * lcw[c * 3] + y1 * lcw[c * 3 + 1] + y2 * lcw[c * 3 + 2];
        zb[c] = (__bf16)o;
        if (valid) { ts += o; tss += o * o; }
        y0 = y1; y1 = y2;
    }
    __bf16* zp = Z + (size_t)m * 64;
    #pragma unroll
    for (int j = 0; j < 8; ++j)
        *(uint4*)(zp + j * 8) = *(uint4*)(zb + j * 8);
    ts = wred(ts); tss = wred(tss);
    int wv = threadIdx.x >> 6, ln = threadIdx.x & 63;
    if (ln == 0) { sred[wv] = ts; ssred[wv] = tss; }
    __syncthreads();
    if (threadIdx.x == 0) {
        int slot = blockIdx.x & 63;
        atomicAdd(&sto[slot],      sred[0] + sred[1] + sred[2] + sred[3]);
        atomicAdd(&sto[64 + slot], ssred[0] + ssred[1] + ssred[2] + ssred[3]);
    }
}

// ---------------------------------------------------------------------------
// mix as MFMA; global stats read from 64-spread slots; out-stats 4-banked
// ---------------------------------------------------------------------------
template <int POS, int IH, int IW, bool OUTBF>
__global__ __launch_bounds__(256, 2) void k_mixm(
    const __bf16* __restrict__ Z, const float* __restrict__ stp,
    const float* __restrict__ g, const float* __restrict__ be,
    float inv, const __bf16* __restrict__ wqm,
    const float* __restrict__ bm, void* __restrict__ outv,
    float* __restrict__ sto)
{
    const int b = blockIdx.y;
    const int m0 = blockIdx.x * 512;
    const int t = threadIdx.x, lane = t & 63, wv = t >> 6;
    const int l31 = lane & 31, lh = lane >> 5;

    float gs = 0.f, gss = 0.f;
    #pragma unroll
    for (int i = 0; i < 64; ++i) { gs += stp[i]; gss += stp[64 + i]; }
    float mm = gs * inv;
    float vv = gss * inv - mm * mm;
    float s0 = g[0] * rsqrtf(vv + EPSF);
    float t0 = be[0] - mm * s0;

    size_t zbase[4];
    #pragma unroll
    for (int mt = 0; mt < 4; ++mt) {
        int m = m0 + wv * 128 + mt * 32 + l31;
        int mc = m > POS - 1 ? POS - 1 : m;
        zbase[mt] = ((size_t)b * POS + mc) * 64;
    }

    ffrag acc[4][2] = {};
    #pragma unroll
    for (int ks = 0; ks < 4; ++ks) {
        const __bf16* wp = wqm + ks * 1024 + lh * 512 + l31 * 8;
        bfrag b0 = *(const bfrag*)wp;
        bfrag b1 = *(const bfrag*)(wp + 256);
        #pragma unroll
        for (int mt = 0; mt < 4; ++mt) {
            uint4 raw = *(const uint4*)(Z + zbase[mt] + ks * 16 + lh * 8);
            const __bf16* zin = (const __bf16*)&raw;
            __bf16 zout[8] __attribute__((aligned(16)));
            #pragma unroll
            for (int j = 0; j < 8; ++j) {
                float f = (float)zin[j];
                zout[j] = (__bf16)fmaxf(fmaf(s0, f, t0), 0.f);
            }
            bfrag a = *(const bfrag*)zout;
            acc[mt][0] = __builtin_amdgcn_mfma_f32_32x32x16_bf16(a, b0, acc[mt][0], 0, 0, 0);
            acc[mt][1] = __builtin_amdgcn_mfma_f32_32x32x16_bf16(a, b1, acc[mt][1], 0, 0, 0);
        }
    }

    float sS[2] = {0.f, 0.f}, sSS[2] = {0.f, 0.f};
    #pragma unroll
    for (int nt = 0; nt < 2; ++nt) {
        int oc = nt * 32 + l31;
        float bv = bm[oc];
        if constexpr (OUTBF) {
            __bf16* op = (__bf16*)outv;
            #pragma unroll
            for (int mt = 0; mt < 4; ++mt) {
                int mbase = m0 + wv * 128 + mt * 32 + lh * 4;
                #pragma unroll
                for (int g4 = 0; g4 < 4; ++g4) {
                    #pragma unroll
                    for (int q = 0; q < 4; ++q) {
                        int mr = mbase + g4 * 8 + q;
                        if (mr < POS) {
                            float v = acc[mt][nt][g4 * 4 + q] + bv;
                            int ih = mr / IW, iw = mr - ih * IW;
                            op[((size_t)(b * IH + ih) * 2 + nt) * (IW * 32) + iw * 32 + l31] = (__bf16)v;
                            sS[nt] += v; sSS[nt] += v * v;
                        }
                    }
                }
            }
        } else {
            float* op = (float*)outv + ((size_t)b * 64 + oc) * POS;
            #pragma unroll
            for (int mt = 0; mt < 4; ++mt) {
                int mbase = m0 + wv * 128 + mt * 32 + lh * 4;
                #pragma unroll
                for (int g4 = 0; g4 < 4; ++g4) {
                    int mr = mbase + g4 * 8;
                    if (mr < POS) {
                        float v0 = acc[mt][nt][g4 * 4 + 0] + bv;
                        float v1 = acc[mt][nt][g4 * 4 + 1] + bv;
                        *(float2*)(op + mr) = make_float2(v0, v1);
                        sS[nt] += v0 + v1; sSS[nt] += v0 * v0 + v1 * v1;
                        if (mr + 2 < POS) {
                            float v2 = acc[mt][nt][g4 * 4 + 2] + bv;
                            float v3 = acc[mt][nt][g4 * 4 + 3] + bv;
                            *(float2*)(op + mr + 2) = make_float2(v2, v3);
                            sS[nt] += v2 + v3; sSS[nt] += v2 * v2 + v3 * v3;
                        }
                    }
                }
            }
        }
    }
    #pragma unroll
    for (int nt = 0; nt < 2; ++nt) {
        sS[nt]  += __shfl_down(sS[nt], 32);
        sSS[nt] += __shfl_down(sSS[nt], 32);
    }
    __shared__ float red[512];
    if (lane < 32) {
        #pragma unroll
        for (int nt = 0; nt < 2; ++nt) {
            red[wv * 64 + nt * 32 + l31]       = sS[nt];
            red[256 + wv * 64 + nt * 32 + l31] = sSS[nt];
        }
    }
    __syncthreads();
    if (t < 64) {
        int bank = ((blockIdx.x ^ blockIdx.y) & 3) * 128;
        atomicAdd(&sto[bank + t],      red[t] + red[64 + t] + red[128 + t] + red[192 + t]);
        atomicAdd(&sto[bank + 64 + t], red[256 + t] + red[320 + t] + red[384 + t] + red[448 + t]);
    }
}

// ---------------------------------------------------------------------------
// implicit-GEMM conv: MT m-tiles/wave, swizzled LDS, 4-banked stats
// ---------------------------------------------------------------------------
template <int KH, int KW, int IH, int IW, int OH, int OW, int NR, int MT>
__global__ __launch_bounds__(256, 2) void k_convmfma(
    const __bf16* __restrict__ in,
    const __bf16* __restrict__ wq,
    const float* __restrict__ bias,
    float* __restrict__ out,
    float* __restrict__ sto)
{
    constexpr int P = OH * OW;
    constexpr int MB = 128 * MT;
    const int b  = blockIdx.y;
    const int m0 = blockIdx.x * MB;
    const int t  = threadIdx.x;
    const int lane = t & 63;
    const int wv = t >> 6;
    const int l31 = lane & 31, lh = lane >> 5;

    __shared__ __align__(16) __bf16 As[NR * IW * 32 + 64];

    const int oh_lo = m0 / OW;
    int posm[MT];
    #pragma unroll
    for (int mt = 0; mt < MT; ++mt) {
        int m = m0 + wv * (32 * MT) + mt * 32 + l31;
        int mc = m > P - 1 ? P - 1 : m;
        int oh = mc / OW, ow = mc - oh * OW;
        posm[mt] = (oh - oh_lo) * IW + ow;
    }

    ffrag acc[MT][2] = {};

    for (int ich = 0; ich < 2; ++ich) {
        __syncthreads();
        constexpr int ROWCH = IW * 4;
        constexpr int CH = NR * ROWCH;
        for (int idx = t; idx < CH; idx += 256) {
            int r = idx / ROWCH, o = idx - r * ROWCH;
            int ih = oh_lo + r; if (ih > IH - 1) ih = IH - 1;
            const __bf16* src = in + ((size_t)(b * IH + ih) * 2 + ich) * (IW * 32) + o * 8;
            int sw = idx ^ ((idx >> 2) & 7);
            *(uint4*)&As[sw * 8] = *(const uint4*)src;
        }
        __syncthreads();

        const __bf16* wich = wq + ich * 2048;
        for (int kh = 0; kh < KH; ++kh) {
            const int rowoff = kh * IW;
            const __bf16* wkh = wich + (size_t)(kh * KW) * 4096 + lh * 512 + l31 * 8;
            #pragma unroll 2
            for (int kw = 0; kw < KW; ++kw) {
                const __bf16* wp = wkh + kw * 4096;
                #pragma unroll
                for (int cc = 0; cc < 2; ++cc) {
                    bfrag b0 = *(const bfrag*)(wp + cc * 1024);
                    bfrag b1 = *(const bfrag*)(wp + cc * 1024 + 256);
                    #pragma unroll
                    for (int mt = 0; mt < MT; ++mt) {
                        int X = posm[mt] + rowoff + kw;
                        int gc = (X << 2) + cc * 2 + lh;
                        bfrag a = *(const bfrag*)&As[(gc ^ (X & 7)) * 8];
                        acc[mt][0] = __builtin_amdgcn_mfma_f32_32x32x16_bf16(a, b0, acc[mt][0], 0, 0, 0);
                        acc[mt][1] = __builtin_amdgcn_mfma_f32_32x32x16_bf16(a, b1, acc[mt][1], 0, 0, 0);
                    }
                }
            }
        }
    }

    float sS[2] = {0.f, 0.f}, sSS[2] = {0.f, 0.f};
    #pragma unroll
    for (int nt = 0; nt < 2; ++nt) {
        int oc = nt * 32 + l31;
        float bv = bias[oc];
        float* op = out + ((size_t)b * 64 + oc) * P;
        #pragma unroll
        for (int mt = 0; mt < MT; ++mt) {
            int mbase = m0 + wv * (32 * MT) + mt * 32 + lh * 4;
            #pragma unroll
            for (int g = 0; g < 4; ++g) {
                int mr = mbase + g * 8;
                if (mr < P) {
                    float v0 = acc[mt][nt][g * 4 + 0] + bv;
                    float v1 = acc[mt][nt][g * 4 + 1] + bv;
                    *(float2*)(op + mr) = make_float2(v0, v1);
                    sS[nt] += v0 + v1; sSS[nt] += v0 * v0 + v1 * v1;
                    if (mr + 2 < P) {
                        float v2 = acc[mt][nt][g * 4 + 2] + bv;
                        float v3 = acc[mt][nt][g * 4 + 3] + bv;
                        *(float2*)(op + mr + 2) = make_float2(v2, v3);
                        sS[nt] += v2 + v3; sSS[nt] += v2 * v2 + v3 * v3;
                    }
                }
            }
        }
    }
    #pragma unroll
    for (int nt = 0; nt < 2; ++nt) {
        sS[nt]  += __shfl_down(sS[nt], 32);
        sSS[nt] += __shfl_down(sSS[nt], 32);
    }
    __syncthreads();
    float* redS  = (float*)As;
    float* redSS = redS + 256;
    if (lane < 32) {
        #pragma unroll
        for (int nt = 0; nt < 2; ++nt) {
            redS[wv * 64 + nt * 32 + l31]  = sS[nt];
            redSS[wv * 64 + nt * 32 + l31] = sSS[nt];
        }
    }
    __syncthreads();
    if (t < 64) {
        int bank = ((blockIdx.x ^ blockIdx.y) & 3) * 128;
        atomicAdd(&sto[bank + t],      redS[t] + redS[64 + t] + redS[128 + t] + redS[192 + t]);
        atomicAdd(&sto[bank + 64 + t], redSS[t] + redSS[64 + t] + redSS[128 + t] + redSS[192 + t]);
    }
}

// ---------------------------------------------------------------------------
// prep_hb: Y fp32 [b][64][P3] + affine(slot8) -> hb bf16 [b][k] (flat cast),
// plus Wf1 fp32 -> bf16 flat.  8 elements per thread; 8 | P3.
// ---------------------------------------------------------------------------
constexpr int NHB  = M3 * 64 / 8;        // 1,089,536
constexpr int NWFB = 64 * KFC / 8;       // 544,768
__global__ __launch_bounds__(256) void k_prep_hb(
    const float* __restrict__ Y, const float* __restrict__ stp,
    const float* __restrict__ g, const float* __restrict__ be, float inv,
    const float* __restrict__ Wf1,
    __bf16* __restrict__ hb, __bf16* __restrict__ wf1b)
{
    int idx = blockIdx.x * 256 + threadIdx.x;
    if (idx < NHB) {
        size_t base = (size_t)idx * 8;
        int c = (int)(base / P3) & 63;
        float mm = bank4(stp, c) * inv;
        float vv = bank4(stp, 64 + c) * inv - mm * mm;
        float sc = g[c] * rsqrtf(vv + EPSF);
        float sh = be[c] - mm * sc;
        __bf16 tmp[8] __attribute__((aligned(16)));
        #pragma unroll
        for (int j = 0; j < 8; ++j)
            tmp[j] = (__bf16)(sc * Y[base + j] + sh);
        *(uint4*)(hb + base) = *(uint4*)tmp;
        return;
    }
    idx -= NHB;
    if (idx < NWFB) {
        size_t base = (size_t)idx * 8;
        __bf16 tmp[8] __attribute__((aligned(16)));
        #pragma unroll
        for (int j = 0; j < 8; ++j)
            tmp[j] = (__bf16)Wf1[base + j];
        *(uint4*)(wf1b + base) = *(uint4*)tmp;
    }
}

// ---------------------------------------------------------------------------
// fc1 as MFMA: [128 x K] x [K x 64], split-K 112 chunks of 608
// ---------------------------------------------------------------------------
__global__ __launch_bounds__(256) void k_fc1m(const __bf16* __restrict__ hb,
                                              const __bf16* __restrict__ wf1b,
                                              float* __restrict__ Pb) {
    const int kc = blockIdx.x;
    const int t = threadIdx.x, lane = t & 63, wv = t >> 6;
    const int l31 = lane & 31, lh = lane >> 5;
    const int k0 = kc * FCKL;

    const __bf16* ap = hb + (size_t)(wv * 32 + l31) * KFC + k0 + lh * 8;
    const __bf16* bp0 = wf1b + (size_t)l31 * KFC + k0 + lh * 8;
    const __bf16* bp1 = wf1b + (size_t)(32 + l31) * KFC + k0 + lh * 8;

    ffrag acc[2] = {};
    #pragma unroll 2
    for (int ks = 0; ks < FCKS; ++ks) {
        bfrag a  = *(const bfrag*)(ap  + ks * 16);
        bfrag b0 = *(const bfrag*)(bp0 + ks * 16);
        bfrag b1 = *(const bfrag*)(bp1 + ks * 16);
        acc[0] = __builtin_amdgcn_mfma_f32_32x32x16_bf16(a, b0, acc[0], 0, 0, 0);
        acc[1] = __builtin_amdgcn_mfma_f32_32x32x16_bf16(a, b1, acc[1], 0, 0, 0);
    }
    float* pp = Pb + (size_t)kc * 8192;
    #pragma unroll
    for (int nt = 0; nt < 2; ++nt) {
        #pragma unroll
        for (int g = 0; g < 4; ++g) {
            #pragma unroll
            for (int q = 0; q < 4; ++q) {
                int row = q + g * 8 + lh * 4;
                int bb = wv * 32 + row;
                pp[bb * 64 + nt * 32 + l31] = acc[nt][g * 4 + q];
            }
        }
    }
}

__global__ __launch_bounds__(256) void k_fc1red(const float* __restrict__ Pb,
                                                float* __restrict__ F) {
    int m = blockIdx.x * 256 + threadIdx.x;
    float s = 0.f;
    for (int kc = 0; kc < FCCH; ++kc) s += Pb[(size_t)kc * 8192 + m];
    F[m] = s;
}

__global__ __launch_bounds__(256) void k_fcfin(const float* __restrict__ F,
                                               const float* __restrict__ bf1,
                                               const float* __restrict__ gf,
                                               const float* __restrict__ bef,
                                               const float* __restrict__ Wf2,
                                               const float* __restrict__ bf2,
                                               float* __restrict__ out) {
    __shared__ float sF[8192];
    __shared__ float sfa[128];
    const int t = threadIdx.x;
    for (int m = t; m < 8192; m += 256) sF[m] = F[m];
    __syncthreads();
    if (t < 64) {
        float s = 0.f, ss = 0.f;
        for (int b = 0; b < Bn; ++b) {
            float v = sF[b * 64 + t] + bf1[t];
            s += v; ss += v * v;
        }
        float m  = s / 128.f;
        float va = ss / 128.f - m * m;
        float sc = gf[t] * rsqrtf(va + EPSF);
        sfa[t] = sc;
        sfa[64 + t] = sc * bf1[t] + bef[t] - m * sc;
    }
    __syncthreads();
    for (int m = t; m < Bn * 35; m += 256) {
        int b = m / 35, o = m - b * 35;
        float acc = bf2[o];
        for (int ff = 0; ff < 64; ++ff) {
            int f = (ff + t) & 63;
            float z = fmaxf(sfa[f] * sF[b * 64 + f] + sfa[64 + f], 0.f);
            acc += z * Wf2[o * 64 + f];
        }
        out[m] = acc;
    }
}

// ---------------------------------------------------------------------------
// launch
// ---------------------------------------------------------------------------
extern "C" void kernel_launch(void* const* d_in, const int* in_sizes, int n_in,
                              void* d_out, int out_size, void* d_ws, size_t ws_size,
                              hipStream_t stream) {
    const float* x    = (const float*)d_in[0];
    const float* W11  = (const float*)d_in[1];
    const float* b11  = (const float*)d_in[2];
    const float* g11  = (const float*)d_in[3];
    const float* be11 = (const float*)d_in[4];
    const float* lc1w = (const float*)d_in[5];
    const float* lc1b = (const float*)d_in[6];
    const float* g12  = (const float*)d_in[7];
    const float* be12 = (const float*)d_in[8];
    const float* W13  = (const float*)d_in[9];
    const float* b13  = (const float*)d_in[10];
    const float* g13  = (const float*)d_in[11];
    const float* be13 = (const float*)d_in[12];
    const float* W21  = (const float*)d_in[13];
    const float* b21  = (const float*)d_in[14];
    const float* g21  = (const float*)d_in[15];
    const float* be21 = (const float*)d_in[16];
    const float* lc2w = (const float*)d_in[17];
    const float* lc2b = (const float*)d_in[18];
    const float* g22  = (const float*)d_in[19];
    const float* be22 = (const float*)d_in[20];
    const float* W23  = (const float*)d_in[21];
    const float* b23  = (const float*)d_in[22];
    const float* g23  = (const float*)d_in[23];
    const float* be23 = (const float*)d_in[24];
    const float* W31  = (const float*)d_in[25];
    const float* b31  = (const float*)d_in[26];
    const float* g31  = (const float*)d_in[27];
    const float* be31 = (const float*)d_in[28];
    const float* lc3w = (const float*)d_in[29];
    const float* lc3b = (const float*)d_in[30];
    const float* g32  = (const float*)d_in[31];
    const float* be32 = (const float*)d_in[32];
    const float* W33  = (const float*)d_in[33];
    const float* b33  = (const float*)d_in[34];
    const float* g33  = (const float*)d_in[35];
    const float* be33 = (const float*)d_in[36];
    const float* Wf1  = (const float*)d_in[37];
    const float* bf1  = (const float*)d_in[38];
    const float* gf   = (const float*)d_in[39];
    const float* bef  = (const float*)d_in[40];
    const float* Wf2  = (const float*)d_in[41];
    const float* bf2  = (const float*)d_in[42];

    float* ws  = (float*)d_ws;
    float* A   = ws + oA;
    float* Bb  = ws + oB;
    __bf16* Abf = (__bf16*)(ws + oA);
    __bf16* Bbf = (__bf16*)(ws + oB);
    __bf16* hb   = (__bf16*)(ws + oHB);
    __bf16* wf1b = (__bf16*)(ws + oWF);
    __bf16* wq2f = (__bf16*)(ws + oW2);
    __bf16* wq3f = (__bf16*)(ws + oW3);
    __bf16* wq1  = (__bf16*)(ws + oW1);
    __bf16* wqm  = (__bf16*)(ws + oWM);
    float* bfold = ws + oBF;
    float* Pb  = ws + oP;
    float* st  = ws + oSt;
    float* F   = ws + oF;

    const int blk1 = (M1 + 255) / 256;
    const int blk2 = M2 / 256;
    const int blk3 = M3 / 256;

    k_prep_all<<<(NPREP + 255) / 256, 256, 0, stream>>>(W11, W13, W23, W33, wq1, wqm, st);

    // ---- stage 1 ----
    k_conv1m<<<dim3((P1 + 511) / 512, Bn), 256, 0, stream>>>(x, wq1, b11, A, st + 0 * 512);
    k_lc<P1><<<blk1, 256, 0, stream>>>(A, st + 0 * 512, g11, be11, 1.0f / (float)M1,
                                       lc1w, lc1b, Bbf, st + 1 * 512);
    k_mixm<P1, H1, Wo1, true><<<dim3((P1 + 511) / 512, Bn), 256, 0, stream>>>(
        Bbf, st + 1 * 512, g12, be12, 1.0f / (62.0f * (float)M1),
        wqm + 0 * 4096, b13, (void*)Abf, st + 2 * 512);

    // ---- stage 2 ----
    k_foldw<KH2, KW2><<<64, 256, 0, stream>>>(W21, st + 2 * 512, g13, be13,
                                              1.0f / (float)M1, b21, wq2f, bfold + 0);
    k_convmfma<KH2, KW2, H1, Wo1, H2, Wo2, 35, 4>
        <<<dim3((P2 + 511) / 512, Bn), 256, 0, stream>>>(Abf, wq2f, bfold + 0, Bb, st + 3 * 512);
    k_lc<P2><<<blk2, 256, 0, stream>>>(Bb, st + 3 * 512, g21, be21, 1.0f / (float)M2,
                                       lc2w, lc2b, Abf, st + 4 * 512);
    k_mixm<P2, H2, Wo2, true><<<dim3((P2 + 511) / 512, Bn), 256, 0, stream>>>(
        Abf, st + 4 * 512, g22, be22, 1.0f / (62.0f * (float)M2),
        wqm + 1 * 4096, b23, (void*)Bbf, st + 5 * 512);

    // ---- stage 3 ----
    k_foldw<KH3, KW3><<<64, 256, 0, stream>>>(W31, st + 5 * 512, g23, be23,
                                              1.0f / (float)M2, b31, wq3f, bfold + 64);
    k_convmfma<KH3, KW3, H2, Wo2, H3, Wo3, 30, 3>
        <<<dim3((P3 + 383) / 384, Bn), 256, 0, stream>>>(Bbf, wq3f, bfold + 64, A, st + 6 * 512);
    k_lc<P3><<<blk3, 256, 0, stream>>>(A, st + 6 * 512, g31, be31, 1.0f / (float)M3,
                                       lc3w, lc3b, Bbf, st + 7 * 512);
    k_mixm<P3, 1, 1, false><<<dim3((P3 + 511) / 512, Bn), 256, 0, stream>>>(
        Bbf, st + 7 * 512, g32, be32, 1.0f / (62.0f * (float)M3),
        wqm + 2 * 4096, b33, (void*)A, st + 8 * 512);

    // ---- FC head ----
    k_prep_hb<<<(NHB + NWFB + 255) / 256, 256, 0, stream>>>(
        A, st + 8 * 512, g33, be33, 1.0f / (float)M3, Wf1, hb, wf1b);
    k_fc1m<<<FCCH, 256, 0, stream>>>(hb, wf1b, Pb);
    k_fc1red<<<32, 256, 0, stream>>>(Pb, F);
    k_fcfin<<<1, 256, 0, stream>>>(F, bf1, gf, bef, Wf2, bf2, (float*)d_out);
}

// Round 11
// 897.836 us; speedup vs baseline: 2.5217x; 1.0131x over previous
//
#include <hip/hip_runtime.h>

typedef __bf16 bfrag __attribute__((ext_vector_type(8)));
typedef float ffrag __attribute__((ext_vector_type(16)));

// ---------------------------------------------------------------------------
// Shapes / constants
// ---------------------------------------------------------------------------
constexpr int Bn  = 128;
constexpr int H0  = 98, Wi0 = 40;
constexpr int KH1 = 20, KW1 = 8, H1 = 79, Wo1 = 33, P1 = H1 * Wo1;   // 2607
constexpr int KH2 = 15, KW2 = 8, H2 = 65, Wo2 = 26, P2 = H2 * Wo2;   // 1690
constexpr int KH3 = 10, KW3 = 8, H3 = 56, Wo3 = 19, P3 = H3 * Wo3;   // 1064
constexpr int M1  = Bn * P1;
constexpr int M2  = Bn * P2;
constexpr int M3  = Bn * P3;
constexpr int KFC = 64 * P3;       // 68096
constexpr int FCCH = 112;          // split-K chunks
constexpr int FCKL = KFC / FCCH;   // 608 = 38 k-steps * 16
constexpr int FCKS = FCKL / 16;    // 38
constexpr float EPSF = 1e-5f;

// ---------------------------------------------------------------------------
// Workspace layout (float slots).  Activations are channel-last [m][64] now.
// ---------------------------------------------------------------------------
constexpr size_t oA   = 0;
constexpr size_t oB   = oA  + (size_t)Bn * 64 * P1;          // 21,356,544
constexpr size_t oHB  = oB;                                  // hb bf16 (4,358,144 fl)
constexpr size_t oWF  = oB  + 4358144;                       // Wf1b bf16 (2,179,072 fl)
constexpr size_t oW2  = oB  + (size_t)Bn * 62 * P1;          // wq2f @ +20.69M
constexpr size_t oW3  = oW2 + 245760;                        // wq3f
constexpr size_t oW1  = oW3 + 163840;                        // wq1
constexpr size_t oWM  = oW1 + 5120;                          // wqm (3x2048 fl)
constexpr size_t oBF  = oWM + 6144;                          // folded biases
constexpr size_t oP   = oBF + 128;                           // Pb (112x8192)
constexpr size_t oSt  = oP  + (size_t)FCCH * 8192;           // stats 9x512
constexpr size_t oF   = oSt + 9 * 512;                       // fc1 out (8192)

__device__ __forceinline__ float wred(float v) {
    #pragma unroll
    for (int o = 32; o > 0; o >>= 1) v += __shfl_down(v, o);
    return v;
}

__device__ __forceinline__ float bank4(const float* stp, int c) {
    return stp[c] + stp[128 + c] + stp[256 + c] + stp[384 + c];
}

// ---------------------------------------------------------------------------
// prep: zero stats + pack wq1 + pack mix matrices
// ---------------------------------------------------------------------------
constexpr int NZ  = 9 * 512;
constexpr int NW1 = 10240;
constexpr int NWM = 3 * 4096;
constexpr int NPREP = NZ + NW1 + NWM;
__global__ __launch_bounds__(256) void k_prep_all(
    const float* __restrict__ W11, const float* __restrict__ W13,
    const float* __restrict__ W23, const float* __restrict__ W33,
    __bf16* __restrict__ wq1, __bf16* __restrict__ wqm,
    float* __restrict__ st)
{
    int idx = blockIdx.x * 256 + threadIdx.x;
    if (idx < NZ) { st[idx] = 0.f; return; }
    idx -= NZ;
    if (idx < NW1) {
        int j = idx & 7, oc = (idx >> 3) & 63, khh = idx >> 9;
        wq1[idx] = (__bf16)W11[(size_t)oc * 160 + khh * 8 + j];
        return;
    }
    idx -= NW1;
    if (idx < NWM) {
        int which = idx >> 12, r = idx & 4095;
        int j = r & 7, oc = (r >> 3) & 63, sub = (r >> 9) & 1, ks = r >> 10;
        int k = ks * 16 + sub * 8 + j;
        const float* Wm = which == 0 ? W13 : (which == 1 ? W23 : W33);
        wqm[idx] = (k < 62) ? (__bf16)Wm[oc * 62 + k] : (__bf16)0.f;
    }
}

// ---------------------------------------------------------------------------
// fold BN affine into conv weights (stats 4-banked)
// ---------------------------------------------------------------------------
template <int KH, int KW>
__global__ __launch_bounds__(256) void k_foldw(
    const float* __restrict__ W, const float* __restrict__ stp,
    const float* __restrict__ g, const float* __restrict__ be,
    float inv, const float* __restrict__ bias,
    __bf16* __restrict__ wqf, float* __restrict__ biasf)
{
    constexpr int KK = KH * KW;
    __shared__ float sSc[64], sSh[64], ls[4];
    const int t = threadIdx.x;
    if (t < 64) {
        float mm = bank4(stp, t) * inv;
        float vv = bank4(stp, 64 + t) * inv - mm * mm;
        float sc = g[t] * rsqrtf(vv + EPSF);
        sSc[t] = sc;
        sSh[t] = be[t] - mm * sc;
    }
    __syncthreads();
    const int oc = blockIdx.x;
    float local = 0.f;
    for (int i = t; i < 64 * KK; i += 256) {
        int ic = i / KK, rem = i - ic * KK;
        int kh = rem / KW, kw = rem - kh * KW;
        float wv = W[(((size_t)oc * 64 + ic) * KH + kh) * KW + kw];
        int c = ic >> 4, sub = (ic >> 3) & 1, j = ic & 7, pos = kh * KW + kw;
        wqf[(size_t)pos * 4096 + c * 1024 + sub * 512 + oc * 8 + j] = (__bf16)(wv * sSc[ic]);
        local += wv * sSh[ic];
    }
    local = wred(local);
    int wv2 = t >> 6, ln = t & 63;
    if (ln == 0) ls[wv2] = local;
    __syncthreads();
    if (t == 0) biasf[oc] = bias[oc] + ls[0] + ls[1] + ls[2] + ls[3];
}

// ---------------------------------------------------------------------------
// conv1 MFMA: x -> out fp32 channel-last [m][64], fused 4-banked ch-stats
// ---------------------------------------------------------------------------
constexpr int C1COPY = 1736;
__global__ __launch_bounds__(256, 2) void k_conv1m(
    const float* __restrict__ x, const __bf16* __restrict__ wq,
    const float* __restrict__ bias, float* __restrict__ out,
    float* __restrict__ sto)
{
    const int b = blockIdx.y;
    const int m0 = blockIdx.x * 512;
    const int t = threadIdx.x, lane = t & 63, wv = t >> 6;
    const int l31 = lane & 31, lh = lane >> 5;
    __shared__ __align__(16) __bf16 X8[8 * C1COPY];

    const int oh_lo = m0 / Wo1;
    int abase[4];
    #pragma unroll
    for (int mt = 0; mt < 4; ++mt) {
        int m = m0 + wv * 128 + mt * 32 + l31;
        int mc = m > P1 - 1 ? P1 - 1 : m;
        int oh = mc / Wo1, ow = mc - oh * Wo1;
        int s = ow & 7;
        abase[mt] = s * C1COPY + (oh - oh_lo) * 48 + (ow - s);
    }
    for (int idx = t; idx < 8 * 36 * 6; idx += 256) {
        int s = idx / 216; int rr = idx - s * 216;
        int r = rr / 6, q = rr - r * 6;
        int ih = oh_lo + r; if (ih > H0 - 1) ih = H0 - 1;
        const float* src = x + ((size_t)b * H0 + ih) * Wi0;
        __bf16 tmp[8] __attribute__((aligned(16)));
        #pragma unroll
        for (int j = 0; j < 8; ++j) {
            int col = q * 8 + s + j; if (col > Wi0 - 1) col = Wi0 - 1;
            tmp[j] = (__bf16)src[col];
        }
        *(uint4*)&X8[s * C1COPY + r * 48 + q * 8] = *(uint4*)tmp;
    }
    __syncthreads();

    ffrag acc[4][2] = {};
    #pragma unroll 1
    for (int st2 = 0; st2 < 10; ++st2) {
        const int khl = st2 * 2 + lh;
        const __bf16* wp = wq + ((size_t)khl * 64 + l31) * 8;
        bfrag b0 = *(const bfrag*)(wp);
        bfrag b1 = *(const bfrag*)(wp + 256);
        #pragma unroll
        for (int mt = 0; mt < 4; ++mt) {
            bfrag a = *(const bfrag*)&X8[abase[mt] + khl * 48];
            acc[mt][0] = __builtin_amdgcn_mfma_f32_32x32x16_bf16(a, b0, acc[mt][0], 0, 0, 0);
            acc[mt][1] = __builtin_amdgcn_mfma_f32_32x32x16_bf16(a, b1, acc[mt][1], 0, 0, 0);
        }
    }

    float sS[2] = {0.f, 0.f}, sSS[2] = {0.f, 0.f};
    #pragma unroll
    for (int nt = 0; nt < 2; ++nt) {
        int oc = nt * 32 + l31;
        float bv = bias[oc];
        float* op = out + (size_t)b * P1 * 64 + oc;
        #pragma unroll
        for (int mt = 0; mt < 4; ++mt) {
            int mbase = m0 + wv * 128 + mt * 32 + lh * 4;
            #pragma unroll
            for (int g = 0; g < 4; ++g) {
                #pragma unroll
                for (int q = 0; q < 4; ++q) {
                    int mr = mbase + g * 8 + q;
                    if (mr < P1) {
                        float v = acc[mt][nt][g * 4 + q] + bv;
                        op[(size_t)mr * 64] = v;
                        sS[nt] += v; sSS[nt] += v * v;
                    }
                }
            }
        }
    }
    #pragma unroll
    for (int nt = 0; nt < 2; ++nt) {
        sS[nt]  += __shfl_down(sS[nt], 32);
        sSS[nt] += __shfl_down(sSS[nt], 32);
    }
    __syncthreads();
    float* redS  = (float*)X8;
    float* redSS = redS + 256;
    if (lane < 32) {
        #pragma unroll
        for (int nt = 0; nt < 2; ++nt) {
            redS[wv * 64 + nt * 32 + l31]  = sS[nt];
            redSS[wv * 64 + nt * 32 + l31] = sSS[nt];
        }
    }
    __syncthreads();
    if (t < 64) {
        int bank = ((blockIdx.x ^ blockIdx.y) & 3) * 128;
        atomicAdd(&sto[bank + t],      redS[t] + redS[64 + t] + redS[128 + t] + redS[192 + t]);
        atomicAdd(&sto[bank + 64 + t], redSS[t] + redSS[64 + t] + redSS[128 + t] + redSS[192 + t]);
    }
}

// ---------------------------------------------------------------------------
// lc: channel-last fp32 in [m][64]; per-ch affine + relu, 3-tap -> bf16
// Z[m][64]; fused global stats (64 slots). Fully unrolled (no scratch).
// ---------------------------------------------------------------------------
template <int POS>
__global__ __launch_bounds__(256) void k_lc(const float* __restrict__ in,
                                            const float* __restrict__ stp,
                                            const float* __restrict__ g,
                                            const float* __restrict__ be,
                                            float inv,
                                            const float* __restrict__ lcw,
                                            const float* __restrict__ lcb,
                                            __bf16* __restrict__ Z,
                                            float* __restrict__ sto) {
    __shared__ float sAff[128];
    __shared__ float sred[4], ssred[4];
    if (threadIdx.x < 64) {
        int tt = threadIdx.x;
        float mm = bank4(stp, tt) * inv;
        float vv = bank4(stp, 64 + tt) * inv - mm * mm;
        float sc = g[tt] * rsqrtf(vv + EPSF);
        sAff[tt] = sc;
        sAff[64 + tt] = be[tt] - mm * sc;
    }
    __syncthreads();
    int morig = blockIdx.x * 256 + threadIdx.x;
    bool valid = morig < Bn * POS;
    int m = valid ? morig : Bn * POS - 1;
    const float* ip = in + (size_t)m * 64;
    float xv[64];
    #pragma unroll
    for (int j = 0; j < 16; ++j)
        *(float4*)&xv[j * 4] = *(const float4*)(ip + j * 4);
    __bf16 zb[64] __attribute__((aligned(16)));
    zb[62] = (__bf16)0.f; zb[63] = (__bf16)0.f;
    float ts = 0.f, tss = 0.f;
    float y0 = fmaxf(sAff[0] * xv[0] + sAff[64], 0.f);
    float y1 = fmaxf(sAff[1] * xv[1] + sAff[65], 0.f);
    #pragma unroll
    for (int c = 0; c < 62; ++c) {
        float y2 = fmaxf(sAff[c + 2] * xv[c + 2] + sAff[64 + c + 2], 0.f);
        float o = lcb[c] + y0 * lcw[c * 3] + y1 * lcw[c * 3 + 1] + y2 * lcw[c * 3 + 2];
        zb[c] = (__bf16)o;
        if (valid) { ts += o; tss += o * o; }
        y0 = y1; y1 = y2;
    }
    __bf16* zp = Z + (size_t)m * 64;
    #pragma unroll
    for (int j = 0; j < 8; ++j)
        *(uint4*)(zp + j * 8) = *(uint4*)(zb + j * 8);
    ts = wred(ts); tss = wred(tss);
    int wv = threadIdx.x >> 6, ln = threadIdx.x & 63;
    if (ln == 0) { sred[wv] = ts; ssred[wv] = tss; }
    __syncthreads();
    if (threadIdx.x == 0) {
        int slot = blockIdx.x & 63;
        atomicAdd(&sto[slot],      sred[0] + sred[1] + sred[2] + sred[3]);
        atomicAdd(&sto[64 + slot], ssred[0] + ssred[1] + ssred[2] + ssred[3]);
    }
}

// ---------------------------------------------------------------------------
// mix as MFMA; OUTBF: bf16 conv-input layout; else fp32 channel-last [m][64]
// ---------------------------------------------------------------------------
template <int POS, int IH, int IW, bool OUTBF>
__global__ __launch_bounds__(256, 2) void k_mixm(
    const __bf16* __restrict__ Z, const float* __restrict__ stp,
    const float* __restrict__ g, const float* __restrict__ be,
    float inv, const __bf16* __restrict__ wqm,
    const float* __restrict__ bm, void* __restrict__ outv,
    float* __restrict__ sto)
{
    const int b = blockIdx.y;
    const int m0 = blockIdx.x * 512;
    const int t = threadIdx.x, lane = t & 63, wv = t >> 6;
    const int l31 = lane & 31, lh = lane >> 5;

    float gs = 0.f, gss = 0.f;
    #pragma unroll
    for (int i = 0; i < 64; ++i) { gs += stp[i]; gss += stp[64 + i]; }
    float mm = gs * inv;
    float vv = gss * inv - mm * mm;
    float s0 = g[0] * rsqrtf(vv + EPSF);
    float t0 = be[0] - mm * s0;

    size_t zbase[4];
    #pragma unroll
    for (int mt = 0; mt < 4; ++mt) {
        int m = m0 + wv * 128 + mt * 32 + l31;
        int mc = m > POS - 1 ? POS - 1 : m;
        zbase[mt] = ((size_t)b * POS + mc) * 64;
    }

    ffrag acc[4][2] = {};
    #pragma unroll
    for (int ks = 0; ks < 4; ++ks) {
        const __bf16* wp = wqm + ks * 1024 + lh * 512 + l31 * 8;
        bfrag b0 = *(const bfrag*)wp;
        bfrag b1 = *(const bfrag*)(wp + 256);
        #pragma unroll
        for (int mt = 0; mt < 4; ++mt) {
            uint4 raw = *(const uint4*)(Z + zbase[mt] + ks * 16 + lh * 8);
            const __bf16* zin = (const __bf16*)&raw;
            __bf16 zout[8] __attribute__((aligned(16)));
            #pragma unroll
            for (int j = 0; j < 8; ++j) {
                float f = (float)zin[j];
                zout[j] = (__bf16)fmaxf(fmaf(s0, f, t0), 0.f);
            }
            bfrag a = *(const bfrag*)zout;
            acc[mt][0] = __builtin_amdgcn_mfma_f32_32x32x16_bf16(a, b0, acc[mt][0], 0, 0, 0);
            acc[mt][1] = __builtin_amdgcn_mfma_f32_32x32x16_bf16(a, b1, acc[mt][1], 0, 0, 0);
        }
    }

    float sS[2] = {0.f, 0.f}, sSS[2] = {0.f, 0.f};
    #pragma unroll
    for (int nt = 0; nt < 2; ++nt) {
        int oc = nt * 32 + l31;
        float bv = bm[oc];
        if constexpr (OUTBF) {
            __bf16* op = (__bf16*)outv;
            #pragma unroll
            for (int mt = 0; mt < 4; ++mt) {
                int mbase = m0 + wv * 128 + mt * 32 + lh * 4;
                #pragma unroll
                for (int g4 = 0; g4 < 4; ++g4) {
                    #pragma unroll
                    for (int q = 0; q < 4; ++q) {
                        int mr = mbase + g4 * 8 + q;
                        if (mr < POS) {
                            float v = acc[mt][nt][g4 * 4 + q] + bv;
                            int ih = mr / IW, iw = mr - ih * IW;
                            op[((size_t)(b * IH + ih) * 2 + nt) * (IW * 32) + iw * 32 + l31] = (__bf16)v;
                            sS[nt] += v; sSS[nt] += v * v;
                        }
                    }
                }
            }
        } else {
            float* op = (float*)outv + (size_t)b * POS * 64 + oc;
            #pragma unroll
            for (int mt = 0; mt < 4; ++mt) {
                int mbase = m0 + wv * 128 + mt * 32 + lh * 4;
                #pragma unroll
                for (int g4 = 0; g4 < 4; ++g4) {
                    #pragma unroll
                    for (int q = 0; q < 4; ++q) {
                        int mr = mbase + g4 * 8 + q;
                        if (mr < POS) {
                            float v = acc[mt][nt][g4 * 4 + q] + bv;
                            op[(size_t)mr * 64] = v;
                            sS[nt] += v; sSS[nt] += v * v;
                        }
                    }
                }
            }
        }
    }
    #pragma unroll
    for (int nt = 0; nt < 2; ++nt) {
        sS[nt]  += __shfl_down(sS[nt], 32);
        sSS[nt] += __shfl_down(sSS[nt], 32);
    }
    __shared__ float red[512];
    if (lane < 32) {
        #pragma unroll
        for (int nt = 0; nt < 2; ++nt) {
            red[wv * 64 + nt * 32 + l31]       = sS[nt];
            red[256 + wv * 64 + nt * 32 + l31] = sSS[nt];
        }
    }
    __syncthreads();
    if (t < 64) {
        int bank = ((blockIdx.x ^ blockIdx.y) & 3) * 128;
        atomicAdd(&sto[bank + t],      red[t] + red[64 + t] + red[128 + t] + red[192 + t]);
        atomicAdd(&sto[bank + 64 + t], red[256 + t] + red[320 + t] + red[384 + t] + red[448 + t]);
    }
}

// ---------------------------------------------------------------------------
// implicit-GEMM conv: MT m-tiles/wave, wrap-safe bijective swizzle,
// channel-last fp32 out [m][64], 4-banked stats
// swizzle key(X) = (X ^ (X>>3)) & 7: bit2(key)=X2^X5 invariant under bit0(X)
// -> (2q,2q+1) slot pairs disjoint (bijective); X -> X+8 changes key
// -> row-wrap (ΔX=8) no longer aliases bank groups.
// ---------------------------------------------------------------------------
template <int KH, int KW, int IH, int IW, int OH, int OW, int NR, int MT>
__global__ __launch_bounds__(256, 2) void k_convmfma(
    const __bf16* __restrict__ in,
    const __bf16* __restrict__ wq,
    const float* __restrict__ bias,
    float* __restrict__ out,
    float* __restrict__ sto)
{
    constexpr int P = OH * OW;
    constexpr int MB = 128 * MT;
    const int b  = blockIdx.y;
    const int m0 = blockIdx.x * MB;
    const int t  = threadIdx.x;
    const int lane = t & 63;
    const int wv = t >> 6;
    const int l31 = lane & 31, lh = lane >> 5;

    __shared__ __align__(16) __bf16 As[NR * IW * 32 + 64];

    const int oh_lo = m0 / OW;
    int posm[MT];
    #pragma unroll
    for (int mt = 0; mt < MT; ++mt) {
        int m = m0 + wv * (32 * MT) + mt * 32 + l31;
        int mc = m > P - 1 ? P - 1 : m;
        int oh = mc / OW, ow = mc - oh * OW;
        posm[mt] = (oh - oh_lo) * IW + ow;
    }

    ffrag acc[MT][2] = {};

    for (int ich = 0; ich < 2; ++ich) {
        __syncthreads();
        constexpr int ROWCH = IW * 4;
        constexpr int CH = NR * ROWCH;
        for (int idx = t; idx < CH; idx += 256) {
            int r = idx / ROWCH, o = idx - r * ROWCH;
            int ih = oh_lo + r; if (ih > IH - 1) ih = IH - 1;
            const __bf16* src = in + ((size_t)(b * IH + ih) * 2 + ich) * (IW * 32) + o * 8;
            int Xw = idx >> 2;
            int sw = idx ^ ((Xw ^ (Xw >> 3)) & 7);
            *(uint4*)&As[sw * 8] = *(const uint4*)src;
        }
        __syncthreads();

        const __bf16* wich = wq + ich * 2048;
        for (int kh = 0; kh < KH; ++kh) {
            const int rowoff = kh * IW;
            const __bf16* wkh = wich + (size_t)(kh * KW) * 4096 + lh * 512 + l31 * 8;
            #pragma unroll 2
            for (int kw = 0; kw < KW; ++kw) {
                const __bf16* wp = wkh + kw * 4096;
                #pragma unroll
                for (int cc = 0; cc < 2; ++cc) {
                    bfrag b0 = *(const bfrag*)(wp + cc * 1024);
                    bfrag b1 = *(const bfrag*)(wp + cc * 1024 + 256);
                    #pragma unroll
                    for (int mt = 0; mt < MT; ++mt) {
                        int X = posm[mt] + rowoff + kw;
                        int gc = (X << 2) + cc * 2 + lh;
                        int sw = gc ^ ((X ^ (X >> 3)) & 7);
                        bfrag a = *(const bfrag*)&As[sw * 8];
                        acc[mt][0] = __builtin_amdgcn_mfma_f32_32x32x16_bf16(a, b0, acc[mt][0], 0, 0, 0);
                        acc[mt][1] = __builtin_amdgcn_mfma_f32_32x32x16_bf16(a, b1, acc[mt][1], 0, 0, 0);
                    }
                }
            }
        }
    }

    float sS[2] = {0.f, 0.f}, sSS[2] = {0.f, 0.f};
    #pragma unroll
    for (int nt = 0; nt < 2; ++nt) {
        int oc = nt * 32 + l31;
        float bv = bias[oc];
        float* op = out + (size_t)b * P * 64 + oc;
        #pragma unroll
        for (int mt = 0; mt < MT; ++mt) {
            int mbase = m0 + wv * (32 * MT) + mt * 32 + lh * 4;
            #pragma unroll
            for (int g = 0; g < 4; ++g) {
                #pragma unroll
                for (int q = 0; q < 4; ++q) {
                    int mr = mbase + g * 8 + q;
                    if (mr < P) {
                        float v = acc[mt][nt][g * 4 + q] + bv;
                        op[(size_t)mr * 64] = v;
                        sS[nt] += v; sSS[nt] += v * v;
                    }
                }
            }
        }
    }
    #pragma unroll
    for (int nt = 0; nt < 2; ++nt) {
        sS[nt]  += __shfl_down(sS[nt], 32);
        sSS[nt] += __shfl_down(sSS[nt], 32);
    }
    __syncthreads();
    float* redS  = (float*)As;
    float* redSS = redS + 256;
    if (lane < 32) {
        #pragma unroll
        for (int nt = 0; nt < 2; ++nt) {
            redS[wv * 64 + nt * 32 + l31]  = sS[nt];
            redSS[wv * 64 + nt * 32 + l31] = sSS[nt];
        }
    }
    __syncthreads();
    if (t < 64) {
        int bank = ((blockIdx.x ^ blockIdx.y) & 3) * 128;
        atomicAdd(&sto[bank + t],      redS[t] + redS[64 + t] + redS[128 + t] + redS[192 + t]);
        atomicAdd(&sto[bank + 64 + t], redSS[t] + redSS[64 + t] + redSS[128 + t] + redSS[192 + t]);
    }
}

// ---------------------------------------------------------------------------
// prep_hb: Y fp32 channel-last [m][64] + affine -> hb bf16 flat (same order),
// Wf1 -> bf16 with matching k-permutation k' = p*64+c.
// ---------------------------------------------------------------------------
constexpr int NHB  = M3 * 64 / 8;        // 1,089,536
constexpr int NWFB = 64 * KFC / 8;       // 544,768
__global__ __launch_bounds__(256) void k_prep_hb(
    const float* __restrict__ Y, const float* __restrict__ stp,
    const float* __restrict__ g, const float* __restrict__ be, float inv,
    const float* __restrict__ Wf1,
    __bf16* __restrict__ hb, __bf16* __restrict__ wf1b)
{
    __shared__ float sA[128];
    if (threadIdx.x < 64) {
        int c = threadIdx.x;
        float mm = bank4(stp, c) * inv;
        float vv = bank4(stp, 64 + c) * inv - mm * mm;
        float sc = g[c] * rsqrtf(vv + EPSF);
        sA[c] = sc; sA[64 + c] = be[c] - mm * sc;
    }
    __syncthreads();
    int idx = blockIdx.x * 256 + threadIdx.x;
    if (idx < NHB) {
        size_t base = (size_t)idx * 8;
        int c0 = (int)(base & 63);
        __bf16 tmp[8] __attribute__((aligned(16)));
        #pragma unroll
        for (int j = 0; j < 8; ++j)
            tmp[j] = (__bf16)(sA[c0 + j] * Y[base + j] + sA[64 + c0 + j]);
        *(uint4*)(hb + base) = *(uint4*)tmp;
        return;
    }
    idx -= NHB;
    if (idx < NWFB) {
        size_t base = (size_t)idx * 8;
        int f = (int)(base / KFC);
        int r = (int)(base - (size_t)f * KFC);    // r = p*64 + c0
        int p = r >> 6, c0 = r & 63;
        __bf16 tmp[8] __attribute__((aligned(16)));
        #pragma unroll
        for (int j = 0; j < 8; ++j)
            tmp[j] = (__bf16)Wf1[(size_t)f * KFC + (size_t)(c0 + j) * P3 + p];
        *(uint4*)(wf1b + base) = *(uint4*)tmp;
    }
}

// ---------------------------------------------------------------------------
// fc1 as MFMA: [128 x K] x [K x 64], split-K 112 chunks of 608
// ---------------------------------------------------------------------------
__global__ __launch_bounds__(256) void k_fc1m(const __bf16* __restrict__ hb,
                                              const __bf16* __restrict__ wf1b,
                                              float* __restrict__ Pb) {
    const int kc = blockIdx.x;
    const int t = threadIdx.x, lane = t & 63, wv = t >> 6;
    const int l31 = lane & 31, lh = lane >> 5;
    const int k0 = kc * FCKL;

    const __bf16* ap = hb + (size_t)(wv * 32 + l31) * KFC + k0 + lh * 8;
    const __bf16* bp0 = wf1b + (size_t)l31 * KFC + k0 + lh * 8;
    const __bf16* bp1 = wf1b + (size_t)(32 + l31) * KFC + k0 + lh * 8;

    ffrag acc[2] = {};
    #pragma unroll 2
    for (int ks = 0; ks < FCKS; ++ks) {
        bfrag a  = *(const bfrag*)(ap  + ks * 16);
        bfrag b0 = *(const bfrag*)(bp0 + ks * 16);
        bfrag b1 = *(const bfrag*)(bp1 + ks * 16);
        acc[0] = __builtin_amdgcn_mfma_f32_32x32x16_bf16(a, b0, acc[0], 0, 0, 0);
        acc[1] = __builtin_amdgcn_mfma_f32_32x32x16_bf16(a, b1, acc[1], 0, 0, 0);
    }
    float* pp = Pb + (size_t)kc * 8192;
    #pragma unroll
    for (int nt = 0; nt < 2; ++nt) {
        #pragma unroll
        for (int g = 0; g < 4; ++g) {
            #pragma unroll
            for (int q = 0; q < 4; ++q) {
                int row = q + g * 8 + lh * 4;
                int bb = wv * 32 + row;
                pp[bb * 64 + nt * 32 + l31] = acc[nt][g * 4 + q];
            }
        }
    }
}

__global__ __launch_bounds__(256) void k_fc1red(const float* __restrict__ Pb,
                                                float* __restrict__ F) {
    int m = blockIdx.x * 256 + threadIdx.x;
    float s = 0.f;
    for (int kc = 0; kc < FCCH; ++kc) s += Pb[(size_t)kc * 8192 + m];
    F[m] = s;
}

__global__ __launch_bounds__(256) void k_fcfin(const float* __restrict__ F,
                                               const float* __restrict__ bf1,
                                               const float* __restrict__ gf,
                                               const float* __restrict__ bef,
                                               const float* __restrict__ Wf2,
                                               const float* __restrict__ bf2,
                                               float* __restrict__ out) {
    __shared__ float sF[8192];
    __shared__ float sfa[128];
    const int t = threadIdx.x;
    for (int m = t; m < 8192; m += 256) sF[m] = F[m];
    __syncthreads();
    if (t < 64) {
        float s = 0.f, ss = 0.f;
        for (int b = 0; b < Bn; ++b) {
            float v = sF[b * 64 + t] + bf1[t];
            s += v; ss += v * v;
        }
        float m  = s / 128.f;
        float va = ss / 128.f - m * m;
        float sc = gf[t] * rsqrtf(va + EPSF);
        sfa[t] = sc;
        sfa[64 + t] = sc * bf1[t] + bef[t] - m * sc;
    }
    __syncthreads();
    for (int m = t; m < Bn * 35; m += 256) {
        int b = m / 35, o = m - b * 35;
        float acc = bf2[o];
        for (int ff = 0; ff < 64; ++ff) {
            int f = (ff + t) & 63;
            float z = fmaxf(sfa[f] * sF[b * 64 + f] + sfa[64 + f], 0.f);
            acc += z * Wf2[o * 64 + f];
        }
        out[m] = acc;
    }
}

// ---------------------------------------------------------------------------
// launch
// ---------------------------------------------------------------------------
extern "C" void kernel_launch(void* const* d_in, const int* in_sizes, int n_in,
                              void* d_out, int out_size, void* d_ws, size_t ws_size,
                              hipStream_t stream) {
    const float* x    = (const float*)d_in[0];
    const float* W11  = (const float*)d_in[1];
    const float* b11  = (const float*)d_in[2];
    const float* g11  = (const float*)d_in[3];
    const float* be11 = (const float*)d_in[4];
    const float* lc1w = (const float*)d_in[5];
    const float* lc1b = (const float*)d_in[6];
    const float* g12  = (const float*)d_in[7];
    const float* be12 = (const float*)d_in[8];
    const float* W13  = (const float*)d_in[9];
    const float* b13  = (const float*)d_in[10];
    const float* g13  = (const float*)d_in[11];
    const float* be13 = (const float*)d_in[12];
    const float* W21  = (const float*)d_in[13];
    const float* b21  = (const float*)d_in[14];
    const float* g21  = (const float*)d_in[15];
    const float* be21 = (const float*)d_in[16];
    const float* lc2w = (const float*)d_in[17];
    const float* lc2b = (const float*)d_in[18];
    const float* g22  = (const float*)d_in[19];
    const float* be22 = (const float*)d_in[20];
    const float* W23  = (const float*)d_in[21];
    const float* b23  = (const float*)d_in[22];
    const float* g23  = (const float*)d_in[23];
    const float* be23 = (const float*)d_in[24];
    const float* W31  = (const float*)d_in[25];
    const float* b31  = (const float*)d_in[26];
    const float* g31  = (const float*)d_in[27];
    const float* be31 = (const float*)d_in[28];
    const float* lc3w = (const float*)d_in[29];
    const float* lc3b = (const float*)d_in[30];
    const float* g32  = (const float*)d_in[31];
    const float* be32 = (const float*)d_in[32];
    const float* W33  = (const float*)d_in[33];
    const float* b33  = (const float*)d_in[34];
    const float* g33  = (const float*)d_in[35];
    const float* be33 = (const float*)d_in[36];
    const float* Wf1  = (const float*)d_in[37];
    const float* bf1  = (const float*)d_in[38];
    const float* gf   = (const float*)d_in[39];
    const float* bef  = (const float*)d_in[40];
    const float* Wf2  = (const float*)d_in[41];
    const float* bf2  = (const float*)d_in[42];

    float* ws  = (float*)d_ws;
    float* A   = ws + oA;
    float* Bb  = ws + oB;
    __bf16* Abf = (__bf16*)(ws + oA);
    __bf16* Bbf = (__bf16*)(ws + oB);
    __bf16* hb   = (__bf16*)(ws + oHB);
    __bf16* wf1b = (__bf16*)(ws + oWF);
    __bf16* wq2f = (__bf16*)(ws + oW2);
    __bf16* wq3f = (__bf16*)(ws + oW3);
    __bf16* wq1  = (__bf16*)(ws + oW1);
    __bf16* wqm  = (__bf16*)(ws + oWM);
    float* bfold = ws + oBF;
    float* Pb  = ws + oP;
    float* st  = ws + oSt;
    float* F   = ws + oF;

    const int blk1 = (M1 + 255) / 256;
    const int blk2 = M2 / 256;
    const int blk3 = M3 / 256;

    k_prep_all<<<(NPREP + 255) / 256, 256, 0, stream>>>(W11, W13, W23, W33, wq1, wqm, st);

    // ---- stage 1 ----
    k_conv1m<<<dim3((P1 + 511) / 512, Bn), 256, 0, stream>>>(x, wq1, b11, A, st + 0 * 512);
    k_lc<P1><<<blk1, 256, 0, stream>>>(A, st + 0 * 512, g11, be11, 1.0f / (float)M1,
                                       lc1w, lc1b, Bbf, st + 1 * 512);
    k_mixm<P1, H1, Wo1, true><<<dim3((P1 + 511) / 512, Bn), 256, 0, stream>>>(
        Bbf, st + 1 * 512, g12, be12, 1.0f / (62.0f * (float)M1),
        wqm + 0 * 4096, b13, (void*)Abf, st + 2 * 512);

    // ---- stage 2 ----
    k_foldw<KH2, KW2><<<64, 256, 0, stream>>>(W21, st + 2 * 512, g13, be13,
                                              1.0f / (float)M1, b21, wq2f, bfold + 0);
    k_convmfma<KH2, KW2, H1, Wo1, H2, Wo2, 35, 4>
        <<<dim3((P2 + 511) / 512, Bn), 256, 0, stream>>>(Abf, wq2f, bfold + 0, Bb, st + 3 * 512);
    k_lc<P2><<<blk2, 256, 0, stream>>>(Bb, st + 3 * 512, g21, be21, 1.0f / (float)M2,
                                       lc2w, lc2b, Abf, st + 4 * 512);
    k_mixm<P2, H2, Wo2, true><<<dim3((P2 + 511) / 512, Bn), 256, 0, stream>>>(
        Abf, st + 4 * 512, g22, be22, 1.0f / (62.0f * (float)M2),
        wqm + 1 * 4096, b23, (void*)Bbf, st + 5 * 512);

    // ---- stage 3 ----
    k_foldw<KH3, KW3><<<64, 256, 0, stream>>>(W31, st + 5 * 512, g23, be23,
                                              1.0f / (float)M2, b31, wq3f, bfold + 64);
    k_convmfma<KH3, KW3, H2, Wo2, H3, Wo3, 30, 3>
        <<<dim3((P3 + 383) / 384, Bn), 256, 0, stream>>>(Bbf, wq3f, bfold + 64, A, st + 6 * 512);
    k_lc<P3><<<blk3, 256, 0, stream>>>(A, st + 6 * 512, g31, be31, 1.0f / (float)M3,
                                       lc3w, lc3b, Bbf, st + 7 * 512);
    k_mixm<P3, 1, 1, false><<<dim3((P3 + 511) / 512, Bn), 256, 0, stream>>>(
        Bbf, st + 7 * 512, g32, be32, 1.0f / (62.0f * (float)M3),
        wqm + 2 * 4096, b33, (void*)A, st + 8 * 512);

    // ---- FC head ----
    k_prep_hb<<<(NHB + NWFB + 255) / 256, 256, 0, stream>>>(
        A, st + 8 * 512, g33, be33, 1.0f / (float)M3, Wf1, hb, wf1b);
    k_fc1m<<<FCCH, 256, 0, stream>>>(hb, wf1b, Pb);
    k_fc1red<<<32, 256, 0, stream>>>(Pb, F);
    k_fcfin<<<1, 256, 0, stream>>>(F, bf1, gf, bef, Wf2, bf2, (float*)d_out);
}

// Round 12
// 886.858 us; speedup vs baseline: 2.5529x; 1.0124x over previous
//
#include <hip/hip_runtime.h>

typedef __bf16 bfrag __attribute__((ext_vector_type(8)));
typedef float ffrag __attribute__((ext_vector_type(16)));

// ---------------------------------------------------------------------------
// Shapes / constants
// ---------------------------------------------------------------------------
constexpr int Bn  = 128;
constexpr int H0  = 98, Wi0 = 40;
constexpr int KH1 = 20, KW1 = 8, H1 = 79, Wo1 = 33, P1 = H1 * Wo1;   // 2607
constexpr int KH2 = 15, KW2 = 8, H2 = 65, Wo2 = 26, P2 = H2 * Wo2;   // 1690
constexpr int KH3 = 10, KW3 = 8, H3 = 56, Wo3 = 19, P3 = H3 * Wo3;   // 1064
constexpr int M1  = Bn * P1;
constexpr int M2  = Bn * P2;
constexpr int M3  = Bn * P3;
constexpr int KFC = 64 * P3;       // 68096
constexpr int FCCH = 112;          // split-K chunks
constexpr int FCKL = KFC / FCCH;   // 608 = 38 k-steps * 16
constexpr int FCKS = FCKL / 16;    // 38
constexpr float EPSF = 1e-5f;

// ---------------------------------------------------------------------------
// Workspace layout (float slots).  Activations channel-last [m][64].
// ---------------------------------------------------------------------------
constexpr size_t oA   = 0;
constexpr size_t oB   = oA  + (size_t)Bn * 64 * P1;          // 21,356,544
constexpr size_t oHB  = oB;                                  // hb bf16 (4,358,144 fl)
constexpr size_t oWF  = oB  + 4358144;                       // Wf1b bf16 (2,179,072 fl)
constexpr size_t oW2  = oB  + (size_t)Bn * 62 * P1;          // wq2f @ +20.69M
constexpr size_t oW3  = oW2 + 245760;                        // wq3f
constexpr size_t oW1  = oW3 + 163840;                        // wq1
constexpr size_t oWM  = oW1 + 5120;                          // wqm (3x2048 fl)
constexpr size_t oBF  = oWM + 6144;                          // folded biases
constexpr size_t oP   = oBF + 128;                           // Pb (112x8192)
constexpr size_t oSt  = oP  + (size_t)FCCH * 8192;           // stats 9x512
constexpr size_t oF   = oSt + 9 * 512;                       // fc1 out (8192)

__device__ __forceinline__ float wred(float v) {
    #pragma unroll
    for (int o = 32; o > 0; o >>= 1) v += __shfl_down(v, o);
    return v;
}

__device__ __forceinline__ float bank4(const float* stp, int c) {
    return stp[c] + stp[128 + c] + stp[256 + c] + stp[384 + c];
}

// ---------------------------------------------------------------------------
// prep: zero stats + pack wq1 + pack mix matrices
// ---------------------------------------------------------------------------
constexpr int NZ  = 9 * 512;
constexpr int NW1 = 10240;
constexpr int NWM = 3 * 4096;
constexpr int NPREP = NZ + NW1 + NWM;
__global__ __launch_bounds__(256) void k_prep_all(
    const float* __restrict__ W11, const float* __restrict__ W13,
    const float* __restrict__ W23, const float* __restrict__ W33,
    __bf16* __restrict__ wq1, __bf16* __restrict__ wqm,
    float* __restrict__ st)
{
    int idx = blockIdx.x * 256 + threadIdx.x;
    if (idx < NZ) { st[idx] = 0.f; return; }
    idx -= NZ;
    if (idx < NW1) {
        int j = idx & 7, oc = (idx >> 3) & 63, khh = idx >> 9;
        wq1[idx] = (__bf16)W11[(size_t)oc * 160 + khh * 8 + j];
        return;
    }
    idx -= NW1;
    if (idx < NWM) {
        int which = idx >> 12, r = idx & 4095;
        int j = r & 7, oc = (r >> 3) & 63, sub = (r >> 9) & 1, ks = r >> 10;
        int k = ks * 16 + sub * 8 + j;
        const float* Wm = which == 0 ? W13 : (which == 1 ? W23 : W33);
        wqm[idx] = (k < 62) ? (__bf16)Wm[oc * 62 + k] : (__bf16)0.f;
    }
}

// ---------------------------------------------------------------------------
// fold BN affine into conv weights (stats 4-banked)
// ---------------------------------------------------------------------------
template <int KH, int KW>
__global__ __launch_bounds__(256) void k_foldw(
    const float* __restrict__ W, const float* __restrict__ stp,
    const float* __restrict__ g, const float* __restrict__ be,
    float inv, const float* __restrict__ bias,
    __bf16* __restrict__ wqf, float* __restrict__ biasf)
{
    constexpr int KK = KH * KW;
    __shared__ float sSc[64], sSh[64], ls[4];
    const int t = threadIdx.x;
    if (t < 64) {
        float mm = bank4(stp, t) * inv;
        float vv = bank4(stp, 64 + t) * inv - mm * mm;
        float sc = g[t] * rsqrtf(vv + EPSF);
        sSc[t] = sc;
        sSh[t] = be[t] - mm * sc;
    }
    __syncthreads();
    const int oc = blockIdx.x;
    float local = 0.f;
    for (int i = t; i < 64 * KK; i += 256) {
        int ic = i / KK, rem = i - ic * KK;
        int kh = rem / KW, kw = rem - kh * KW;
        float wv = W[(((size_t)oc * 64 + ic) * KH + kh) * KW + kw];
        int c = ic >> 4, sub = (ic >> 3) & 1, j = ic & 7, pos = kh * KW + kw;
        wqf[(size_t)pos * 4096 + c * 1024 + sub * 512 + oc * 8 + j] = (__bf16)(wv * sSc[ic]);
        local += wv * sSh[ic];
    }
    local = wred(local);
    int wv2 = t >> 6, ln = t & 63;
    if (ln == 0) ls[wv2] = local;
    __syncthreads();
    if (t == 0) biasf[oc] = bias[oc] + ls[0] + ls[1] + ls[2] + ls[3];
}

// ---------------------------------------------------------------------------
// conv1 MFMA: x -> out fp32 channel-last [m][64], fused 4-banked ch-stats
// ---------------------------------------------------------------------------
constexpr int C1COPY = 1736;
__global__ __launch_bounds__(256, 2) void k_conv1m(
    const float* __restrict__ x, const __bf16* __restrict__ wq,
    const float* __restrict__ bias, float* __restrict__ out,
    float* __restrict__ sto)
{
    const int b = blockIdx.y;
    const int m0 = blockIdx.x * 512;
    const int t = threadIdx.x, lane = t & 63, wv = t >> 6;
    const int l31 = lane & 31, lh = lane >> 5;
    __shared__ __align__(16) __bf16 X8[8 * C1COPY];

    const int oh_lo = m0 / Wo1;
    int abase[4];
    #pragma unroll
    for (int mt = 0; mt < 4; ++mt) {
        int m = m0 + wv * 128 + mt * 32 + l31;
        int mc = m > P1 - 1 ? P1 - 1 : m;
        int oh = mc / Wo1, ow = mc - oh * Wo1;
        int s = ow & 7;
        abase[mt] = s * C1COPY + (oh - oh_lo) * 48 + (ow - s);
    }
    for (int idx = t; idx < 8 * 36 * 6; idx += 256) {
        int s = idx / 216; int rr = idx - s * 216;
        int r = rr / 6, q = rr - r * 6;
        int ih = oh_lo + r; if (ih > H0 - 1) ih = H0 - 1;
        const float* src = x + ((size_t)b * H0 + ih) * Wi0;
        __bf16 tmp[8] __attribute__((aligned(16)));
        #pragma unroll
        for (int j = 0; j < 8; ++j) {
            int col = q * 8 + s + j; if (col > Wi0 - 1) col = Wi0 - 1;
            tmp[j] = (__bf16)src[col];
        }
        *(uint4*)&X8[s * C1COPY + r * 48 + q * 8] = *(uint4*)tmp;
    }
    __syncthreads();

    ffrag acc[4][2] = {};
    #pragma unroll 1
    for (int st2 = 0; st2 < 10; ++st2) {
        const int khl = st2 * 2 + lh;
        const __bf16* wp = wq + ((size_t)khl * 64 + l31) * 8;
        bfrag b0 = *(const bfrag*)(wp);
        bfrag b1 = *(const bfrag*)(wp + 256);
        #pragma unroll
        for (int mt = 0; mt < 4; ++mt) {
            bfrag a = *(const bfrag*)&X8[abase[mt] + khl * 48];
            acc[mt][0] = __builtin_amdgcn_mfma_f32_32x32x16_bf16(a, b0, acc[mt][0], 0, 0, 0);
            acc[mt][1] = __builtin_amdgcn_mfma_f32_32x32x16_bf16(a, b1, acc[mt][1], 0, 0, 0);
        }
    }

    float sS[2] = {0.f, 0.f}, sSS[2] = {0.f, 0.f};
    #pragma unroll
    for (int nt = 0; nt < 2; ++nt) {
        int oc = nt * 32 + l31;
        float bv = bias[oc];
        float* op = out + (size_t)b * P1 * 64 + oc;
        #pragma unroll
        for (int mt = 0; mt < 4; ++mt) {
            int mbase = m0 + wv * 128 + mt * 32 + lh * 4;
            #pragma unroll
            for (int g = 0; g < 4; ++g) {
                #pragma unroll
                for (int q = 0; q < 4; ++q) {
                    int mr = mbase + g * 8 + q;
                    if (mr < P1) {
                        float v = acc[mt][nt][g * 4 + q] + bv;
                        op[(size_t)mr * 64] = v;
                        sS[nt] += v; sSS[nt] += v * v;
                    }
                }
            }
        }
    }
    #pragma unroll
    for (int nt = 0; nt < 2; ++nt) {
        sS[nt]  += __shfl_down(sS[nt], 32);
        sSS[nt] += __shfl_down(sSS[nt], 32);
    }
    __syncthreads();
    float* redS  = (float*)X8;
    float* redSS = redS + 256;
    if (lane < 32) {
        #pragma unroll
        for (int nt = 0; nt < 2; ++nt) {
            redS[wv * 64 + nt * 32 + l31]  = sS[nt];
            redSS[wv * 64 + nt * 32 + l31] = sSS[nt];
        }
    }
    __syncthreads();
    if (t < 64) {
        int bank = ((blockIdx.x ^ blockIdx.y) & 3) * 128;
        atomicAdd(&sto[bank + t],      redS[t] + redS[64 + t] + redS[128 + t] + redS[192 + t]);
        atomicAdd(&sto[bank + 64 + t], redSS[t] + redSS[64 + t] + redSS[128 + t] + redSS[192 + t]);
    }
}

// ---------------------------------------------------------------------------
// lc: channel-last fp32 in [m][64]; per-ch affine + relu, 3-tap -> bf16
// Z[m][64]; fused global stats (64 slots).
// ---------------------------------------------------------------------------
template <int POS>
__global__ __launch_bounds__(256) void k_lc(const float* __restrict__ in,
                                            const float* __restrict__ stp,
                                            const float* __restrict__ g,
                                            const float* __restrict__ be,
                                            float inv,
                                            const float* __restrict__ lcw,
                                            const float* __restrict__ lcb,
                                            __bf16* __restrict__ Z,
                                            float* __restrict__ sto) {
    __shared__ float sAff[128];
    __shared__ float sred[4], ssred[4];
    if (threadIdx.x < 64) {
        int tt = threadIdx.x;
        float mm = bank4(stp, tt) * inv;
        float vv = bank4(stp, 64 + tt) * inv - mm * mm;
        float sc = g[tt] * rsqrtf(vv + EPSF);
        sAff[tt] = sc;
        sAff[64 + tt] = be[tt] - mm * sc;
    }
    __syncthreads();
    int morig = blockIdx.x * 256 + threadIdx.x;
    bool valid = morig < Bn * POS;
    int m = valid ? morig : Bn * POS - 1;
    const float* ip = in + (size_t)m * 64;
    float xv[64];
    #pragma unroll
    for (int j = 0; j < 16; ++j)
        *(float4*)&xv[j * 4] = *(const float4*)(ip + j * 4);
    __bf16 zb[64] __attribute__((aligned(16)));
    zb[62] = (__bf16)0.f; zb[63] = (__bf16)0.f;
    float ts = 0.f, tss = 0.f;
    float y0 = fmaxf(sAff[0] * xv[0] + sAff[64], 0.f);
    float y1 = fmaxf(sAff[1] * xv[1] + sAff[65], 0.f);
    #pragma unroll
    for (int c = 0; c < 62; ++c) {
        float y2 = fmaxf(sAff[c + 2] * xv[c + 2] + sAff[64 + c + 2], 0.f);
        float o = lcb[c] + y0 * lcw[c * 3] + y1 * lcw[c * 3 + 1] + y2 * lcw[c * 3 + 2];
        zb[c] = (__bf16)o;
        if (valid) { ts += o; tss += o * o; }
        y0 = y1; y1 = y2;
    }
    __bf16* zp = Z + (size_t)m * 64;
    #pragma unroll
    for (int j = 0; j < 8; ++j)
        *(uint4*)(zp + j * 8) = *(uint4*)(zb + j * 8);
    ts = wred(ts); tss = wred(tss);
    int wv = threadIdx.x >> 6, ln = threadIdx.x & 63;
    if (ln == 0) { sred[wv] = ts; ssred[wv] = tss; }
    __syncthreads();
    if (threadIdx.x == 0) {
        int slot = blockIdx.x & 63;
        atomicAdd(&sto[slot],      sred[0] + sred[1] + sred[2] + sred[3]);
        atomicAdd(&sto[64 + slot], ssred[0] + ssred[1] + ssred[2] + ssred[3]);
    }
}

// ---------------------------------------------------------------------------
// mix as MFMA; OUTBF: bf16 conv-input layout; else fp32 channel-last [m][64]
// ---------------------------------------------------------------------------
template <int POS, int IH, int IW, bool OUTBF>
__global__ __launch_bounds__(256, 2) void k_mixm(
    const __bf16* __restrict__ Z, const float* __restrict__ stp,
    const float* __restrict__ g, const float* __restrict__ be,
    float inv, const __bf16* __restrict__ wqm,
    const float* __restrict__ bm, void* __restrict__ outv,
    float* __restrict__ sto)
{
    const int b = blockIdx.y;
    const int m0 = blockIdx.x * 512;
    const int t = threadIdx.x, lane = t & 63, wv = t >> 6;
    const int l31 = lane & 31, lh = lane >> 5;

    float gs = 0.f, gss = 0.f;
    #pragma unroll
    for (int i = 0; i < 64; ++i) { gs += stp[i]; gss += stp[64 + i]; }
    float mm = gs * inv;
    float vv = gss * inv - mm * mm;
    float s0 = g[0] * rsqrtf(vv + EPSF);
    float t0 = be[0] - mm * s0;

    size_t zbase[4];
    #pragma unroll
    for (int mt = 0; mt < 4; ++mt) {
        int m = m0 + wv * 128 + mt * 32 + l31;
        int mc = m > POS - 1 ? POS - 1 : m;
        zbase[mt] = ((size_t)b * POS + mc) * 64;
    }

    ffrag acc[4][2] = {};
    #pragma unroll
    for (int ks = 0; ks < 4; ++ks) {
        const __bf16* wp = wqm + ks * 1024 + lh * 512 + l31 * 8;
        bfrag b0 = *(const bfrag*)wp;
        bfrag b1 = *(const bfrag*)(wp + 256);
        #pragma unroll
        for (int mt = 0; mt < 4; ++mt) {
            uint4 raw = *(const uint4*)(Z + zbase[mt] + ks * 16 + lh * 8);
            const __bf16* zin = (const __bf16*)&raw;
            __bf16 zout[8] __attribute__((aligned(16)));
            #pragma unroll
            for (int j = 0; j < 8; ++j) {
                float f = (float)zin[j];
                zout[j] = (__bf16)fmaxf(fmaf(s0, f, t0), 0.f);
            }
            bfrag a = *(const bfrag*)zout;
            acc[mt][0] = __builtin_amdgcn_mfma_f32_32x32x16_bf16(a, b0, acc[mt][0], 0, 0, 0);
            acc[mt][1] = __builtin_amdgcn_mfma_f32_32x32x16_bf16(a, b1, acc[mt][1], 0, 0, 0);
        }
    }

    float sS[2] = {0.f, 0.f}, sSS[2] = {0.f, 0.f};
    #pragma unroll
    for (int nt = 0; nt < 2; ++nt) {
        int oc = nt * 32 + l31;
        float bv = bm[oc];
        if constexpr (OUTBF) {
            __bf16* op = (__bf16*)outv;
            #pragma unroll
            for (int mt = 0; mt < 4; ++mt) {
                int mbase = m0 + wv * 128 + mt * 32 + lh * 4;
                #pragma unroll
                for (int g4 = 0; g4 < 4; ++g4) {
                    #pragma unroll
                    for (int q = 0; q < 4; ++q) {
                        int mr = mbase + g4 * 8 + q;
                        if (mr < POS) {
                            float v = acc[mt][nt][g4 * 4 + q] + bv;
                            int ih = mr / IW, iw = mr - ih * IW;
                            op[((size_t)(b * IH + ih) * 2 + nt) * (IW * 32) + iw * 32 + l31] = (__bf16)v;
                            sS[nt] += v; sSS[nt] += v * v;
                        }
                    }
                }
            }
        } else {
            float* op = (float*)outv + (size_t)b * POS * 64 + oc;
            #pragma unroll
            for (int mt = 0; mt < 4; ++mt) {
                int mbase = m0 + wv * 128 + mt * 32 + lh * 4;
                #pragma unroll
                for (int g4 = 0; g4 < 4; ++g4) {
                    #pragma unroll
                    for (int q = 0; q < 4; ++q) {
                        int mr = mbase + g4 * 8 + q;
                        if (mr < POS) {
                            float v = acc[mt][nt][g4 * 4 + q] + bv;
                            op[(size_t)mr * 64] = v;
                            sS[nt] += v; sSS[nt] += v * v;
                        }
                    }
                }
            }
        }
    }
    #pragma unroll
    for (int nt = 0; nt < 2; ++nt) {
        sS[nt]  += __shfl_down(sS[nt], 32);
        sSS[nt] += __shfl_down(sSS[nt], 32);
    }
    __shared__ float red[512];
    if (lane < 32) {
        #pragma unroll
        for (int nt = 0; nt < 2; ++nt) {
            red[wv * 64 + nt * 32 + l31]       = sS[nt];
            red[256 + wv * 64 + nt * 32 + l31] = sSS[nt];
        }
    }
    __syncthreads();
    if (t < 64) {
        int bank = ((blockIdx.x ^ blockIdx.y) & 3) * 128;
        atomicAdd(&sto[bank + t],      red[t] + red[64 + t] + red[128 + t] + red[192 + t]);
        atomicAdd(&sto[bank + 64 + t], red[256 + t] + red[320 + t] + red[384 + t] + red[448 + t]);
    }
}

// ---------------------------------------------------------------------------
// implicit-GEMM conv: MT m-tiles/wave, channel-subgroup-major LDS A-tile
//   As[sub(4)][NR*IW][8ch], sub = cc*2+lh.  A-fragment = one 16B chunk at
//   slot sub*NR*IW + X; consecutive lanes step +16B -> bank group (a+i)%8,
//   and row-wraps (dX=8==0 mod 8) preserve uniformity -> conflict-free for
//   ALL windows, no swizzle arithmetic in the K-loop.
// ---------------------------------------------------------------------------
template <int KH, int KW, int IH, int IW, int OH, int OW, int NR, int MT>
__global__ __launch_bounds__(256, 2) void k_convmfma(
    const __bf16* __restrict__ in,
    const __bf16* __restrict__ wq,
    const float* __restrict__ bias,
    float* __restrict__ out,
    float* __restrict__ sto)
{
    constexpr int P = OH * OW;
    constexpr int MB = 128 * MT;
    constexpr int PLANE = NR * IW;          // chunks per sub-plane
    const int b  = blockIdx.y;
    const int m0 = blockIdx.x * MB;
    const int t  = threadIdx.x;
    const int lane = t & 63;
    const int wv = t >> 6;
    const int l31 = lane & 31, lh = lane >> 5;

    __shared__ __align__(16) __bf16 As[4 * PLANE * 8];

    const int oh_lo = m0 / OW;
    int posm[MT];
    #pragma unroll
    for (int mt = 0; mt < MT; ++mt) {
        int m = m0 + wv * (32 * MT) + mt * 32 + l31;
        int mc = m > P - 1 ? P - 1 : m;
        int oh = mc / OW, ow = mc - oh * OW;
        posm[mt] = (oh - oh_lo) * IW + ow;
    }

    ffrag acc[MT][2] = {};

    for (int ich = 0; ich < 2; ++ich) {
        __syncthreads();
        constexpr int CHUNKS = PLANE * 4;
        for (int idx = t; idx < CHUNKS; idx += 256) {
            int cg = idx & 3, iwr = idx >> 2;
            int r = iwr / IW, iw = iwr - r * IW;
            int ih = oh_lo + r; if (ih > IH - 1) ih = IH - 1;
            const __bf16* src = in + ((size_t)(b * IH + ih) * 2 + ich) * (IW * 32) + iw * 32 + cg * 8;
            *(uint4*)&As[(cg * PLANE + r * IW + iw) * 8] = *(const uint4*)src;
        }
        __syncthreads();

        const __bf16* wich = wq + ich * 2048;
        const int subplane0 = lh * PLANE;           // cc=0 plane for this lane-half
        for (int kh = 0; kh < KH; ++kh) {
            const int rowoff = kh * IW;
            const __bf16* wkh = wich + (size_t)(kh * KW) * 4096 + lh * 512 + l31 * 8;
            #pragma unroll 2
            for (int kw = 0; kw < KW; ++kw) {
                const __bf16* wp = wkh + kw * 4096;
                #pragma unroll
                for (int cc = 0; cc < 2; ++cc) {
                    bfrag b0 = *(const bfrag*)(wp + cc * 1024);
                    bfrag b1 = *(const bfrag*)(wp + cc * 1024 + 256);
                    const int plane = subplane0 + cc * 2 * PLANE;
                    #pragma unroll
                    for (int mt = 0; mt < MT; ++mt) {
                        int X = posm[mt] + rowoff + kw;
                        bfrag a = *(const bfrag*)&As[(plane + X) * 8];
                        acc[mt][0] = __builtin_amdgcn_mfma_f32_32x32x16_bf16(a, b0, acc[mt][0], 0, 0, 0);
                        acc[mt][1] = __builtin_amdgcn_mfma_f32_32x32x16_bf16(a, b1, acc[mt][1], 0, 0, 0);
                    }
                }
            }
        }
    }

    float sS[2] = {0.f, 0.f}, sSS[2] = {0.f, 0.f};
    #pragma unroll
    for (int nt = 0; nt < 2; ++nt) {
        int oc = nt * 32 + l31;
        float bv = bias[oc];
        float* op = out + (size_t)b * P * 64 + oc;
        #pragma unroll
        for (int mt = 0; mt < MT; ++mt) {
            int mbase = m0 + wv * (32 * MT) + mt * 32 + lh * 4;
            #pragma unroll
            for (int g = 0; g < 4; ++g) {
                #pragma unroll
                for (int q = 0; q < 4; ++q) {
                    int mr = mbase + g * 8 + q;
                    if (mr < P) {
                        float v = acc[mt][nt][g * 4 + q] + bv;
                        op[(size_t)mr * 64] = v;
                        sS[nt] += v; sSS[nt] += v * v;
                    }
                }
            }
        }
    }
    #pragma unroll
    for (int nt = 0; nt < 2; ++nt) {
        sS[nt]  += __shfl_down(sS[nt], 32);
        sSS[nt] += __shfl_down(sSS[nt], 32);
    }
    __syncthreads();
    float* redS  = (float*)As;
    float* redSS = redS + 256;
    if (lane < 32) {
        #pragma unroll
        for (int nt = 0; nt < 2; ++nt) {
            redS[wv * 64 + nt * 32 + l31]  = sS[nt];
            redSS[wv * 64 + nt * 32 + l31] = sSS[nt];
        }
    }
    __syncthreads();
    if (t < 64) {
        int bank = ((blockIdx.x ^ blockIdx.y) & 3) * 128;
        atomicAdd(&sto[bank + t],      redS[t] + redS[64 + t] + redS[128 + t] + redS[192 + t]);
        atomicAdd(&sto[bank + 64 + t], redSS[t] + redSS[64 + t] + redSS[128 + t] + redSS[192 + t]);
    }
}

// ---------------------------------------------------------------------------
// prep_hb: Y fp32 channel-last [m][64] + affine -> hb bf16 flat (same order),
// Wf1 -> bf16 with matching k-permutation k' = p*64+c.
// ---------------------------------------------------------------------------
constexpr int NHB  = M3 * 64 / 8;        // 1,089,536
constexpr int NWFB = 64 * KFC / 8;       // 544,768
__global__ __launch_bounds__(256) void k_prep_hb(
    const float* __restrict__ Y, const float* __restrict__ stp,
    const float* __restrict__ g, const float* __restrict__ be, float inv,
    const float* __restrict__ Wf1,
    __bf16* __restrict__ hb, __bf16* __restrict__ wf1b)
{
    __shared__ float sA[128];
    if (threadIdx.x < 64) {
        int c = threadIdx.x;
        float mm = bank4(stp, c) * inv;
        float vv = bank4(stp, 64 + c) * inv - mm * mm;
        float sc = g[c] * rsqrtf(vv + EPSF);
        sA[c] = sc; sA[64 + c] = be[c] - mm * sc;
    }
    __syncthreads();
    int idx = blockIdx.x * 256 + threadIdx.x;
    if (idx < NHB) {
        size_t base = (size_t)idx * 8;
        int c0 = (int)(base & 63);
        __bf16 tmp[8] __attribute__((aligned(16)));
        #pragma unroll
        for (int j = 0; j < 8; ++j)
            tmp[j] = (__bf16)(sA[c0 + j] * Y[base + j] + sA[64 + c0 + j]);
        *(uint4*)(hb + base) = *(uint4*)tmp;
        return;
    }
    idx -= NHB;
    if (idx < NWFB) {
        size_t base = (size_t)idx * 8;
        int f = (int)(base / KFC);
        int r = (int)(base - (size_t)f * KFC);    // r = p*64 + c0
        int p = r >> 6, c0 = r & 63;
        __bf16 tmp[8] __attribute__((aligned(16)));
        #pragma unroll
        for (int j = 0; j < 8; ++j)
            tmp[j] = (__bf16)Wf1[(size_t)f * KFC + (size_t)(c0 + j) * P3 + p];
        *(uint4*)(wf1b + base) = *(uint4*)tmp;
    }
}

// ---------------------------------------------------------------------------
// fc1 as MFMA: [128 x K] x [K x 64], split-K 112 chunks of 608
// ---------------------------------------------------------------------------
__global__ __launch_bounds__(256) void k_fc1m(const __bf16* __restrict__ hb,
                                              const __bf16* __restrict__ wf1b,
                                              float* __restrict__ Pb) {
    const int kc = blockIdx.x;
    const int t = threadIdx.x, lane = t & 63, wv = t >> 6;
    const int l31 = lane & 31, lh = lane >> 5;
    const int k0 = kc * FCKL;

    const __bf16* ap = hb + (size_t)(wv * 32 + l31) * KFC + k0 + lh * 8;
    const __bf16* bp0 = wf1b + (size_t)l31 * KFC + k0 + lh * 8;
    const __bf16* bp1 = wf1b + (size_t)(32 + l31) * KFC + k0 + lh * 8;

    ffrag acc[2] = {};
    #pragma unroll 2
    for (int ks = 0; ks < FCKS; ++ks) {
        bfrag a  = *(const bfrag*)(ap  + ks * 16);
        bfrag b0 = *(const bfrag*)(bp0 + ks * 16);
        bfrag b1 = *(const bfrag*)(bp1 + ks * 16);
        acc[0] = __builtin_amdgcn_mfma_f32_32x32x16_bf16(a, b0, acc[0], 0, 0, 0);
        acc[1] = __builtin_amdgcn_mfma_f32_32x32x16_bf16(a, b1, acc[1], 0, 0, 0);
    }
    float* pp = Pb + (size_t)kc * 8192;
    #pragma unroll
    for (int nt = 0; nt < 2; ++nt) {
        #pragma unroll
        for (int g = 0; g < 4; ++g) {
            #pragma unroll
            for (int q = 0; q < 4; ++q) {
                int row = q + g * 8 + lh * 4;
                int bb = wv * 32 + row;
                pp[bb * 64 + nt * 32 + l31] = acc[nt][g * 4 + q];
            }
        }
    }
}

__global__ __launch_bounds__(256) void k_fc1red(const float* __restrict__ Pb,
                                                float* __restrict__ F) {
    int m = blockIdx.x * 256 + threadIdx.x;
    float s = 0.f;
    for (int kc = 0; kc < FCCH; ++kc) s += Pb[(size_t)kc * 8192 + m];
    F[m] = s;
}

__global__ __launch_bounds__(256) void k_fcfin(const float* __restrict__ F,
                                               const float* __restrict__ bf1,
                                               const float* __restrict__ gf,
                                               const float* __restrict__ bef,
                                               const float* __restrict__ Wf2,
                                               const float* __restrict__ bf2,
                                               float* __restrict__ out) {
    __shared__ float sF[8192];
    __shared__ float sfa[128];
    const int t = threadIdx.x;
    for (int m = t; m < 8192; m += 256) sF[m] = F[m];
    __syncthreads();
    if (t < 64) {
        float s = 0.f, ss = 0.f;
        for (int b = 0; b < Bn; ++b) {
            float v = sF[b * 64 + t] + bf1[t];
            s += v; ss += v * v;
        }
        float m  = s / 128.f;
        float va = ss / 128.f - m * m;
        float sc = gf[t] * rsqrtf(va + EPSF);
        sfa[t] = sc;
        sfa[64 + t] = sc * bf1[t] + bef[t] - m * sc;
    }
    __syncthreads();
    for (int m = t; m < Bn * 35; m += 256) {
        int b = m / 35, o = m - b * 35;
        float acc = bf2[o];
        for (int ff = 0; ff < 64; ++ff) {
            int f = (ff + t) & 63;
            float z = fmaxf(sfa[f] * sF[b * 64 + f] + sfa[64 + f], 0.f);
            acc += z * Wf2[o * 64 + f];
        }
        out[m] = acc;
    }
}

// ---------------------------------------------------------------------------
// launch
// ---------------------------------------------------------------------------
extern "C" void kernel_launch(void* const* d_in, const int* in_sizes, int n_in,
                              void* d_out, int out_size, void* d_ws, size_t ws_size,
                              hipStream_t stream) {
    const float* x    = (const float*)d_in[0];
    const float* W11  = (const float*)d_in[1];
    const float* b11  = (const float*)d_in[2];
    const float* g11  = (const float*)d_in[3];
    const float* be11 = (const float*)d_in[4];
    const float* lc1w = (const float*)d_in[5];
    const float* lc1b = (const float*)d_in[6];
    const float* g12  = (const float*)d_in[7];
    const float* be12 = (const float*)d_in[8];
    const float* W13  = (const float*)d_in[9];
    const float* b13  = (const float*)d_in[10];
    const float* g13  = (const float*)d_in[11];
    const float* be13 = (const float*)d_in[12];
    const float* W21  = (const float*)d_in[13];
    const float* b21  = (const float*)d_in[14];
    const float* g21  = (const float*)d_in[15];
    const float* be21 = (const float*)d_in[16];
    const float* lc2w = (const float*)d_in[17];
    const float* lc2b = (const float*)d_in[18];
    const float* g22  = (const float*)d_in[19];
    const float* be22 = (const float*)d_in[20];
    const float* W23  = (const float*)d_in[21];
    const float* b23  = (const float*)d_in[22];
    const float* g23  = (const float*)d_in[23];
    const float* be23 = (const float*)d_in[24];
    const float* W31  = (const float*)d_in[25];
    const float* b31  = (const float*)d_in[26];
    const float* g31  = (const float*)d_in[27];
    const float* be31 = (const float*)d_in[28];
    const float* lc3w = (const float*)d_in[29];
    const float* lc3b = (const float*)d_in[30];
    const float* g32  = (const float*)d_in[31];
    const float* be32 = (const float*)d_in[32];
    const float* W33  = (const float*)d_in[33];
    const float* b33  = (const float*)d_in[34];
    const float* g33  = (const float*)d_in[35];
    const float* be33 = (const float*)d_in[36];
    const float* Wf1  = (const float*)d_in[37];
    const float* bf1  = (const float*)d_in[38];
    const float* gf   = (const float*)d_in[39];
    const float* bef  = (const float*)d_in[40];
    const float* Wf2  = (const float*)d_in[41];
    const float* bf2  = (const float*)d_in[42];

    float* ws  = (float*)d_ws;
    float* A   = ws + oA;
    float* Bb  = ws + oB;
    __bf16* Abf = (__bf16*)(ws + oA);
    __bf16* Bbf = (__bf16*)(ws + oB);
    __bf16* hb   = (__bf16*)(ws + oHB);
    __bf16* wf1b = (__bf16*)(ws + oWF);
    __bf16* wq2f = (__bf16*)(ws + oW2);
    __bf16* wq3f = (__bf16*)(ws + oW3);
    __bf16* wq1  = (__bf16*)(ws + oW1);
    __bf16* wqm  = (__bf16*)(ws + oWM);
    float* bfold = ws + oBF;
    float* Pb  = ws + oP;
    float* st  = ws + oSt;
    float* F   = ws + oF;

    const int blk1 = (M1 + 255) / 256;
    const int blk2 = M2 / 256;
    const int blk3 = M3 / 256;

    k_prep_all<<<(NPREP + 255) / 256, 256, 0, stream>>>(W11, W13, W23, W33, wq1, wqm, st);

    // ---- stage 1 ----
    k_conv1m<<<dim3((P1 + 511) / 512, Bn), 256, 0, stream>>>(x, wq1, b11, A, st + 0 * 512);
    k_lc<P1><<<blk1, 256, 0, stream>>>(A, st + 0 * 512, g11, be11, 1.0f / (float)M1,
                                       lc1w, lc1b, Bbf, st + 1 * 512);
    k_mixm<P1, H1, Wo1, true><<<dim3((P1 + 511) / 512, Bn), 256, 0, stream>>>(
        Bbf, st + 1 * 512, g12, be12, 1.0f / (62.0f * (float)M1),
        wqm + 0 * 4096, b13, (void*)Abf, st + 2 * 512);

    // ---- stage 2 ----
    k_foldw<KH2, KW2><<<64, 256, 0, stream>>>(W21, st + 2 * 512, g13, be13,
                                              1.0f / (float)M1, b21, wq2f, bfold + 0);
    k_convmfma<KH2, KW2, H1, Wo1, H2, Wo2, 35, 4>
        <<<dim3((P2 + 511) / 512, Bn), 256, 0, stream>>>(Abf, wq2f, bfold + 0, Bb, st + 3 * 512);
    k_lc<P2><<<blk2, 256, 0, stream>>>(Bb, st + 3 * 512, g21, be21, 1.0f / (float)M2,
                                       lc2w, lc2b, Abf, st + 4 * 512);
    k_mixm<P2, H2, Wo2, true><<<dim3((P2 + 511) / 512, Bn), 256, 0, stream>>>(
        Abf, st + 4 * 512, g22, be22, 1.0f / (62.0f * (float)M2),
        wqm + 1 * 4096, b23, (void*)Bbf, st + 5 * 512);

    // ---- stage 3 ----
    k_foldw<KH3, KW3><<<64, 256, 0, stream>>>(W31, st + 5 * 512, g23, be23,
                                              1.0f / (float)M2, b31, wq3f, bfold + 64);
    k_convmfma<KH3, KW3, H2, Wo2, H3, Wo3, 30, 3>
        <<<dim3((P3 + 383) / 384, Bn), 256, 0, stream>>>(Bbf, wq3f, bfold + 64, A, st + 6 * 512);
    k_lc<P3><<<blk3, 256, 0, stream>>>(A, st + 6 * 512, g31, be31, 1.0f / (float)M3,
                                       lc3w, lc3b, Bbf, st + 7 * 512);
    k_mixm<P3, 1, 1, false><<<dim3((P3 + 511) / 512, Bn), 256, 0, stream>>>(
        Bbf, st + 7 * 512, g32, be32, 1.0f / (62.0f * (float)M3),
        wqm + 2 * 4096, b33, (void*)A, st + 8 * 512);

    // ---- FC head ----
    k_prep_hb<<<(NHB + NWFB + 255) / 256, 256, 0, stream>>>(
        A, st + 8 * 512, g33, be33, 1.0f / (float)M3, Wf1, hb, wf1b);
    k_fc1m<<<FCCH, 256, 0, stream>>>(hb, wf1b, Pb);
    k_fc1red<<<32, 256, 0, stream>>>(Pb, F);
    k_fcfin<<<1, 256, 0, stream>>>(F, bf1, gf, bef, Wf2, bf2, (float*)d_out);
}